// Round 1
// baseline (1532.234 us; speedup 1.0000x reference)
//
#include <hip/hip_runtime.h>
#include <math.h>

#define NG 2048
#define NPG 64
#define EPG 512
#define ETOT (NG*EPG)     // 1048576 edges
#define IND 64
#define H1D 128
#define H2D 64
#define OUTD 2016

// ---------------- Kernel 1: per-graph fused encoder ----------------
// block = 256 threads, grid = 2048 (one block per graph)
// LDS: R1 = [x(64x65) | agg1(64x65)] later reused as agg2[64][129]
//      R2 = h1[64][129], ssum[128] for the segment-mean reduction.
__global__ __launch_bounds__(256, 2) void k1_encoder(
    const float* __restrict__ x, const int* __restrict__ ei,
    const float* __restrict__ eps,
    const float* __restrict__ w1_rel, const float* __restrict__ b1, const float* __restrict__ w1_root,
    const float* __restrict__ w2_rel, const float* __restrict__ b2, const float* __restrict__ w2_root,
    const float* __restrict__ w3_rel, const float* __restrict__ b3, const float* __restrict__ w3_root,
    float* __restrict__ out_mu, float* __restrict__ out_lv, float* __restrict__ zbuf)
{
  __shared__ float R1[2*64*65];   // 33280 B
  __shared__ float R2[64*129];    // 33024 B
  __shared__ float ssum[128];

  const int g = blockIdx.x;
  const int tid = threadIdx.x;

  // ---- stage x tile [64][64] into R1 (stride 65), zero agg1 region ----
  const float* xg = x + (size_t)g * (NPG*IND);
  for (int i = tid; i < (NPG*IND)/4; i += 256) {
    float4 v = ((const float4*)xg)[i];
    int n = i >> 4, k = (i & 15) * 4;
    float* p = &R1[n*65 + k];
    p[0] = v.x; p[1] = v.y; p[2] = v.z; p[3] = v.w;
  }
  for (int i = tid; i < 64*65; i += 256) R1[64*65 + i] = 0.f;
  if (tid < 128) ssum[tid] = 0.f;

  // ---- each thread owns 2 edges of this graph ----
  const int e0 = g*EPG + tid*2;
  const int s0 = ei[e0] & 63,     d0 = ei[ETOT + e0] & 63;
  const int s1 = ei[e0 + 1] & 63, d1 = ei[ETOT + e0 + 1] & 63;
  __syncthreads();

  // ---- agg1[d] += x[s]  (LDS scatter, 64 dims) ----
  {
    float* agg1 = R1 + 64*65;
    #pragma unroll 4
    for (int k = 0; k < 64; ++k) atomicAdd(&agg1[d0*65 + k], R1[s0*65 + k]);
    #pragma unroll 4
    for (int k = 0; k < 64; ++k) atomicAdd(&agg1[d1*65 + k], R1[s1*65 + k]);
  }
  __syncthreads();

  const int c  = tid & 15;   // col group (8 cols each)
  const int rg = tid >> 4;   // row group (4 rows each)

  // ---- conv1: h1 = relu(agg1@w1_rel + b1 + x@w1_root), out [64][128] ----
  {
    const int jb = c*8;
    const float* agg1 = R1 + 64*65;
    float acc[4][8];
    #pragma unroll
    for (int i = 0; i < 4; ++i)
      #pragma unroll
      for (int j = 0; j < 8; ++j) acc[i][j] = 0.f;

    #pragma unroll 2
    for (int k = 0; k < 64; ++k) {
      float w[8], a[4];
      *(float4*)&w[0] = *(const float4*)&w1_rel[k*H1D + jb];
      *(float4*)&w[4] = *(const float4*)&w1_rel[k*H1D + jb + 4];
      #pragma unroll
      for (int i = 0; i < 4; ++i) a[i] = agg1[(rg*4 + i)*65 + k];
      #pragma unroll
      for (int i = 0; i < 4; ++i)
        #pragma unroll
        for (int j = 0; j < 8; ++j) acc[i][j] += a[i]*w[j];
    }
    #pragma unroll 2
    for (int k = 0; k < 64; ++k) {
      float w[8], a[4];
      *(float4*)&w[0] = *(const float4*)&w1_root[k*H1D + jb];
      *(float4*)&w[4] = *(const float4*)&w1_root[k*H1D + jb + 4];
      #pragma unroll
      for (int i = 0; i < 4; ++i) a[i] = R1[(rg*4 + i)*65 + k];
      #pragma unroll
      for (int i = 0; i < 4; ++i)
        #pragma unroll
        for (int j = 0; j < 8; ++j) acc[i][j] += a[i]*w[j];
    }
    #pragma unroll
    for (int j = 0; j < 8; ++j) {
      float bb = b1[jb + j];
      #pragma unroll
      for (int i = 0; i < 4; ++i) {
        float v = acc[i][j] + bb;
        R2[(rg*4 + i)*129 + jb + j] = v > 0.f ? v : 0.f;
      }
    }
  }
  __syncthreads();

  // ---- zero agg2 (reuse R1 as [64][129]) ----
  for (int i = tid; i < 64*129; i += 256) R1[i] = 0.f;
  __syncthreads();

  // ---- agg2[d] += h1[s]  (128 dims) ----
  {
    #pragma unroll 4
    for (int k = 0; k < 128; ++k) atomicAdd(&R1[d0*129 + k], R2[s0*129 + k]);
    #pragma unroll 4
    for (int k = 0; k < 128; ++k) atomicAdd(&R1[d1*129 + k], R2[s1*129 + k]);
  }
  __syncthreads();

  // ---- conv2+conv3 fused: out [64 rows][128 cols]; cols<64 -> mu-pre (w2),
  //      cols>=64 -> logvar-pre (w3). K = 256 (agg2 | h1). Then column-mean. ----
  {
    const bool is_lv = (c >= 8);
    const int jb = (c & 7)*8;
    const float* wrel  = is_lv ? w3_rel  : w2_rel;
    const float* wroot = is_lv ? w3_root : w2_root;
    float acc[4][8];
    #pragma unroll
    for (int i = 0; i < 4; ++i)
      #pragma unroll
      for (int j = 0; j < 8; ++j) acc[i][j] = 0.f;

    #pragma unroll 2
    for (int k = 0; k < 128; ++k) {
      float w[8], a[4];
      *(float4*)&w[0] = *(const float4*)&wrel[k*H2D + jb];
      *(float4*)&w[4] = *(const float4*)&wrel[k*H2D + jb + 4];
      #pragma unroll
      for (int i = 0; i < 4; ++i) a[i] = R1[(rg*4 + i)*129 + k];  // agg2
      #pragma unroll
      for (int i = 0; i < 4; ++i)
        #pragma unroll
        for (int j = 0; j < 8; ++j) acc[i][j] += a[i]*w[j];
    }
    #pragma unroll 2
    for (int k = 0; k < 128; ++k) {
      float w[8], a[4];
      *(float4*)&w[0] = *(const float4*)&wroot[k*H2D + jb];
      *(float4*)&w[4] = *(const float4*)&wroot[k*H2D + jb + 4];
      #pragma unroll
      for (int i = 0; i < 4; ++i) a[i] = R2[(rg*4 + i)*129 + k];  // h1
      #pragma unroll
      for (int i = 0; i < 4; ++i)
        #pragma unroll
        for (int j = 0; j < 8; ++j) acc[i][j] += a[i]*w[j];
    }
    // partial column sums (4 rows) -> ssum
    #pragma unroll
    for (int j = 0; j < 8; ++j) {
      float p = acc[0][j] + acc[1][j] + acc[2][j] + acc[3][j];
      atomicAdd(&ssum[(is_lv ? 64 : 0) + jb + j], p);
    }
  }
  __syncthreads();

  // ---- mean, bias, reparameterize, write mu/logvar/z ----
  if (tid < 64) {
    float mu = ssum[tid]      * (1.f/64.f) + b2[tid];
    float lv = ssum[64 + tid] * (1.f/64.f) + b3[tid];
    out_mu[(size_t)g*64 + tid] = mu;
    out_lv[(size_t)g*64 + tid] = lv;
    zbuf[(size_t)g*64 + tid] = mu + eps[(size_t)g*64 + tid] * __expf(0.5f*lv);
  }
}

// ---------------- Kernel 2: decoder GEMM ----------------
// grid = (32 graph-tiles of 64, 9 col-chunks of 224), block = 256
__global__ __launch_bounds__(256, 2) void k2_decoder(
    const float* __restrict__ z, const float* __restrict__ fc1_w, const float* __restrict__ fc1_b,
    const float* __restrict__ fc2_w, const float* __restrict__ fc2_b, float* __restrict__ recon)
{
  __shared__ float sz[64*65];   // z tile
  __shared__ float sh[64*129];  // h tile
  const int bg  = blockIdx.x;   // graph tile
  const int cc  = blockIdx.y;   // col chunk
  const int tid = threadIdx.x;

  const float* zg = z + (size_t)bg*64*H2D;
  for (int i = tid; i < (64*H2D)/4; i += 256) {
    float4 v = ((const float4*)zg)[i];
    int n = i >> 4, k = (i & 15)*4;
    float* p = &sz[n*65 + k];
    p[0]=v.x; p[1]=v.y; p[2]=v.z; p[3]=v.w;
  }
  __syncthreads();

  // h = relu(z @ fc1_w + fc1_b) : [64][128], K=64
  {
    const int c = tid & 15, rg = tid >> 4, jb = c*8;
    float acc[4][8];
    #pragma unroll
    for (int i = 0; i < 4; ++i)
      #pragma unroll
      for (int j = 0; j < 8; ++j) acc[i][j] = 0.f;
    #pragma unroll 2
    for (int k = 0; k < 64; ++k) {
      float w[8], a[4];
      *(float4*)&w[0] = *(const float4*)&fc1_w[k*H1D + jb];
      *(float4*)&w[4] = *(const float4*)&fc1_w[k*H1D + jb + 4];
      #pragma unroll
      for (int i = 0; i < 4; ++i) a[i] = sz[(rg*4 + i)*65 + k];
      #pragma unroll
      for (int i = 0; i < 4; ++i)
        #pragma unroll
        for (int j = 0; j < 8; ++j) acc[i][j] += a[i]*w[j];
    }
    #pragma unroll
    for (int j = 0; j < 8; ++j) {
      float bb = fc1_b[jb + j];
      #pragma unroll
      for (int i = 0; i < 4; ++i) {
        float v = acc[i][j] + bb;
        sh[(rg*4 + i)*129 + jb + j] = v > 0.f ? v : 0.f;
      }
    }
  }
  __syncthreads();

  // recon chunk = sigmoid(h @ fc2_w[:, chunk] + fc2_b[chunk])
  // thread: 1 row (r = tid>>2), 56 cols
  {
    const int r  = tid >> 2;
    const int c0 = cc*224 + (tid & 3)*56;
    float acc[56];
    #pragma unroll
    for (int q = 0; q < 56; ++q) acc[q] = 0.f;
    for (int k = 0; k < H1D; ++k) {
      float a = sh[r*129 + k];
      const float* wrow = &fc2_w[(size_t)k*OUTD + c0];
      #pragma unroll
      for (int q = 0; q < 14; ++q) {
        float4 w = *(const float4*)&wrow[q*4];
        acc[q*4+0] += a*w.x; acc[q*4+1] += a*w.y;
        acc[q*4+2] += a*w.z; acc[q*4+3] += a*w.w;
      }
    }
    float* outr = recon + ((size_t)(bg*64 + r))*OUTD + c0;
    #pragma unroll
    for (int q = 0; q < 14; ++q) {
      float4 o;
      float v0 = acc[q*4+0] + fc2_b[c0 + q*4+0];
      float v1 = acc[q*4+1] + fc2_b[c0 + q*4+1];
      float v2 = acc[q*4+2] + fc2_b[c0 + q*4+2];
      float v3 = acc[q*4+3] + fc2_b[c0 + q*4+3];
      o.x = 1.f/(1.f + __expf(-v0));
      o.y = 1.f/(1.f + __expf(-v1));
      o.z = 1.f/(1.f + __expf(-v2));
      o.w = 1.f/(1.f + __expf(-v3));
      *(float4*)outr = o;
      outr += 4;
    }
  }
}

extern "C" void kernel_launch(void* const* d_in, const int* in_sizes, int n_in,
                              void* d_out, int out_size, void* d_ws, size_t ws_size,
                              hipStream_t stream) {
  const float* x       = (const float*)d_in[0];
  const int*   ei      = (const int*)d_in[1];
  // d_in[2] = batch (structure is implicit: 64 nodes per graph) — unused
  const float* eps     = (const float*)d_in[3];
  const float* w1_rel  = (const float*)d_in[4];
  const float* b1      = (const float*)d_in[5];
  const float* w1_root = (const float*)d_in[6];
  const float* w2_rel  = (const float*)d_in[7];
  const float* b2      = (const float*)d_in[8];
  const float* w2_root = (const float*)d_in[9];
  const float* w3_rel  = (const float*)d_in[10];
  const float* b3      = (const float*)d_in[11];
  const float* w3_root = (const float*)d_in[12];
  const float* fc1_w   = (const float*)d_in[13];
  const float* fc1_b   = (const float*)d_in[14];
  const float* fc2_w   = (const float*)d_in[15];
  const float* fc2_b   = (const float*)d_in[16];

  float* recon  = (float*)d_out;                       // [2048][2016]
  float* out_mu = recon + (size_t)NG*OUTD;             // [2048][64]
  float* out_lv = out_mu + (size_t)NG*H2D;             // [2048][64]
  float* zbuf   = (float*)d_ws;                        // [2048][64] scratch

  k1_encoder<<<NG, 256, 0, stream>>>(x, ei, eps,
      w1_rel, b1, w1_root, w2_rel, b2, w2_root, w3_rel, b3, w3_root,
      out_mu, out_lv, zbuf);
  k2_decoder<<<dim3(32, 9), 256, 0, stream>>>(zbuf, fc1_w, fc1_b, fc2_w, fc2_b, recon);
}

// Round 2
// 417.668 us; speedup vs baseline: 3.6685x; 3.6685x over previous
//
#include <hip/hip_runtime.h>
#include <math.h>

#define NG 2048
#define NPG 64
#define EPG 512
#define ETOT (NG*EPG)     // 1048576 edges
#define IND 64
#define H1D 128
#define H2D 64
#define OUTD 2016

// ---------------- Kernel 1: per-graph fused encoder + reparam + fc1 ----------------
// One block (256 thr) per graph. Key algebra: we only need the column-MEAN of
// conv2/conv3 outputs, so  mean_i(agg2@Wrel) = (sum_s degout[s]*h1[s])@Wrel/64
// and mean_i(h1@Wroot) = (sum_s h1[s])@Wroot/64  -> h1 is reduced from registers,
// never materialized; conv2/3 become four 128x64 vec-mats.
__global__ __launch_bounds__(256, 3) void k1_encoder(
    const float* __restrict__ x, const int* __restrict__ ei,
    const float* __restrict__ eps,
    const float* __restrict__ w1_rel, const float* __restrict__ b1, const float* __restrict__ w1_root,
    const float* __restrict__ w2_rel, const float* __restrict__ b2, const float* __restrict__ w2_root,
    const float* __restrict__ w3_rel, const float* __restrict__ b3, const float* __restrict__ w3_root,
    const float* __restrict__ fc1_w, const float* __restrict__ fc1_b,
    float* __restrict__ out_mu, float* __restrict__ out_lv, float* __restrict__ hbuf)
{
  __shared__ float X[64*65];     // x tile, stride 65
  __shared__ float A[64*66];     // adjacency counts, stride 66 (even+2 -> 2-way free)
  __shared__ float AG[64*65];    // agg1 = A @ X
  __shared__ float degout[64];
  __shared__ float wsum[H1D];    // sum_s degout[s]*h1[s][k]
  __shared__ float hsum[H1D];    // sum_s h1[s][k]
  __shared__ float part[4*64];
  __shared__ float zrow[64];

  const int g = blockIdx.x;
  const int tid = threadIdx.x;

  // ---- stage x tile, zero accumulators ----
  const float* xg = x + (size_t)g * (NPG*IND);
  for (int i = tid; i < (NPG*IND)/4; i += 256) {
    float4 v = ((const float4*)xg)[i];
    int n = i >> 4, k = (i & 15) * 4;
    float* p = &X[n*65 + k];
    p[0] = v.x; p[1] = v.y; p[2] = v.z; p[3] = v.w;
  }
  for (int i = tid; i < 64*66; i += 256) A[i] = 0.f;
  if (tid < 64) degout[tid] = 0.f;
  if (tid < 128) { wsum[tid] = 0.f; hsum[tid] = 0.f; }

  const int e0 = g*EPG + tid*2;
  const int s0 = ei[e0] & 63,     d0 = ei[ETOT + e0] & 63;
  const int s1 = ei[e0 + 1] & 63, d1 = ei[ETOT + e0 + 1] & 63;
  __syncthreads();

  // ---- build adjacency (512 scalar atomics) + out-degree ----
  atomicAdd(&A[d0*66 + s0], 1.f);
  atomicAdd(&A[d1*66 + s1], 1.f);
  atomicAdd(&degout[s0], 1.f);
  atomicAdd(&degout[s1], 1.f);
  __syncthreads();

  const int c  = tid & 15;   // col group
  const int rg = tid >> 4;   // row group (4 rows)

  // ---- phase 1: AG = A @ X   (64x64, K=64) ----
  {
    const int jb = c*4;
    float acc[4][4];
    #pragma unroll
    for (int i = 0; i < 4; ++i)
      #pragma unroll
      for (int j = 0; j < 4; ++j) acc[i][j] = 0.f;
    #pragma unroll 4
    for (int k = 0; k < 64; ++k) {
      float4 xv = *(const float4*)&X[k*65 + jb];
      float a0 = A[(rg*4+0)*66 + k];
      float a1 = A[(rg*4+1)*66 + k];
      float a2 = A[(rg*4+2)*66 + k];
      float a3 = A[(rg*4+3)*66 + k];
      acc[0][0]+=a0*xv.x; acc[0][1]+=a0*xv.y; acc[0][2]+=a0*xv.z; acc[0][3]+=a0*xv.w;
      acc[1][0]+=a1*xv.x; acc[1][1]+=a1*xv.y; acc[1][2]+=a1*xv.z; acc[1][3]+=a1*xv.w;
      acc[2][0]+=a2*xv.x; acc[2][1]+=a2*xv.y; acc[2][2]+=a2*xv.z; acc[2][3]+=a2*xv.w;
      acc[3][0]+=a3*xv.x; acc[3][1]+=a3*xv.y; acc[3][2]+=a3*xv.z; acc[3][3]+=a3*xv.w;
    }
    #pragma unroll
    for (int i = 0; i < 4; ++i) {
      float* p = &AG[(rg*4 + i)*65 + jb];
      p[0]=acc[i][0]; p[1]=acc[i][1]; p[2]=acc[i][2]; p[3]=acc[i][3];
    }
  }
  __syncthreads();

  // ---- phase 2: h1 = relu(AG@w1_rel + X@w1_root + b1); reduce wsum/hsum ----
  {
    const int jb = c*8;
    float acc[4][8];
    #pragma unroll
    for (int i = 0; i < 4; ++i)
      #pragma unroll
      for (int j = 0; j < 8; ++j) acc[i][j] = 0.f;

    #pragma unroll 2
    for (int k = 0; k < 64; ++k) {
      float w[8], a[4];
      *(float4*)&w[0] = *(const float4*)&w1_rel[k*H1D + jb];
      *(float4*)&w[4] = *(const float4*)&w1_rel[k*H1D + jb + 4];
      #pragma unroll
      for (int i = 0; i < 4; ++i) a[i] = AG[(rg*4 + i)*65 + k];
      #pragma unroll
      for (int i = 0; i < 4; ++i)
        #pragma unroll
        for (int j = 0; j < 8; ++j) acc[i][j] += a[i]*w[j];
    }
    #pragma unroll 2
    for (int k = 0; k < 64; ++k) {
      float w[8], a[4];
      *(float4*)&w[0] = *(const float4*)&w1_root[k*H1D + jb];
      *(float4*)&w[4] = *(const float4*)&w1_root[k*H1D + jb + 4];
      #pragma unroll
      for (int i = 0; i < 4; ++i) a[i] = X[(rg*4 + i)*65 + k];
      #pragma unroll
      for (int i = 0; i < 4; ++i)
        #pragma unroll
        for (int j = 0; j < 8; ++j) acc[i][j] += a[i]*w[j];
    }
    float dw[4];
    #pragma unroll
    for (int i = 0; i < 4; ++i) dw[i] = degout[rg*4 + i];
    #pragma unroll
    for (int j = 0; j < 8; ++j) {
      float bb = b1[jb + j];
      float h0 = fmaxf(acc[0][j] + bb, 0.f);
      float h1v = fmaxf(acc[1][j] + bb, 0.f);
      float h2 = fmaxf(acc[2][j] + bb, 0.f);
      float h3 = fmaxf(acc[3][j] + bb, 0.f);
      atomicAdd(&hsum[jb + j], h0 + h1v + h2 + h3);
      atomicAdd(&wsum[jb + j], dw[0]*h0 + dw[1]*h1v + dw[2]*h2 + dw[3]*h3);
    }
  }
  __syncthreads();

  // ---- phase 3: four 128x64 vec-mats (one wave each, no divergence) ----
  {
    const int q = tid >> 6;        // 0:mu-rel 1:mu-root 2:lv-rel 3:lv-root
    const int j = tid & 63;
    const float* W = (q == 0) ? w2_rel : (q == 1) ? w2_root : (q == 2) ? w3_rel : w3_root;
    const float* V = (q == 1 || q == 3) ? hsum : wsum;
    float s = 0.f;
    #pragma unroll 4
    for (int k = 0; k < H1D; ++k) s += V[k] * W[k*H2D + j];
    part[q*64 + j] = s;
  }
  __syncthreads();

  if (tid < 64) {
    float mu = (part[tid]       + part[64 + tid])  * (1.f/64.f) + b2[tid];
    float lv = (part[128 + tid] + part[192 + tid]) * (1.f/64.f) + b3[tid];
    out_mu[(size_t)g*64 + tid] = mu;
    out_lv[(size_t)g*64 + tid] = lv;
    zrow[tid] = mu + eps[(size_t)g*64 + tid] * __expf(0.5f*lv);
  }
  __syncthreads();

  // ---- fc1 fused: h = relu(z @ fc1_w + fc1_b) -> hbuf[g][128] ----
  if (tid < 128) {
    float s = fc1_b[tid];
    #pragma unroll 4
    for (int k = 0; k < H2D; ++k) s += zrow[k] * fc1_w[k*H1D + tid];
    hbuf[(size_t)g*H1D + tid] = fmaxf(s, 0.f);
  }
}

// ---------------- Kernel 2: decoder GEMM  recon = sigmoid(h @ fc2_w + fc2_b) ----------------
// grid = (32 row-tiles of 64, 18 col-chunks of 112), block = 256
__global__ __launch_bounds__(256, 4) void k2_decoder(
    const float* __restrict__ hbuf, const float* __restrict__ fc2_w,
    const float* __restrict__ fc2_b, float* __restrict__ recon)
{
  __shared__ float sh[64*129];
  const int bg  = blockIdx.x;
  const int cc  = blockIdx.y;
  const int tid = threadIdx.x;

  const float* hg = hbuf + (size_t)bg*64*H1D;
  for (int i = tid; i < (64*H1D)/4; i += 256) {
    float4 v = ((const float4*)hg)[i];
    int n = i >> 5, k = (i & 31)*4;
    float* p = &sh[n*129 + k];
    p[0]=v.x; p[1]=v.y; p[2]=v.z; p[3]=v.w;
  }
  __syncthreads();

  const int r  = tid >> 2;                       // 64 rows
  const int c0 = cc*112 + (tid & 3)*28;          // 28 cols/thread
  float acc[28];
  #pragma unroll
  for (int q = 0; q < 28; ++q) acc[q] = 0.f;

  for (int k = 0; k < H1D; ++k) {
    float a = sh[r*129 + k];
    const float* wrow = &fc2_w[(size_t)k*OUTD + c0];
    #pragma unroll
    for (int q = 0; q < 7; ++q) {
      float4 w = *(const float4*)&wrow[q*4];
      acc[q*4+0] += a*w.x; acc[q*4+1] += a*w.y;
      acc[q*4+2] += a*w.z; acc[q*4+3] += a*w.w;
    }
  }
  float* outr = recon + ((size_t)(bg*64 + r))*OUTD + c0;
  #pragma unroll
  for (int q = 0; q < 7; ++q) {
    float4 o;
    float v0 = acc[q*4+0] + fc2_b[c0 + q*4+0];
    float v1 = acc[q*4+1] + fc2_b[c0 + q*4+1];
    float v2 = acc[q*4+2] + fc2_b[c0 + q*4+2];
    float v3 = acc[q*4+3] + fc2_b[c0 + q*4+3];
    o.x = 1.f/(1.f + __expf(-v0));
    o.y = 1.f/(1.f + __expf(-v1));
    o.z = 1.f/(1.f + __expf(-v2));
    o.w = 1.f/(1.f + __expf(-v3));
    *(float4*)&outr[q*4] = o;
  }
}

extern "C" void kernel_launch(void* const* d_in, const int* in_sizes, int n_in,
                              void* d_out, int out_size, void* d_ws, size_t ws_size,
                              hipStream_t stream) {
  const float* x       = (const float*)d_in[0];
  const int*   ei      = (const int*)d_in[1];
  // d_in[2] = batch — implicit (64 nodes/graph), unused
  const float* eps     = (const float*)d_in[3];
  const float* w1_rel  = (const float*)d_in[4];
  const float* b1      = (const float*)d_in[5];
  const float* w1_root = (const float*)d_in[6];
  const float* w2_rel  = (const float*)d_in[7];
  const float* b2      = (const float*)d_in[8];
  const float* w2_root = (const float*)d_in[9];
  const float* w3_rel  = (const float*)d_in[10];
  const float* b3      = (const float*)d_in[11];
  const float* w3_root = (const float*)d_in[12];
  const float* fc1_w   = (const float*)d_in[13];
  const float* fc1_b   = (const float*)d_in[14];
  const float* fc2_w   = (const float*)d_in[15];
  const float* fc2_b   = (const float*)d_in[16];

  float* recon  = (float*)d_out;             // [2048][2016]
  float* out_mu = recon + (size_t)NG*OUTD;   // [2048][64]
  float* out_lv = out_mu + (size_t)NG*H2D;   // [2048][64]
  float* hbuf   = (float*)d_ws;              // [2048][128] fc1 activations

  k1_encoder<<<NG, 256, 0, stream>>>(x, ei, eps,
      w1_rel, b1, w1_root, w2_rel, b2, w2_root, w3_rel, b3, w3_root,
      fc1_w, fc1_b, out_mu, out_lv, hbuf);
  k2_decoder<<<dim3(32, 18), 256, 0, stream>>>(hbuf, fc2_w, fc2_b, recon);
}

// Round 3
// 193.601 us; speedup vs baseline: 7.9144x; 2.1574x over previous
//
#include <hip/hip_runtime.h>
#include <math.h>

#define NG 2048
#define NPG 64
#define EPG 512
#define ETOT (NG*EPG)
#define IND 64
#define H1D 128
#define H2D 64
#define OUTD 2016

typedef __attribute__((ext_vector_type(8))) short bf16x8;
typedef __attribute__((ext_vector_type(4))) float f32x4;

__device__ inline short f2b(float f) {
  union { float f; unsigned u; } v; v.f = f;
  unsigned r = (v.u + 0x7FFFu + ((v.u >> 16) & 1u)) >> 16;
  return (short)r;
}

// ---- pre-kernel: W1 combined -> B-frag layout WTg[col 0..127][k 0..127], pitch 136 bf16
// k<64: w1_rel[k][col]; k>=64: w1_root[k-64][col]
__global__ void p_w1(const float* __restrict__ w1_rel, const float* __restrict__ w1_root,
                     short* __restrict__ WTg) {
  const int k = blockIdx.x;      // 0..63
  const int c = threadIdx.x;     // 0..127
  WTg[c*136 + k]      = f2b(w1_rel[k*H1D + c]);
  WTg[c*136 + 64 + k] = f2b(w1_root[k*H1D + c]);
}

// ---- pre-kernel: fc2_w [128][2016] -> WT2g[col][k] pitch 136 bf16
__global__ void p_fc2(const float* __restrict__ fc2_w, short* __restrict__ WT2g) {
  const int k = blockIdx.x;          // 0..127
  const int t = threadIdx.x;         // 0..255, use 252
  if (t < 252) {
    const int c0 = t*8;
    float4 a = *(const float4*)&fc2_w[(size_t)k*OUTD + c0];
    float4 b = *(const float4*)&fc2_w[(size_t)k*OUTD + c0 + 4];
    WT2g[(c0+0)*136 + k] = f2b(a.x); WT2g[(c0+1)*136 + k] = f2b(a.y);
    WT2g[(c0+2)*136 + k] = f2b(a.z); WT2g[(c0+3)*136 + k] = f2b(a.w);
    WT2g[(c0+4)*136 + k] = f2b(b.x); WT2g[(c0+5)*136 + k] = f2b(b.y);
    WT2g[(c0+6)*136 + k] = f2b(b.z); WT2g[(c0+7)*136 + k] = f2b(b.w);
  }
}

// ---------------- Kernel 1: per-graph MFMA encoder ----------------
// LDS carve (81664 B total -> 2 blocks/CU):
//  Xb   [64][72] bf16  @0      (A-operand row-major, nodes x feat)
//  XbT  [64][72] bf16  @9216   (B-operand: feat x nodes, for phase1)
//  Ab   [64][72] bf16  @18432  (adjacency bf16)
//  Af   [64][66] f32   @27648  (adjacency fp32 for atomics; AGb aliases after cvt)
//  AGb  [64][72] bf16  @27648  (alias of Af)
//  WTl  [128][136] bf16 @44544 (combined W1, B-frag layout)
//  deg  [64] f32 @79360; hsum[128] @79616; wsum[128] @80128; part[256] @80640
__global__ __launch_bounds__(256, 2) void k1_encoder(
    const float* __restrict__ x, const int* __restrict__ ei,
    const float* __restrict__ eps, const short* __restrict__ WTg,
    const float* __restrict__ b1,
    const float* __restrict__ w2_rel, const float* __restrict__ b2, const float* __restrict__ w2_root,
    const float* __restrict__ w3_rel, const float* __restrict__ b3, const float* __restrict__ w3_root,
    const float* __restrict__ fc1_w, const float* __restrict__ fc1_b,
    float* __restrict__ out_mu, float* __restrict__ out_lv, short* __restrict__ hbufB)
{
  __shared__ __align__(16) unsigned char smem[81664];
  short* Xb   = (short*)smem;
  short* XbT  = (short*)(smem + 9216);
  short* Ab   = (short*)(smem + 18432);
  float* Af   = (float*)(smem + 27648);
  short* AGb  = (short*)(smem + 27648);   // alias (valid after cvt)
  short* WTl  = (short*)(smem + 44544);
  float* deg  = (float*)(smem + 79360);
  float* hsum = (float*)(smem + 79616);
  float* wsum = (float*)(smem + 80128);
  float* part = (float*)(smem + 80640);   // also reused as zrow[0..63]

  const int g = blockIdx.x;
  const int tid = threadIdx.x;
  const int w = tid >> 6, l = tid & 63;

  // ---- zero fp32 accumulators ----
  for (int i = tid; i < 64*66; i += 256) Af[i] = 0.f;
  if (tid < 64) deg[tid] = 0.f;
  if (tid < 128) { hsum[tid] = 0.f; wsum[tid] = 0.f; }
  __syncthreads();

  // ---- edge atomics (scalar, into fp32 adjacency) ----
  {
    const int e0 = g*EPG + tid*2;
    const int s0 = ei[e0] & 63,     d0 = ei[ETOT + e0] & 63;
    const int s1 = ei[e0 + 1] & 63, d1 = ei[ETOT + e0 + 1] & 63;
    atomicAdd(&Af[d0*66 + s0], 1.f);
    atomicAdd(&Af[d1*66 + s1], 1.f);
    atomicAdd(&deg[s0], 1.f);
    atomicAdd(&deg[s1], 1.f);
  }

  // ---- stage Xb (row-major bf16) + XbT (transposed bf16) ----
  {
    const int n = tid >> 2, f0 = (tid & 3) * 16;
    const float* xr = x + (size_t)g*(NPG*IND) + n*IND + f0;
    float4 v0 = *(const float4*)&xr[0];
    float4 v1 = *(const float4*)&xr[4];
    float4 v2 = *(const float4*)&xr[8];
    float4 v3 = *(const float4*)&xr[12];
    short b[16];
    b[0]=f2b(v0.x); b[1]=f2b(v0.y); b[2]=f2b(v0.z); b[3]=f2b(v0.w);
    b[4]=f2b(v1.x); b[5]=f2b(v1.y); b[6]=f2b(v1.z); b[7]=f2b(v1.w);
    b[8]=f2b(v2.x); b[9]=f2b(v2.y); b[10]=f2b(v2.z); b[11]=f2b(v2.w);
    b[12]=f2b(v3.x); b[13]=f2b(v3.y); b[14]=f2b(v3.z); b[15]=f2b(v3.w);
    short* xbp = &Xb[n*72 + f0];
    #pragma unroll
    for (int j = 0; j < 16; ++j) xbp[j] = b[j];
    #pragma unroll
    for (int j = 0; j < 16; ++j) XbT[(f0 + j)*72 + n] = b[j];
  }

  // ---- stage WTl (flat copy, 34816 B) ----
  {
    const uint4* src = (const uint4*)WTg;
    uint4* dst = (uint4*)WTl;
    for (int i = tid; i < 2176; i += 256) dst[i] = src[i];
  }
  __syncthreads();

  // ---- cvt adjacency fp32 -> bf16 ----
  for (int i = tid; i < 4096; i += 256) {
    int n = i >> 6, s = i & 63;
    Ab[n*72 + s] = f2b(Af[n*66 + s]);
  }
  __syncthreads();

  const int rm = w*16;
  const int fr = l & 15;          // frag row/col within tile
  const int koff = (l >> 4) * 8;  // frag k offset

  // ---- phase 1: AG = A @ X  (M=64,N=64,K=64), wave strip of 16 rows ----
  {
    f32x4 agc[4];
    #pragma unroll
    for (int t = 0; t < 4; ++t) agc[t] = (f32x4){0.f,0.f,0.f,0.f};
    #pragma unroll
    for (int ks = 0; ks < 2; ++ks) {
      bf16x8 a = *(const bf16x8*)&Ab[(rm + fr)*72 + ks*32 + koff];
      #pragma unroll
      for (int t = 0; t < 4; ++t) {
        bf16x8 b = *(const bf16x8*)&XbT[(t*16 + fr)*72 + ks*32 + koff];
        agc[t] = __builtin_amdgcn_mfma_f32_16x16x32_bf16(a, b, agc[t], 0, 0, 0);
      }
    }
    __syncthreads();   // Af fully dead (cvt done by all) before AGb overwrite
    #pragma unroll
    for (int t = 0; t < 4; ++t)
      #pragma unroll
      for (int r = 0; r < 4; ++r)
        AGb[(rm + (l>>4)*4 + r)*72 + t*16 + fr] = f2b(agc[t][r]);
  }
  __syncthreads();

  // ---- phase 2: h1pre = [AG | X] @ WTl  (M=64,N=128,K=128); reduce from frags ----
  {
    float dg[4];
    #pragma unroll
    for (int r = 0; r < 4; ++r) dg[r] = deg[rm + (l>>4)*4 + r];

    f32x4 acc[8];
    #pragma unroll
    for (int t = 0; t < 8; ++t) acc[t] = (f32x4){0.f,0.f,0.f,0.f};
    #pragma unroll
    for (int ks = 0; ks < 4; ++ks) {
      bf16x8 a = (ks < 2)
        ? *(const bf16x8*)&AGb[(rm + fr)*72 + ks*32 + koff]
        : *(const bf16x8*)&Xb[(rm + fr)*72 + (ks-2)*32 + koff];
      #pragma unroll
      for (int t = 0; t < 8; ++t) {
        bf16x8 b = *(const bf16x8*)&WTl[(t*16 + fr)*136 + ks*32 + koff];
        acc[t] = __builtin_amdgcn_mfma_f32_16x16x32_bf16(a, b, acc[t], 0, 0, 0);
      }
    }
    #pragma unroll
    for (int t = 0; t < 8; ++t) {
      const int col = t*16 + fr;
      const float bb = b1[col];
      float hs = 0.f, ws = 0.f;
      #pragma unroll
      for (int r = 0; r < 4; ++r) {
        float v = fmaxf(acc[t][r] + bb, 0.f);
        hs += v; ws += dg[r]*v;
      }
      hs += __shfl_down(hs, 32); ws += __shfl_down(ws, 32);
      hs += __shfl_down(hs, 16); ws += __shfl_down(ws, 16);
      if (l < 16) { atomicAdd(&hsum[col], hs); atomicAdd(&wsum[col], ws); }
    }
  }
  __syncthreads();

  // ---- phase 3: four 128x64 vec-mats (fp32) ----
  {
    const int q = tid >> 6, j = tid & 63;
    const float* W = (q == 0) ? w2_rel : (q == 1) ? w2_root : (q == 2) ? w3_rel : w3_root;
    const float* V = (q == 1 || q == 3) ? hsum : wsum;
    float s = 0.f;
    #pragma unroll 4
    for (int k = 0; k < H1D; ++k) s += V[k] * W[k*H2D + j];
    part[q*64 + j] = s;
  }
  __syncthreads();

  if (tid < 64) {
    float mu = (part[tid]       + part[64 + tid])  * (1.f/64.f) + b2[tid];
    float lv = (part[128 + tid] + part[192 + tid]) * (1.f/64.f) + b3[tid];
    out_mu[(size_t)g*64 + tid] = mu;
    out_lv[(size_t)g*64 + tid] = lv;
    part[tid] = mu + eps[(size_t)g*64 + tid] * __expf(0.5f*lv);  // zrow
  }
  __syncthreads();

  // ---- fc1: h = relu(z @ fc1_w + fc1_b) -> hbufB bf16 [g][128] ----
  if (tid < 128) {
    float s = fc1_b[tid];
    #pragma unroll 4
    for (int k = 0; k < H2D; ++k) s += part[k] * fc1_w[k*H1D + tid];
    hbufB[(size_t)g*H1D + tid] = f2b(fmaxf(s, 0.f));
  }
}

// ---------------- Kernel 2: MFMA decoder GEMM ----------------
// C[2048,2016] = sigmoid(H[2048,128] @ fc2_w[128,2016] + b)
// grid (64, 21): 32-row x 96-col tiles; block 256 = 4 waves
__global__ __launch_bounds__(256, 4) void k2_decoder(
    const short* __restrict__ hbufB, const short* __restrict__ WT2g,
    const float* __restrict__ fc2_b, float* __restrict__ recon)
{
  __shared__ __align__(16) short Hb[32*136];
  __shared__ __align__(16) short Wt[96*136];
  const int bx = blockIdx.x, by = blockIdx.y;
  const int tid = threadIdx.x;
  const int w = tid >> 6, l = tid & 63;

  // stage H tile (32 rows x 128 k, bf16, repitch 128->136)
  {
    const uint4* src = (const uint4*)(hbufB + (size_t)bx*32*H1D);
    for (int i = tid; i < 512; i += 256) {
      int r = i >> 4, k0 = (i & 15) * 8;
      *(uint4*)&Hb[r*136 + k0] = src[i];
    }
  }
  // stage W tile (96 cols x 128 k): flat copy, same pitch
  {
    const uint4* src = (const uint4*)(WT2g + (size_t)by*96*136);
    uint4* dst = (uint4*)Wt;
    for (int i = tid; i < 1632; i += 256) dst[i] = src[i];
  }
  __syncthreads();

  const int s = w >> 1;        // row strip (16 rows)
  const int h = w & 1;         // col half (48 cols)
  const int fr = l & 15;
  const int koff = (l >> 4) * 8;

  f32x4 acc[3];
  #pragma unroll
  for (int t = 0; t < 3; ++t) acc[t] = (f32x4){0.f,0.f,0.f,0.f};

  #pragma unroll
  for (int ks = 0; ks < 4; ++ks) {
    bf16x8 a = *(const bf16x8*)&Hb[(s*16 + fr)*136 + ks*32 + koff];
    #pragma unroll
    for (int t = 0; t < 3; ++t) {
      bf16x8 b = *(const bf16x8*)&Wt[(h*48 + t*16 + fr)*136 + ks*32 + koff];
      acc[t] = __builtin_amdgcn_mfma_f32_16x16x32_bf16(a, b, acc[t], 0, 0, 0);
    }
  }

  #pragma unroll
  for (int t = 0; t < 3; ++t) {
    const int col = by*96 + h*48 + t*16 + fr;
    const float bb = fc2_b[col];
    #pragma unroll
    for (int r = 0; r < 4; ++r) {
      const int row = bx*32 + s*16 + (l>>4)*4 + r;
      float v = acc[t][r] + bb;
      recon[(size_t)row*OUTD + col] = 1.f/(1.f + __expf(-v));
    }
  }
}

extern "C" void kernel_launch(void* const* d_in, const int* in_sizes, int n_in,
                              void* d_out, int out_size, void* d_ws, size_t ws_size,
                              hipStream_t stream) {
  const float* x       = (const float*)d_in[0];
  const int*   ei      = (const int*)d_in[1];
  const float* eps     = (const float*)d_in[3];
  const float* w1_rel  = (const float*)d_in[4];
  const float* b1      = (const float*)d_in[5];
  const float* w1_root = (const float*)d_in[6];
  const float* w2_rel  = (const float*)d_in[7];
  const float* b2      = (const float*)d_in[8];
  const float* w2_root = (const float*)d_in[9];
  const float* w3_rel  = (const float*)d_in[10];
  const float* b3      = (const float*)d_in[11];
  const float* w3_root = (const float*)d_in[12];
  const float* fc1_w   = (const float*)d_in[13];
  const float* fc1_b   = (const float*)d_in[14];
  const float* fc2_w   = (const float*)d_in[15];
  const float* fc2_b   = (const float*)d_in[16];

  float* recon  = (float*)d_out;
  float* out_mu = recon + (size_t)NG*OUTD;
  float* out_lv = out_mu + (size_t)NG*H2D;

  // workspace carve
  short* WTg   = (short*)d_ws;                              // 128*136*2 = 34816 B
  short* WT2g  = (short*)((char*)d_ws + 34816);             // 2016*136*2 = 548352 B
  short* hbufB = (short*)((char*)d_ws + 34816 + 548352);    // 2048*128*2 = 524288 B

  p_w1 <<<64, 128, 0, stream>>>(w1_rel, w1_root, WTg);
  p_fc2<<<128, 256, 0, stream>>>(fc2_w, WT2g);
  k1_encoder<<<NG, 256, 0, stream>>>(x, ei, eps, WTg, b1,
      w2_rel, b2, w2_root, w3_rel, b3, w3_root,
      fc1_w, fc1_b, out_mu, out_lv, hbufB);
  k2_decoder<<<dim3(64, 21), 256, 0, stream>>>(hbufB, WT2g, fc2_b, recon);
}

// Round 4
// 170.027 us; speedup vs baseline: 9.0117x; 1.1386x over previous
//
#include <hip/hip_runtime.h>
#include <math.h>

#define NG 2048
#define NPG 64
#define EPG 512
#define ETOT (NG*EPG)
#define IND 64
#define H1D 128
#define H2D 64
#define OUTD 2016

typedef __attribute__((ext_vector_type(8))) short bf16x8;
typedef __attribute__((ext_vector_type(4))) float f32x4;

__device__ inline short f2b(float f) {
  union { float f; unsigned u; } v; v.f = f;
  unsigned r = (v.u + 0x7FFFu + ((v.u >> 16) & 1u)) >> 16;
  return (short)r;
}

// ================= unified pre-kernel: all weight transposes (coalesced) ==========
// bid <63 : fc2_w [128][2016] -> WT2g[col][k] pitch 136   (32 cols/block)
// bid 63-66: w2/w3 stacked     -> W23T[col][k] pitch 264   (K=256: rel|root; cols 0..63 w2, 64..127 w3)
// bid 67-68: fc1_w [64][128]   -> fc1T[col][k] pitch 72    (64 cols/block)
// bid 69-70: w1_rel|w1_root    -> WTg [col][k] pitch 136   (K=128; 64 cols/block)
__global__ __launch_bounds__(256) void p_pre(
    const float* __restrict__ fc2_w, const float* __restrict__ w2_rel, const float* __restrict__ w2_root,
    const float* __restrict__ w3_rel, const float* __restrict__ w3_root,
    const float* __restrict__ fc1_w, const float* __restrict__ w1_rel, const float* __restrict__ w1_root,
    short* __restrict__ WT2g, short* __restrict__ W23T, short* __restrict__ fc1T, short* __restrict__ WTg)
{
  __shared__ float L[8448];   // 33792 B
  const int bid = blockIdx.x, t = threadIdx.x;

  if (bid < 63) {                       // ---- fc2 ----
    const int c0 = bid*32;
    for (int i = t; i < 4096; i += 256) {
      int k = i >> 5, c = i & 31;
      L[k*33 + c] = fc2_w[(size_t)k*OUTD + c0 + c];
    }
    __syncthreads();
    const int c = t >> 3, k0 = (t & 7)*16;
    for (int kk = 0; kk < 16; ++kk)
      WT2g[(size_t)(c0 + c)*136 + k0 + kk] = f2b(L[(k0 + kk)*33 + c]);
  } else if (bid < 67) {                // ---- w2/w3 ----
    const int cc = bid - 63;            // 0..3
    const int j0 = cc*32;
    const float* wrel  = (cc < 2) ? w2_rel  : w3_rel;
    const float* wroot = (cc < 2) ? w2_root : w3_root;
    const int jl = j0 & 63;
    for (int i = t; i < 4096; i += 256) {
      int k = i >> 5, c = i & 31;
      L[k*33 + c]        = wrel [k*H2D + jl + c];
      L[4224 + k*33 + c] = wroot[k*H2D + jl + c];
    }
    __syncthreads();
    const int c = t >> 3, k0 = (t & 7)*32;
    for (int kk = 0; kk < 32; ++kk) {
      int k = k0 + kk;
      float v = (k < 128) ? L[k*33 + c] : L[4224 + (k - 128)*33 + c];
      W23T[(size_t)(j0 + c)*264 + k] = f2b(v);
    }
  } else if (bid < 69) {                // ---- fc1 ----
    const int c0 = (bid - 67)*64;
    for (int i = t; i < 4096; i += 256) {
      int k = i >> 6, c = i & 63;
      L[k*65 + c] = fc1_w[k*H1D + c0 + c];
    }
    __syncthreads();
    const int c = t >> 2, k0 = (t & 3)*16;
    for (int kk = 0; kk < 16; ++kk)
      fc1T[(size_t)(c0 + c)*72 + k0 + kk] = f2b(L[(k0 + kk)*65 + c]);
  } else {                              // ---- w1 ----
    const int c0 = (bid - 69)*64;
    for (int i = t; i < 4096; i += 256) {
      int k = i >> 6, c = i & 63;
      L[k*65 + c]        = w1_rel [k*H1D + c0 + c];
      L[4160 + k*65 + c] = w1_root[k*H1D + c0 + c];
    }
    __syncthreads();
    const int c = t >> 2, k0 = (t & 3)*32;
    for (int kk = 0; kk < 32; ++kk) {
      int k = k0 + kk;
      float v = (k < 64) ? L[k*65 + c] : L[4160 + (k - 64)*65 + c];
      WTg[(size_t)(c0 + c)*136 + k] = f2b(v);
    }
  }
}

// ================= Kernel 1: per-graph adjacency + conv1 + reductions ==========
// Output per graph: SVg[g][0..127]=wsum (deg-weighted h1 colsum), [128..255]=hsum.
// LDS = 45824 B -> 3 blocks/CU. W1 B-frags read straight from L2-hot global.
__global__ __launch_bounds__(256, 3) void k1_encoder(
    const float* __restrict__ x, const int* __restrict__ ei,
    const short* __restrict__ WTg, const float* __restrict__ b1,
    short* __restrict__ SVg)
{
  __shared__ short Xb [64*72];
  __shared__ short XbT[64*72];
  __shared__ short Ab [64*72];
  __shared__ float Af [64*66];
  __shared__ float deg[64];
  __shared__ float hsum[128];
  __shared__ float wsum[128];
  short* AGb = (short*)Af;   // alias: valid after cvt+deg consume Af

  const int g = blockIdx.x;
  const int tid = threadIdx.x;
  const int w = tid >> 6, l = tid & 63;

  // hoist edge loads (HBM latency overlaps the zeroing below)
  const int e0 = g*EPG + tid*2;
  const int s0 = ei[e0] & 63,     d0 = ei[ETOT + e0] & 63;
  const int s1 = ei[e0 + 1] & 63, d1 = ei[ETOT + e0 + 1] & 63;

  for (int i = tid; i < 64*66; i += 256) Af[i] = 0.f;
  if (tid < 128) { hsum[tid] = 0.f; wsum[tid] = 0.f; }

  // stage Xb (row-major) + XbT (transposed)
  {
    const int n = tid >> 2, f0 = (tid & 3) * 16;
    const float* xr = x + (size_t)g*(NPG*IND) + n*IND + f0;
    float4 v0 = *(const float4*)&xr[0];
    float4 v1 = *(const float4*)&xr[4];
    float4 v2 = *(const float4*)&xr[8];
    float4 v3 = *(const float4*)&xr[12];
    short b[16];
    b[0]=f2b(v0.x); b[1]=f2b(v0.y); b[2]=f2b(v0.z); b[3]=f2b(v0.w);
    b[4]=f2b(v1.x); b[5]=f2b(v1.y); b[6]=f2b(v1.z); b[7]=f2b(v1.w);
    b[8]=f2b(v2.x); b[9]=f2b(v2.y); b[10]=f2b(v2.z); b[11]=f2b(v2.w);
    b[12]=f2b(v3.x); b[13]=f2b(v3.y); b[14]=f2b(v3.z); b[15]=f2b(v3.w);
    short* xbp = &Xb[n*72 + f0];
    #pragma unroll
    for (int j = 0; j < 16; ++j) xbp[j] = b[j];
    #pragma unroll
    for (int j = 0; j < 16; ++j) XbT[(f0 + j)*72 + n] = b[j];
  }
  __syncthreads();

  // adjacency atomics (512 scalar adds)
  atomicAdd(&Af[d0*66 + s0], 1.f);
  atomicAdd(&Af[d1*66 + s1], 1.f);
  __syncthreads();

  // cvt A -> bf16; deg = column sums (conflict-free, replaces 1024 hot atomics)
  for (int i = tid; i < 4096; i += 256) {
    int n = i >> 6, s = i & 63;
    Ab[n*72 + s] = f2b(Af[n*66 + s]);
  }
  if (tid < 64) {
    float s = 0.f;
    #pragma unroll 8
    for (int d = 0; d < 64; ++d) s += Af[d*66 + tid];
    deg[tid] = s;
  }
  __syncthreads();

  const int rm = w*16;
  const int fr = l & 15;
  const int koff = (l >> 4) * 8;

  // phase 1: AG = A @ X  (M=64,N=64,K=64)
  {
    f32x4 agc[4];
    #pragma unroll
    for (int t = 0; t < 4; ++t) agc[t] = (f32x4){0.f,0.f,0.f,0.f};
    #pragma unroll
    for (int ks = 0; ks < 2; ++ks) {
      bf16x8 a = *(const bf16x8*)&Ab[(rm + fr)*72 + ks*32 + koff];
      #pragma unroll
      for (int t = 0; t < 4; ++t) {
        bf16x8 b = *(const bf16x8*)&XbT[(t*16 + fr)*72 + ks*32 + koff];
        agc[t] = __builtin_amdgcn_mfma_f32_16x16x32_bf16(a, b, agc[t], 0, 0, 0);
      }
    }
    // Af is dead (cvt+deg done before last barrier) -> safe to overwrite alias
    #pragma unroll
    for (int t = 0; t < 4; ++t)
      #pragma unroll
      for (int r = 0; r < 4; ++r)
        AGb[(rm + (l>>4)*4 + r)*72 + t*16 + fr] = f2b(agc[t][r]);
  }
  __syncthreads();

  // phase 2: h1pre = [AG|X] @ W1 (M=64,N=128,K=128), B-frags from global (L2-hot)
  {
    float dg[4];
    #pragma unroll
    for (int r = 0; r < 4; ++r) dg[r] = deg[rm + (l>>4)*4 + r];

    f32x4 acc[8];
    #pragma unroll
    for (int t = 0; t < 8; ++t) acc[t] = (f32x4){0.f,0.f,0.f,0.f};
    #pragma unroll
    for (int ks = 0; ks < 4; ++ks) {
      bf16x8 a = (ks < 2)
        ? *(const bf16x8*)&AGb[(rm + fr)*72 + ks*32 + koff]
        : *(const bf16x8*)&Xb[(rm + fr)*72 + (ks-2)*32 + koff];
      #pragma unroll
      for (int t = 0; t < 8; ++t) {
        bf16x8 b = *(const bf16x8*)&WTg[(t*16 + fr)*136 + ks*32 + koff];
        acc[t] = __builtin_amdgcn_mfma_f32_16x16x32_bf16(a, b, acc[t], 0, 0, 0);
      }
    }
    #pragma unroll
    for (int t = 0; t < 8; ++t) {
      const int col = t*16 + fr;
      const float bb = b1[col];
      float hs = 0.f, ws = 0.f;
      #pragma unroll
      for (int r = 0; r < 4; ++r) {
        float v = fmaxf(acc[t][r] + bb, 0.f);
        hs += v; ws += dg[r]*v;
      }
      hs += __shfl_down(hs, 32); ws += __shfl_down(ws, 32);
      hs += __shfl_down(hs, 16); ws += __shfl_down(ws, 16);
      if (l < 16) { atomicAdd(&hsum[col], hs); atomicAdd(&wsum[col], ws); }
    }
  }
  __syncthreads();

  if (tid < 128) {
    SVg[(size_t)g*256 + tid]       = f2b(wsum[tid]);
    SVg[(size_t)g*256 + 128 + tid] = f2b(hsum[tid]);
  }
}

// ================= Kernel 1b: batched conv2/3-mean + reparam + fc1 ==========
// grid 64 blocks x 32 graphs. GEMM1: SV[32x256] @ W23T -> mu|lv (128 cols);
// reparam in-register; GEMM2: Z[32x64] @ fc1T -> h (128 cols) -> hbufB bf16.
__global__ __launch_bounds__(256) void k1b_latent(
    const short* __restrict__ SVg, const short* __restrict__ W23T,
    const float* __restrict__ b2, const float* __restrict__ b3,
    const float* __restrict__ eps, const short* __restrict__ fc1T,
    const float* __restrict__ fc1_b,
    float* __restrict__ out_mu, float* __restrict__ out_lv, short* __restrict__ hbufB)
{
  __shared__ short SV[32*264];   // 16896 B
  __shared__ short Zt[32*72];    // 4608 B
  const int g0 = blockIdx.x * 32;
  const int tid = threadIdx.x;
  const int w = tid >> 6, l = tid & 63;
  const int s = w >> 1;          // row strip (16 rows)
  const int h = w & 1;           // half
  const int fr = l & 15;
  const int koff = (l >> 4) * 8;

  // stage SV tile (repitch 256 -> 264)
  {
    const uint4* src = (const uint4*)(SVg + (size_t)g0*256);
    for (int i = tid; i < 1024; i += 256) {
      int r = i >> 5, k0 = (i & 31) * 8;
      *(uint4*)&SV[r*264 + k0] = src[i];
    }
  }
  __syncthreads();

  // GEMM1: wave handles mu tiles {2h,2h+1} and lv tiles {2h+4,2h+5}, rows strip s
  f32x4 acc[4];
  #pragma unroll
  for (int t = 0; t < 4; ++t) acc[t] = (f32x4){0.f,0.f,0.f,0.f};
  #pragma unroll
  for (int ks = 0; ks < 8; ++ks) {
    bf16x8 a = *(const bf16x8*)&SV[(s*16 + fr)*264 + ks*32 + koff];
    #pragma unroll
    for (int j = 0; j < 2; ++j) {
      bf16x8 bm = *(const bf16x8*)&W23T[((2*h + j)*16 + fr)*264 + ks*32 + koff];
      bf16x8 bl = *(const bf16x8*)&W23T[((2*h + j + 4)*16 + fr)*264 + ks*32 + koff];
      acc[j]     = __builtin_amdgcn_mfma_f32_16x16x32_bf16(a, bm, acc[j], 0, 0, 0);
      acc[2 + j] = __builtin_amdgcn_mfma_f32_16x16x32_bf16(a, bl, acc[2 + j], 0, 0, 0);
    }
  }
  #pragma unroll
  for (int j = 0; j < 2; ++j) {
    const int col = (2*h + j)*16 + fr;     // 0..63
    const float bb2 = b2[col], bb3 = b3[col];
    #pragma unroll
    for (int r = 0; r < 4; ++r) {
      const int row = s*16 + (l>>4)*4 + r;
      const size_t gg = (size_t)(g0 + row);
      float mu = acc[j][r]     * (1.f/64.f) + bb2;
      float lv = acc[2 + j][r] * (1.f/64.f) + bb3;
      out_mu[gg*64 + col] = mu;
      out_lv[gg*64 + col] = lv;
      float z = mu + eps[gg*64 + col] * __expf(0.5f*lv);
      Zt[row*72 + col] = f2b(z);
    }
  }
  __syncthreads();

  // GEMM2: h = relu(Z @ fc1 + b), wave: 4 col tiles (h*4+j), rows strip s
  f32x4 hacc[4];
  #pragma unroll
  for (int t = 0; t < 4; ++t) hacc[t] = (f32x4){0.f,0.f,0.f,0.f};
  #pragma unroll
  for (int ks = 0; ks < 2; ++ks) {
    bf16x8 a = *(const bf16x8*)&Zt[(s*16 + fr)*72 + ks*32 + koff];
    #pragma unroll
    for (int j = 0; j < 4; ++j) {
      bf16x8 b = *(const bf16x8*)&fc1T[((h*4 + j)*16 + fr)*72 + ks*32 + koff];
      hacc[j] = __builtin_amdgcn_mfma_f32_16x16x32_bf16(a, b, hacc[j], 0, 0, 0);
    }
  }
  #pragma unroll
  for (int j = 0; j < 4; ++j) {
    const int col = (h*4 + j)*16 + fr;
    const float bb = fc1_b[col];
    #pragma unroll
    for (int r = 0; r < 4; ++r) {
      const int row = s*16 + (l>>4)*4 + r;
      hbufB[(size_t)(g0 + row)*H1D + col] = f2b(fmaxf(hacc[j][r] + bb, 0.f));
    }
  }
}

// ================= Kernel 2: decoder GEMM ==========
__global__ __launch_bounds__(256, 4) void k2_decoder(
    const short* __restrict__ hbufB, const short* __restrict__ WT2g,
    const float* __restrict__ fc2_b, float* __restrict__ recon)
{
  __shared__ __align__(16) short Hb[32*136];
  __shared__ __align__(16) short Wt[96*136];
  const int bx = blockIdx.x, by = blockIdx.y;
  const int tid = threadIdx.x;
  const int w = tid >> 6, l = tid & 63;

  {
    const uint4* src = (const uint4*)(hbufB + (size_t)bx*32*H1D);
    for (int i = tid; i < 512; i += 256) {
      int r = i >> 4, k0 = (i & 15) * 8;
      *(uint4*)&Hb[r*136 + k0] = src[i];
    }
  }
  {
    const uint4* src = (const uint4*)(WT2g + (size_t)by*96*136);
    uint4* dst = (uint4*)Wt;
    for (int i = tid; i < 1632; i += 256) dst[i] = src[i];
  }
  __syncthreads();

  const int s = w >> 1;
  const int h = w & 1;
  const int fr = l & 15;
  const int koff = (l >> 4) * 8;

  f32x4 acc[3];
  #pragma unroll
  for (int t = 0; t < 3; ++t) acc[t] = (f32x4){0.f,0.f,0.f,0.f};

  #pragma unroll
  for (int ks = 0; ks < 4; ++ks) {
    bf16x8 a = *(const bf16x8*)&Hb[(s*16 + fr)*136 + ks*32 + koff];
    #pragma unroll
    for (int t = 0; t < 3; ++t) {
      bf16x8 b = *(const bf16x8*)&Wt[(h*48 + t*16 + fr)*136 + ks*32 + koff];
      acc[t] = __builtin_amdgcn_mfma_f32_16x16x32_bf16(a, b, acc[t], 0, 0, 0);
    }
  }

  #pragma unroll
  for (int t = 0; t < 3; ++t) {
    const int col = by*96 + h*48 + t*16 + fr;
    const float bb = fc2_b[col];
    #pragma unroll
    for (int r = 0; r < 4; ++r) {
      const int row = bx*32 + s*16 + (l>>4)*4 + r;
      float v = acc[t][r] + bb;
      recon[(size_t)row*OUTD + col] = 1.f/(1.f + __expf(-v));
    }
  }
}

extern "C" void kernel_launch(void* const* d_in, const int* in_sizes, int n_in,
                              void* d_out, int out_size, void* d_ws, size_t ws_size,
                              hipStream_t stream) {
  const float* x       = (const float*)d_in[0];
  const int*   ei      = (const int*)d_in[1];
  const float* eps     = (const float*)d_in[3];
  const float* w1_rel  = (const float*)d_in[4];
  const float* b1      = (const float*)d_in[5];
  const float* w1_root = (const float*)d_in[6];
  const float* w2_rel  = (const float*)d_in[7];
  const float* b2      = (const float*)d_in[8];
  const float* w2_root = (const float*)d_in[9];
  const float* w3_rel  = (const float*)d_in[10];
  const float* b3      = (const float*)d_in[11];
  const float* w3_root = (const float*)d_in[12];
  const float* fc1_w   = (const float*)d_in[13];
  const float* fc1_b   = (const float*)d_in[14];
  const float* fc2_w   = (const float*)d_in[15];
  const float* fc2_b   = (const float*)d_in[16];

  float* recon  = (float*)d_out;
  float* out_mu = recon + (size_t)NG*OUTD;
  float* out_lv = out_mu + (size_t)NG*H2D;

  // workspace carve
  char* p = (char*)d_ws;
  short* WTg   = (short*)p;              p += 128*136*2;     // 34816
  short* WT2g  = (short*)p;              p += 2016*136*2;    // 548352
  short* fc1T  = (short*)p;              p += 128*72*2;      // 18432
  short* W23T  = (short*)p;              p += 128*264*2;     // 67584
  short* SVg   = (short*)p;              p += (size_t)NG*256*2;   // 1048576
  short* hbufB = (short*)p;                                   // 524288

  p_pre<<<71, 256, 0, stream>>>(fc2_w, w2_rel, w2_root, w3_rel, w3_root,
                                fc1_w, w1_rel, w1_root, WT2g, W23T, fc1T, WTg);
  k1_encoder<<<NG, 256, 0, stream>>>(x, ei, WTg, b1, SVg);
  k1b_latent<<<64, 256, 0, stream>>>(SVg, W23T, b2, b3, eps, fc1T, fc1_b,
                                     out_mu, out_lv, hbufB);
  k2_decoder<<<dim3(64, 21), 256, 0, stream>>>(hbufB, WT2g, fc2_b, recon);
}

// Round 5
// 163.250 us; speedup vs baseline: 9.3858x; 1.0415x over previous
//
#include <hip/hip_runtime.h>
#include <math.h>

#define NG 2048
#define NPG 64
#define EPG 512
#define ETOT (NG*EPG)
#define IND 64
#define H1D 128
#define H2D 64
#define OUTD 2016

typedef __attribute__((ext_vector_type(8))) short bf16x8;
typedef __attribute__((ext_vector_type(4))) float f32x4;

__device__ inline short f2b(float f) {
  union { float f; unsigned u; } v; v.f = f;
  unsigned r = (v.u + 0x7FFFu + ((v.u >> 16) & 1u)) >> 16;
  return (short)r;
}

// ---- tiny pre-kernel: w1_rel|w1_root -> WTg[col][k] pitch 136 (must precede k1) ----
__global__ void p_w1(const float* __restrict__ w1_rel, const float* __restrict__ w1_root,
                     short* __restrict__ WTg) {
  const int k = blockIdx.x;      // 0..63
  const int c = threadIdx.x;     // 0..127
  WTg[c*136 + k]      = f2b(w1_rel[k*H1D + c]);
  WTg[c*136 + 64 + k] = f2b(w1_root[k*H1D + c]);
}

// ================= Kernel 1: per-graph encoder (+ folded weight transposes) ==========
// blocks 0..2047: per-graph adjacency + conv1 + colsum reductions -> SVg
// blocks 2048..2116: fc2/w23/fc1 transposes (consumed by k1b/k2, no dep on k1 inputs)
// Encoder LDS = 37632 B -> 4 blocks/CU.
__global__ __launch_bounds__(256, 4) void k1_encoder(
    const float* __restrict__ x, const int* __restrict__ ei,
    const short* __restrict__ WTg, const float* __restrict__ b1,
    short* __restrict__ SVg,
    const float* __restrict__ fc2_w, const float* __restrict__ w2_rel, const float* __restrict__ w2_root,
    const float* __restrict__ w3_rel, const float* __restrict__ w3_root,
    const float* __restrict__ fc1_w,
    short* __restrict__ WT2g, short* __restrict__ W23T, short* __restrict__ fc1T)
{
  __shared__ __align__(16) char smem[37632];
  const int g = blockIdx.x;
  const int tid = threadIdx.x;

  if (g >= NG) {
    // ---------- folded transpose path ----------
    float* L = (float*)smem;              // needs 33792 B <= 37632
    const int bid = g - NG;               // 0..68
    if (bid < 63) {                       // fc2 -> WT2g
      const int c0 = bid*32;
      for (int i = tid; i < 4096; i += 256) {
        int k = i >> 5, c = i & 31;
        L[k*33 + c] = fc2_w[(size_t)k*OUTD + c0 + c];
      }
      __syncthreads();
      const int c = tid >> 3, k0 = (tid & 7)*16;
      for (int kk = 0; kk < 16; ++kk)
        WT2g[(size_t)(c0 + c)*136 + k0 + kk] = f2b(L[(k0 + kk)*33 + c]);
    } else if (bid < 67) {                // w2/w3 -> W23T
      const int cc = bid - 63;
      const int j0 = cc*32;
      const float* wrel  = (cc < 2) ? w2_rel  : w3_rel;
      const float* wroot = (cc < 2) ? w2_root : w3_root;
      const int jl = j0 & 63;
      for (int i = tid; i < 4096; i += 256) {
        int k = i >> 5, c = i & 31;
        L[k*33 + c]        = wrel [k*H2D + jl + c];
        L[4224 + k*33 + c] = wroot[k*H2D + jl + c];
      }
      __syncthreads();
      const int c = tid >> 3, k0 = (tid & 7)*32;
      for (int kk = 0; kk < 32; ++kk) {
        int k = k0 + kk;
        float v = (k < 128) ? L[k*33 + c] : L[4224 + (k - 128)*33 + c];
        W23T[(size_t)(j0 + c)*264 + k] = f2b(v);
      }
    } else {                              // fc1 -> fc1T
      const int c0 = (bid - 67)*64;
      for (int i = tid; i < 4096; i += 256) {
        int k = i >> 6, c = i & 63;
        L[k*65 + c] = fc1_w[k*H1D + c0 + c];
      }
      __syncthreads();
      const int c = tid >> 2, k0 = (tid & 3)*16;
      for (int kk = 0; kk < 16; ++kk)
        fc1T[(size_t)(c0 + c)*72 + k0 + kk] = f2b(L[(k0 + kk)*65 + c]);
    }
    return;
  }

  // ---------- encoder path ----------
  short* Xb    = (short*)smem;             // 9216
  short* XbT   = (short*)(smem + 9216);    // 9216 (aliased by AGb after phase 1)
  float* Af    = (float*)(smem + 18432);   // 16896 (aliased by Ab bf16 after cvt)
  float* dpart = (float*)(smem + 35328);   // 1024
  float* deg   = (float*)(smem + 36352);   // 256
  float* hsum  = (float*)(smem + 36608);   // 512
  float* wsum  = (float*)(smem + 37120);   // 512

  const int w = tid >> 6, l = tid & 63;

  // hoist edge loads (HBM latency overlaps zero+stage)
  const int e0 = g*EPG + tid*2;
  const int s0 = ei[e0] & 63,     d0 = ei[ETOT + e0] & 63;
  const int s1 = ei[e0 + 1] & 63, d1 = ei[ETOT + e0 + 1] & 63;

  for (int i = tid; i < 64*66; i += 256) Af[i] = 0.f;
  if (tid < 128) { hsum[tid] = 0.f; wsum[tid] = 0.f; }

  // stage Xb (row-major bf16) + XbT (transposed bf16)
  {
    const int n = tid >> 2, f0 = (tid & 3) * 16;
    const float* xr = x + (size_t)g*(NPG*IND) + n*IND + f0;
    float4 v0 = *(const float4*)&xr[0];
    float4 v1 = *(const float4*)&xr[4];
    float4 v2 = *(const float4*)&xr[8];
    float4 v3 = *(const float4*)&xr[12];
    short b[16];
    b[0]=f2b(v0.x); b[1]=f2b(v0.y); b[2]=f2b(v0.z); b[3]=f2b(v0.w);
    b[4]=f2b(v1.x); b[5]=f2b(v1.y); b[6]=f2b(v1.z); b[7]=f2b(v1.w);
    b[8]=f2b(v2.x); b[9]=f2b(v2.y); b[10]=f2b(v2.z); b[11]=f2b(v2.w);
    b[12]=f2b(v3.x); b[13]=f2b(v3.y); b[14]=f2b(v3.z); b[15]=f2b(v3.w);
    short* xbp = &Xb[n*72 + f0];
    #pragma unroll
    for (int j = 0; j < 16; ++j) xbp[j] = b[j];
    #pragma unroll
    for (int j = 0; j < 16; ++j) XbT[(f0 + j)*72 + n] = b[j];
  }
  __syncthreads();

  // adjacency atomics (512 scalar adds)
  atomicAdd(&Af[d0*66 + s0], 1.f);
  atomicAdd(&Af[d1*66 + s1], 1.f);
  __syncthreads();

  // cvt A -> regs + per-thread deg partial (thread owns column scol, rows nrow0+4j)
  short cb[16];
  {
    const int scol = tid & 63, nrow0 = tid >> 6;
    float ps = 0.f;
    #pragma unroll
    for (int j = 0; j < 16; ++j) {
      float v = Af[(nrow0 + 4*j)*66 + scol];
      cb[j] = f2b(v); ps += v;
    }
    dpart[tid] = ps;
  }
  __syncthreads();

  // in-place: write Ab bf16 over Af region; finalize deg
  short* Ab = (short*)Af;
  {
    const int scol = tid & 63, nrow0 = tid >> 6;
    #pragma unroll
    for (int j = 0; j < 16; ++j) Ab[(nrow0 + 4*j)*72 + scol] = cb[j];
  }
  if (tid < 64) deg[tid] = dpart[tid] + dpart[64 + tid] + dpart[128 + tid] + dpart[192 + tid];
  __syncthreads();

  const int rm = w*16;
  const int fr = l & 15;
  const int koff = (l >> 4) * 8;

  // phase 1: AG = A @ X  (M=64,N=64,K=64)
  f32x4 agc[4];
  #pragma unroll
  for (int t = 0; t < 4; ++t) agc[t] = (f32x4){0.f,0.f,0.f,0.f};
  #pragma unroll
  for (int ks = 0; ks < 2; ++ks) {
    bf16x8 a = *(const bf16x8*)&Ab[(rm + fr)*72 + ks*32 + koff];
    #pragma unroll
    for (int t = 0; t < 4; ++t) {
      bf16x8 b = *(const bf16x8*)&XbT[(t*16 + fr)*72 + ks*32 + koff];
      agc[t] = __builtin_amdgcn_mfma_f32_16x16x32_bf16(a, b, agc[t], 0, 0, 0);
    }
  }
  __syncthreads();   // all XbT reads complete before alias overwrite

  short* AGb = XbT;  // alias
  #pragma unroll
  for (int t = 0; t < 4; ++t)
    #pragma unroll
    for (int r = 0; r < 4; ++r)
      AGb[(rm + (l>>4)*4 + r)*72 + t*16 + fr] = f2b(agc[t][r]);
  __syncthreads();

  // phase 2: h1pre = [AG|X] @ W1 (M=64,N=128,K=128), B-frags from global (L2-hot)
  {
    float dg[4];
    #pragma unroll
    for (int r = 0; r < 4; ++r) dg[r] = deg[rm + (l>>4)*4 + r];

    f32x4 acc[8];
    #pragma unroll
    for (int t = 0; t < 8; ++t) acc[t] = (f32x4){0.f,0.f,0.f,0.f};
    #pragma unroll
    for (int ks = 0; ks < 4; ++ks) {
      bf16x8 a = (ks < 2)
        ? *(const bf16x8*)&AGb[(rm + fr)*72 + ks*32 + koff]
        : *(const bf16x8*)&Xb[(rm + fr)*72 + (ks-2)*32 + koff];
      #pragma unroll
      for (int t = 0; t < 8; ++t) {
        bf16x8 b = *(const bf16x8*)&WTg[(t*16 + fr)*136 + ks*32 + koff];
        acc[t] = __builtin_amdgcn_mfma_f32_16x16x32_bf16(a, b, acc[t], 0, 0, 0);
      }
    }
    #pragma unroll
    for (int t = 0; t < 8; ++t) {
      const int col = t*16 + fr;
      const float bb = b1[col];
      float hs = 0.f, ws = 0.f;
      #pragma unroll
      for (int r = 0; r < 4; ++r) {
        float v = fmaxf(acc[t][r] + bb, 0.f);
        hs += v; ws += dg[r]*v;
      }
      hs += __shfl_down(hs, 32); ws += __shfl_down(ws, 32);
      hs += __shfl_down(hs, 16); ws += __shfl_down(ws, 16);
      if (l < 16) { atomicAdd(&hsum[col], hs); atomicAdd(&wsum[col], ws); }
    }
  }
  __syncthreads();

  if (tid < 128) {
    SVg[(size_t)g*256 + tid]       = f2b(wsum[tid]);
    SVg[(size_t)g*256 + 128 + tid] = f2b(hsum[tid]);
  }
}

// ================= Kernel 1b: batched conv2/3-mean + reparam + fc1 ==========
__global__ __launch_bounds__(256) void k1b_latent(
    const short* __restrict__ SVg, const short* __restrict__ W23T,
    const float* __restrict__ b2, const float* __restrict__ b3,
    const float* __restrict__ eps, const short* __restrict__ fc1T,
    const float* __restrict__ fc1_b,
    float* __restrict__ out_mu, float* __restrict__ out_lv, short* __restrict__ hbufB)
{
  __shared__ short SV[32*264];
  __shared__ short Zt[32*72];
  const int g0 = blockIdx.x * 32;
  const int tid = threadIdx.x;
  const int w = tid >> 6, l = tid & 63;
  const int s = w >> 1;
  const int h = w & 1;
  const int fr = l & 15;
  const int koff = (l >> 4) * 8;

  {
    const uint4* src = (const uint4*)(SVg + (size_t)g0*256);
    for (int i = tid; i < 1024; i += 256) {
      int r = i >> 5, k0 = (i & 31) * 8;
      *(uint4*)&SV[r*264 + k0] = src[i];
    }
  }
  __syncthreads();

  f32x4 acc[4];
  #pragma unroll
  for (int t = 0; t < 4; ++t) acc[t] = (f32x4){0.f,0.f,0.f,0.f};
  #pragma unroll
  for (int ks = 0; ks < 8; ++ks) {
    bf16x8 a = *(const bf16x8*)&SV[(s*16 + fr)*264 + ks*32 + koff];
    #pragma unroll
    for (int j = 0; j < 2; ++j) {
      bf16x8 bm = *(const bf16x8*)&W23T[((2*h + j)*16 + fr)*264 + ks*32 + koff];
      bf16x8 bl = *(const bf16x8*)&W23T[((2*h + j + 4)*16 + fr)*264 + ks*32 + koff];
      acc[j]     = __builtin_amdgcn_mfma_f32_16x16x32_bf16(a, bm, acc[j], 0, 0, 0);
      acc[2 + j] = __builtin_amdgcn_mfma_f32_16x16x32_bf16(a, bl, acc[2 + j], 0, 0, 0);
    }
  }
  #pragma unroll
  for (int j = 0; j < 2; ++j) {
    const int col = (2*h + j)*16 + fr;
    const float bb2 = b2[col], bb3 = b3[col];
    #pragma unroll
    for (int r = 0; r < 4; ++r) {
      const int row = s*16 + (l>>4)*4 + r;
      const size_t gg = (size_t)(g0 + row);
      float mu = acc[j][r]     * (1.f/64.f) + bb2;
      float lv = acc[2 + j][r] * (1.f/64.f) + bb3;
      out_mu[gg*64 + col] = mu;
      out_lv[gg*64 + col] = lv;
      float z = mu + eps[gg*64 + col] * __expf(0.5f*lv);
      Zt[row*72 + col] = f2b(z);
    }
  }
  __syncthreads();

  f32x4 hacc[4];
  #pragma unroll
  for (int t = 0; t < 4; ++t) hacc[t] = (f32x4){0.f,0.f,0.f,0.f};
  #pragma unroll
  for (int ks = 0; ks < 2; ++ks) {
    bf16x8 a = *(const bf16x8*)&Zt[(s*16 + fr)*72 + ks*32 + koff];
    #pragma unroll
    for (int j = 0; j < 4; ++j) {
      bf16x8 b = *(const bf16x8*)&fc1T[((h*4 + j)*16 + fr)*72 + ks*32 + koff];
      hacc[j] = __builtin_amdgcn_mfma_f32_16x16x32_bf16(a, b, hacc[j], 0, 0, 0);
    }
  }
  #pragma unroll
  for (int j = 0; j < 4; ++j) {
    const int col = (h*4 + j)*16 + fr;
    const float bb = fc1_b[col];
    #pragma unroll
    for (int r = 0; r < 4; ++r) {
      const int row = s*16 + (l>>4)*4 + r;
      hbufB[(size_t)(g0 + row)*H1D + col] = f2b(fmaxf(hacc[j][r] + bb, 0.f));
    }
  }
}

// ================= Kernel 2: decoder GEMM ==========
__global__ __launch_bounds__(256, 4) void k2_decoder(
    const short* __restrict__ hbufB, const short* __restrict__ WT2g,
    const float* __restrict__ fc2_b, float* __restrict__ recon)
{
  __shared__ __align__(16) short Hb[32*136];
  __shared__ __align__(16) short Wt[96*136];
  const int bx = blockIdx.x, by = blockIdx.y;
  const int tid = threadIdx.x;
  const int w = tid >> 6, l = tid & 63;

  {
    const uint4* src = (const uint4*)(hbufB + (size_t)bx*32*H1D);
    for (int i = tid; i < 512; i += 256) {
      int r = i >> 4, k0 = (i & 15) * 8;
      *(uint4*)&Hb[r*136 + k0] = src[i];
    }
  }
  {
    const uint4* src = (const uint4*)(WT2g + (size_t)by*96*136);
    uint4* dst = (uint4*)Wt;
    for (int i = tid; i < 1632; i += 256) dst[i] = src[i];
  }
  __syncthreads();

  const int s = w >> 1;
  const int h = w & 1;
  const int fr = l & 15;
  const int koff = (l >> 4) * 8;

  f32x4 acc[3];
  #pragma unroll
  for (int t = 0; t < 3; ++t) acc[t] = (f32x4){0.f,0.f,0.f,0.f};

  #pragma unroll
  for (int ks = 0; ks < 4; ++ks) {
    bf16x8 a = *(const bf16x8*)&Hb[(s*16 + fr)*136 + ks*32 + koff];
    #pragma unroll
    for (int t = 0; t < 3; ++t) {
      bf16x8 b = *(const bf16x8*)&Wt[(h*48 + t*16 + fr)*136 + ks*32 + koff];
      acc[t] = __builtin_amdgcn_mfma_f32_16x16x32_bf16(a, b, acc[t], 0, 0, 0);
    }
  }

  #pragma unroll
  for (int t = 0; t < 3; ++t) {
    const int col = by*96 + h*48 + t*16 + fr;
    const float bb = fc2_b[col];
    #pragma unroll
    for (int r = 0; r < 4; ++r) {
      const int row = bx*32 + s*16 + (l>>4)*4 + r;
      float v = acc[t][r] + bb;
      recon[(size_t)row*OUTD + col] = 1.f/(1.f + __expf(-v));
    }
  }
}

extern "C" void kernel_launch(void* const* d_in, const int* in_sizes, int n_in,
                              void* d_out, int out_size, void* d_ws, size_t ws_size,
                              hipStream_t stream) {
  const float* x       = (const float*)d_in[0];
  const int*   ei      = (const int*)d_in[1];
  const float* eps     = (const float*)d_in[3];
  const float* w1_rel  = (const float*)d_in[4];
  const float* b1      = (const float*)d_in[5];
  const float* w1_root = (const float*)d_in[6];
  const float* w2_rel  = (const float*)d_in[7];
  const float* b2      = (const float*)d_in[8];
  const float* w2_root = (const float*)d_in[9];
  const float* w3_rel  = (const float*)d_in[10];
  const float* b3      = (const float*)d_in[11];
  const float* w3_root = (const float*)d_in[12];
  const float* fc1_w   = (const float*)d_in[13];
  const float* fc1_b   = (const float*)d_in[14];
  const float* fc2_w   = (const float*)d_in[15];
  const float* fc2_b   = (const float*)d_in[16];

  float* recon  = (float*)d_out;
  float* out_mu = recon + (size_t)NG*OUTD;
  float* out_lv = out_mu + (size_t)NG*H2D;

  char* p = (char*)d_ws;
  short* WTg   = (short*)p;              p += 128*136*2;        // 34816
  short* WT2g  = (short*)p;              p += 2016*136*2;       // 548352
  short* fc1T  = (short*)p;              p += 128*72*2;         // 18432
  short* W23T  = (short*)p;              p += 128*264*2;        // 67584
  short* SVg   = (short*)p;              p += (size_t)NG*256*2; // 1048576
  short* hbufB = (short*)p;                                     // 524288

  p_w1<<<64, 128, 0, stream>>>(w1_rel, w1_root, WTg);
  k1_encoder<<<NG + 69, 256, 0, stream>>>(x, ei, WTg, b1, SVg,
      fc2_w, w2_rel, w2_root, w3_rel, w3_root, fc1_w, WT2g, W23T, fc1T);
  k1b_latent<<<64, 256, 0, stream>>>(SVg, W23T, b2, b3, eps, fc1T, fc1_b,
                                     out_mu, out_lv, hbufB);
  k2_decoder<<<dim3(64, 21), 256, 0, stream>>>(hbufB, WT2g, fc2_b, recon);
}

// Round 6
// 162.521 us; speedup vs baseline: 9.4279x; 1.0045x over previous
//
#include <hip/hip_runtime.h>
#include <math.h>

#define NG 2048
#define NPG 64
#define EPG 512
#define ETOT (NG*EPG)
#define IND 64
#define H1D 128
#define H2D 64
#define OUTD 2016

typedef __attribute__((ext_vector_type(8))) short bf16x8;
typedef __attribute__((ext_vector_type(4))) float f32x4;

__device__ inline short f2b(float f) {
  union { float f; unsigned u; } v; v.f = f;
  unsigned r = (v.u + 0x7FFFu + ((v.u >> 16) & 1u)) >> 16;
  return (short)r;
}

// ---- tiny pre-kernel: w1_rel|w1_root -> WTg[col][k] pitch 136 (must precede k1) ----
__global__ void p_w1(const float* __restrict__ w1_rel, const float* __restrict__ w1_root,
                     short* __restrict__ WTg) {
  const int k = blockIdx.x;      // 0..63
  const int c = threadIdx.x;     // 0..127
  WTg[c*136 + k]      = f2b(w1_rel[k*H1D + c]);
  WTg[c*136 + 64 + k] = f2b(w1_root[k*H1D + c]);
}

// ================= Kernel 1: per-graph encoder (+ folded weight transposes) ==========
// blocks 0..2047: per-graph adjacency + conv1 + colsum reductions -> SVg
// blocks 2048..2116: fc2/w23/fc1 transposes (consumed by k1b/k2)
// Encoder LDS = 37632 B -> 4 blocks/CU. W1 staged to LDS in two halves over the
// dead adjacency region (fixes R4's uncoalesced global B-frag gather: 512KB -> 35KB L2/block).
__global__ __launch_bounds__(256, 4) void k1_encoder(
    const float* __restrict__ x, const int* __restrict__ ei,
    const short* __restrict__ WTg, const float* __restrict__ b1,
    short* __restrict__ SVg,
    const float* __restrict__ fc2_w, const float* __restrict__ w2_rel, const float* __restrict__ w2_root,
    const float* __restrict__ w3_rel, const float* __restrict__ w3_root,
    const float* __restrict__ fc1_w,
    short* __restrict__ WT2g, short* __restrict__ W23T, short* __restrict__ fc1T)
{
  __shared__ __align__(16) char smem[37632];
  const int g = blockIdx.x;
  const int tid = threadIdx.x;

  if (g >= NG) {
    // ---------- folded transpose path ----------
    float* L = (float*)smem;              // needs 33792 B <= 37632
    const int bid = g - NG;               // 0..68
    if (bid < 63) {                       // fc2 -> WT2g
      const int c0 = bid*32;
      for (int i = tid; i < 4096; i += 256) {
        int k = i >> 5, c = i & 31;
        L[k*33 + c] = fc2_w[(size_t)k*OUTD + c0 + c];
      }
      __syncthreads();
      const int c = tid >> 3, k0 = (tid & 7)*16;
      for (int kk = 0; kk < 16; ++kk)
        WT2g[(size_t)(c0 + c)*136 + k0 + kk] = f2b(L[(k0 + kk)*33 + c]);
    } else if (bid < 67) {                // w2/w3 -> W23T
      const int cc = bid - 63;
      const int j0 = cc*32;
      const float* wrel  = (cc < 2) ? w2_rel  : w3_rel;
      const float* wroot = (cc < 2) ? w2_root : w3_root;
      const int jl = j0 & 63;
      for (int i = tid; i < 4096; i += 256) {
        int k = i >> 5, c = i & 31;
        L[k*33 + c]        = wrel [k*H2D + jl + c];
        L[4224 + k*33 + c] = wroot[k*H2D + jl + c];
      }
      __syncthreads();
      const int c = tid >> 3, k0 = (tid & 7)*32;
      for (int kk = 0; kk < 32; ++kk) {
        int k = k0 + kk;
        float v = (k < 128) ? L[k*33 + c] : L[4224 + (k - 128)*33 + c];
        W23T[(size_t)(j0 + c)*264 + k] = f2b(v);
      }
    } else {                              // fc1 -> fc1T
      const int c0 = (bid - 67)*64;
      for (int i = tid; i < 4096; i += 256) {
        int k = i >> 6, c = i & 63;
        L[k*65 + c] = fc1_w[k*H1D + c0 + c];
      }
      __syncthreads();
      const int c = tid >> 2, k0 = (tid & 3)*16;
      for (int kk = 0; kk < 16; ++kk)
        fc1T[(size_t)(c0 + c)*72 + k0 + kk] = f2b(L[(k0 + kk)*65 + c]);
    }
    return;
  }

  // ---------- encoder path ----------
  // layout: [0,9216) Xb | [9216,18432) XbT (->AGb) | [18432,35328) Af (->Ab, ->Wbuf)
  //         [35328,36352) dpart | [36352,36608) deg | [36608,37120) hsum | [37120,37632) wsum
  // Wbuf (17408 B) overlays [18432,35840): Af+dpart region, both dead by then.
  short* Xb    = (short*)smem;
  short* XbT   = (short*)(smem + 9216);
  float* Af    = (float*)(smem + 18432);
  short* Wbuf  = (short*)(smem + 18432);
  float* dpart = (float*)(smem + 35328);
  float* deg   = (float*)(smem + 36352);
  float* hsum  = (float*)(smem + 36608);
  float* wsum  = (float*)(smem + 37120);

  const int w = tid >> 6, l = tid & 63;

  // hoist edge loads (HBM latency overlaps zero+stage)
  const int e0 = g*EPG + tid*2;
  const int s0 = ei[e0] & 63,     d0 = ei[ETOT + e0] & 63;
  const int s1 = ei[e0 + 1] & 63, d1 = ei[ETOT + e0 + 1] & 63;

  for (int i = tid; i < 64*66; i += 256) Af[i] = 0.f;
  if (tid < 128) { hsum[tid] = 0.f; wsum[tid] = 0.f; }

  // stage Xb (row-major bf16) + XbT (transposed bf16)
  {
    const int n = tid >> 2, f0 = (tid & 3) * 16;
    const float* xr = x + (size_t)g*(NPG*IND) + n*IND + f0;
    float4 v0 = *(const float4*)&xr[0];
    float4 v1 = *(const float4*)&xr[4];
    float4 v2 = *(const float4*)&xr[8];
    float4 v3 = *(const float4*)&xr[12];
    short b[16];
    b[0]=f2b(v0.x); b[1]=f2b(v0.y); b[2]=f2b(v0.z); b[3]=f2b(v0.w);
    b[4]=f2b(v1.x); b[5]=f2b(v1.y); b[6]=f2b(v1.z); b[7]=f2b(v1.w);
    b[8]=f2b(v2.x); b[9]=f2b(v2.y); b[10]=f2b(v2.z); b[11]=f2b(v2.w);
    b[12]=f2b(v3.x); b[13]=f2b(v3.y); b[14]=f2b(v3.z); b[15]=f2b(v3.w);
    short* xbp = &Xb[n*72 + f0];
    #pragma unroll
    for (int j = 0; j < 16; ++j) xbp[j] = b[j];
    #pragma unroll
    for (int j = 0; j < 16; ++j) XbT[(f0 + j)*72 + n] = b[j];
  }
  __syncthreads();

  // adjacency atomics (512 scalar adds)
  atomicAdd(&Af[d0*66 + s0], 1.f);
  atomicAdd(&Af[d1*66 + s1], 1.f);
  __syncthreads();

  // cvt A -> regs + per-thread deg partial (thread owns column scol, rows nrow0+4j)
  short cb[16];
  {
    const int scol = tid & 63, nrow0 = tid >> 6;
    float ps = 0.f;
    #pragma unroll
    for (int j = 0; j < 16; ++j) {
      float v = Af[(nrow0 + 4*j)*66 + scol];
      cb[j] = f2b(v); ps += v;
    }
    dpart[tid] = ps;
  }
  __syncthreads();

  // in-place: write Ab bf16 over Af region; finalize deg
  short* Ab = (short*)Af;
  {
    const int scol = tid & 63, nrow0 = tid >> 6;
    #pragma unroll
    for (int j = 0; j < 16; ++j) Ab[(nrow0 + 4*j)*72 + scol] = cb[j];
  }
  if (tid < 64) deg[tid] = dpart[tid] + dpart[64 + tid] + dpart[128 + tid] + dpart[192 + tid];
  __syncthreads();

  const int rm = w*16;
  const int fr = l & 15;
  const int koff = (l >> 4) * 8;

  // phase 1: AG = A @ X  (M=64,N=64,K=64)
  f32x4 agc[4];
  #pragma unroll
  for (int t = 0; t < 4; ++t) agc[t] = (f32x4){0.f,0.f,0.f,0.f};
  #pragma unroll
  for (int ks = 0; ks < 2; ++ks) {
    bf16x8 a = *(const bf16x8*)&Ab[(rm + fr)*72 + ks*32 + koff];
    #pragma unroll
    for (int t = 0; t < 4; ++t) {
      bf16x8 b = *(const bf16x8*)&XbT[(t*16 + fr)*72 + ks*32 + koff];
      agc[t] = __builtin_amdgcn_mfma_f32_16x16x32_bf16(a, b, agc[t], 0, 0, 0);
    }
  }
  __syncthreads();   // all Ab/XbT reads complete before alias overwrite

  // write AGb (over XbT) + stage W half 0 (cols 0..63) over Ab/Af (dead)
  short* AGb = XbT;
  #pragma unroll
  for (int t = 0; t < 4; ++t)
    #pragma unroll
    for (int r = 0; r < 4; ++r)
      AGb[(rm + (l>>4)*4 + r)*72 + t*16 + fr] = f2b(agc[t][r]);
  {
    const uint4* src = (const uint4*)WTg;
    uint4* dst = (uint4*)Wbuf;
    for (int i = tid; i < 1088; i += 256) dst[i] = src[i];
  }
  __syncthreads();

  // phase 2: h1pre = [AG|X] @ W1 (M=64,N=128,K=128), B-frags from LDS, two N-halves
  {
    float dg[4];
    #pragma unroll
    for (int r = 0; r < 4; ++r) dg[r] = deg[rm + (l>>4)*4 + r];

    // A-fragments in registers across both halves
    bf16x8 afr[4];
    #pragma unroll
    for (int ks = 0; ks < 4; ++ks)
      afr[ks] = (ks < 2)
        ? *(const bf16x8*)&AGb[(rm + fr)*72 + ks*32 + koff]
        : *(const bf16x8*)&Xb[(rm + fr)*72 + (ks-2)*32 + koff];

    f32x4 acc[8];
    #pragma unroll
    for (int t = 0; t < 8; ++t) acc[t] = (f32x4){0.f,0.f,0.f,0.f};

    // half A: cols 0..63
    #pragma unroll
    for (int ks = 0; ks < 4; ++ks)
      #pragma unroll
      for (int t = 0; t < 4; ++t) {
        bf16x8 b = *(const bf16x8*)&Wbuf[(t*16 + fr)*136 + ks*32 + koff];
        acc[t] = __builtin_amdgcn_mfma_f32_16x16x32_bf16(afr[ks], b, acc[t], 0, 0, 0);
      }
    __syncthreads();

    // stage W half 1 (cols 64..127)
    {
      const uint4* src = (const uint4*)(WTg + 64*136);
      uint4* dst = (uint4*)Wbuf;
      for (int i = tid; i < 1088; i += 256) dst[i] = src[i];
    }
    __syncthreads();

    // half B: cols 64..127
    #pragma unroll
    for (int ks = 0; ks < 4; ++ks)
      #pragma unroll
      for (int t = 0; t < 4; ++t) {
        bf16x8 b = *(const bf16x8*)&Wbuf[(t*16 + fr)*136 + ks*32 + koff];
        acc[4 + t] = __builtin_amdgcn_mfma_f32_16x16x32_bf16(afr[ks], b, acc[4 + t], 0, 0, 0);
      }

    // epilogue: relu + column sums (plain + deg-weighted)
    #pragma unroll
    for (int t = 0; t < 8; ++t) {
      const int col = t*16 + fr;
      const float bb = b1[col];
      float hs = 0.f, ws = 0.f;
      #pragma unroll
      for (int r = 0; r < 4; ++r) {
        float v = fmaxf(acc[t][r] + bb, 0.f);
        hs += v; ws += dg[r]*v;
      }
      hs += __shfl_down(hs, 32); ws += __shfl_down(ws, 32);
      hs += __shfl_down(hs, 16); ws += __shfl_down(ws, 16);
      if (l < 16) { atomicAdd(&hsum[col], hs); atomicAdd(&wsum[col], ws); }
    }
  }
  __syncthreads();

  if (tid < 128) {
    SVg[(size_t)g*256 + tid]       = f2b(wsum[tid]);
    SVg[(size_t)g*256 + 128 + tid] = f2b(hsum[tid]);
  }
}

// ================= Kernel 1b: batched conv2/3-mean + reparam + fc1 ==========
__global__ __launch_bounds__(256) void k1b_latent(
    const short* __restrict__ SVg, const short* __restrict__ W23T,
    const float* __restrict__ b2, const float* __restrict__ b3,
    const float* __restrict__ eps, const short* __restrict__ fc1T,
    const float* __restrict__ fc1_b,
    float* __restrict__ out_mu, float* __restrict__ out_lv, short* __restrict__ hbufB)
{
  __shared__ short SV[32*264];
  __shared__ short Zt[32*72];
  const int g0 = blockIdx.x * 32;
  const int tid = threadIdx.x;
  const int w = tid >> 6, l = tid & 63;
  const int s = w >> 1;
  const int h = w & 1;
  const int fr = l & 15;
  const int koff = (l >> 4) * 8;

  {
    const uint4* src = (const uint4*)(SVg + (size_t)g0*256);
    for (int i = tid; i < 1024; i += 256) {
      int r = i >> 5, k0 = (i & 31) * 8;
      *(uint4*)&SV[r*264 + k0] = src[i];
    }
  }
  __syncthreads();

  f32x4 acc[4];
  #pragma unroll
  for (int t = 0; t < 4; ++t) acc[t] = (f32x4){0.f,0.f,0.f,0.f};
  #pragma unroll
  for (int ks = 0; ks < 8; ++ks) {
    bf16x8 a = *(const bf16x8*)&SV[(s*16 + fr)*264 + ks*32 + koff];
    #pragma unroll
    for (int j = 0; j < 2; ++j) {
      bf16x8 bm = *(const bf16x8*)&W23T[((2*h + j)*16 + fr)*264 + ks*32 + koff];
      bf16x8 bl = *(const bf16x8*)&W23T[((2*h + j + 4)*16 + fr)*264 + ks*32 + koff];
      acc[j]     = __builtin_amdgcn_mfma_f32_16x16x32_bf16(a, bm, acc[j], 0, 0, 0);
      acc[2 + j] = __builtin_amdgcn_mfma_f32_16x16x32_bf16(a, bl, acc[2 + j], 0, 0, 0);
    }
  }
  #pragma unroll
  for (int j = 0; j < 2; ++j) {
    const int col = (2*h + j)*16 + fr;
    const float bb2 = b2[col], bb3 = b3[col];
    #pragma unroll
    for (int r = 0; r < 4; ++r) {
      const int row = s*16 + (l>>4)*4 + r;
      const size_t gg = (size_t)(g0 + row);
      float mu = acc[j][r]     * (1.f/64.f) + bb2;
      float lv = acc[2 + j][r] * (1.f/64.f) + bb3;
      out_mu[gg*64 + col] = mu;
      out_lv[gg*64 + col] = lv;
      float z = mu + eps[gg*64 + col] * __expf(0.5f*lv);
      Zt[row*72 + col] = f2b(z);
    }
  }
  __syncthreads();

  f32x4 hacc[4];
  #pragma unroll
  for (int t = 0; t < 4; ++t) hacc[t] = (f32x4){0.f,0.f,0.f,0.f};
  #pragma unroll
  for (int ks = 0; ks < 2; ++ks) {
    bf16x8 a = *(const bf16x8*)&Zt[(s*16 + fr)*72 + ks*32 + koff];
    #pragma unroll
    for (int j = 0; j < 4; ++j) {
      bf16x8 b = *(const bf16x8*)&fc1T[((h*4 + j)*16 + fr)*72 + ks*32 + koff];
      hacc[j] = __builtin_amdgcn_mfma_f32_16x16x32_bf16(a, b, hacc[j], 0, 0, 0);
    }
  }
  #pragma unroll
  for (int j = 0; j < 4; ++j) {
    const int col = (h*4 + j)*16 + fr;
    const float bb = fc1_b[col];
    #pragma unroll
    for (int r = 0; r < 4; ++r) {
      const int row = s*16 + (l>>4)*4 + r;
      hbufB[(size_t)(g0 + row)*H1D + col] = f2b(fmaxf(hacc[j][r] + bb, 0.f));
    }
  }
}

// ================= Kernel 2: decoder GEMM ==========
__global__ __launch_bounds__(256, 4) void k2_decoder(
    const short* __restrict__ hbufB, const short* __restrict__ WT2g,
    const float* __restrict__ fc2_b, float* __restrict__ recon)
{
  __shared__ __align__(16) short Hb[32*136];
  __shared__ __align__(16) short Wt[96*136];
  const int bx = blockIdx.x, by = blockIdx.y;
  const int tid = threadIdx.x;
  const int w = tid >> 6, l = tid & 63;

  {
    const uint4* src = (const uint4*)(hbufB + (size_t)bx*32*H1D);
    for (int i = tid; i < 512; i += 256) {
      int r = i >> 4, k0 = (i & 15) * 8;
      *(uint4*)&Hb[r*136 + k0] = src[i];
    }
  }
  {
    const uint4* src = (const uint4*)(WT2g + (size_t)by*96*136);
    uint4* dst = (uint4*)Wt;
    for (int i = tid; i < 1632; i += 256) dst[i] = src[i];
  }
  __syncthreads();

  const int s = w >> 1;
  const int h = w & 1;
  const int fr = l & 15;
  const int koff = (l >> 4) * 8;

  f32x4 acc[3];
  #pragma unroll
  for (int t = 0; t < 3; ++t) acc[t] = (f32x4){0.f,0.f,0.f,0.f};

  #pragma unroll
  for (int ks = 0; ks < 4; ++ks) {
    bf16x8 a = *(const bf16x8*)&Hb[(s*16 + fr)*136 + ks*32 + koff];
    #pragma unroll
    for (int t = 0; t < 3; ++t) {
      bf16x8 b = *(const bf16x8*)&Wt[(h*48 + t*16 + fr)*136 + ks*32 + koff];
      acc[t] = __builtin_amdgcn_mfma_f32_16x16x32_bf16(a, b, acc[t], 0, 0, 0);
    }
  }

  #pragma unroll
  for (int t = 0; t < 3; ++t) {
    const int col = by*96 + h*48 + t*16 + fr;
    const float bb = fc2_b[col];
    #pragma unroll
    for (int r = 0; r < 4; ++r) {
      const int row = bx*32 + s*16 + (l>>4)*4 + r;
      float v = acc[t][r] + bb;
      recon[(size_t)row*OUTD + col] = 1.f/(1.f + __expf(-v));
    }
  }
}

extern "C" void kernel_launch(void* const* d_in, const int* in_sizes, int n_in,
                              void* d_out, int out_size, void* d_ws, size_t ws_size,
                              hipStream_t stream) {
  const float* x       = (const float*)d_in[0];
  const int*   ei      = (const int*)d_in[1];
  const float* eps     = (const float*)d_in[3];
  const float* w1_rel  = (const float*)d_in[4];
  const float* b1      = (const float*)d_in[5];
  const float* w1_root = (const float*)d_in[6];
  const float* w2_rel  = (const float*)d_in[7];
  const float* b2      = (const float*)d_in[8];
  const float* w2_root = (const float*)d_in[9];
  const float* w3_rel  = (const float*)d_in[10];
  const float* b3      = (const float*)d_in[11];
  const float* w3_root = (const float*)d_in[12];
  const float* fc1_w   = (const float*)d_in[13];
  const float* fc1_b   = (const float*)d_in[14];
  const float* fc2_w   = (const float*)d_in[15];
  const float* fc2_b   = (const float*)d_in[16];

  float* recon  = (float*)d_out;
  float* out_mu = recon + (size_t)NG*OUTD;
  float* out_lv = out_mu + (size_t)NG*H2D;

  char* p = (char*)d_ws;
  short* WTg   = (short*)p;              p += 128*136*2;        // 34816
  short* WT2g  = (short*)p;              p += 2016*136*2;       // 548352
  short* fc1T  = (short*)p;              p += 128*72*2;         // 18432
  short* W23T  = (short*)p;              p += 128*264*2;        // 67584
  short* SVg   = (short*)p;              p += (size_t)NG*256*2; // 1048576
  short* hbufB = (short*)p;                                     // 524288

  p_w1<<<64, 128, 0, stream>>>(w1_rel, w1_root, WTg);
  k1_encoder<<<NG + 69, 256, 0, stream>>>(x, ei, WTg, b1, SVg,
      fc2_w, w2_rel, w2_root, w3_rel, w3_root, fc1_w, WT2g, W23T, fc1T);
  k1b_latent<<<64, 256, 0, stream>>>(SVg, W23T, b2, b3, eps, fc1T, fc1_b,
                                     out_mu, out_lv, hbufB);
  k2_decoder<<<dim3(64, 21), 256, 0, stream>>>(hbufB, WT2g, fc2_b, recon);
}

// Round 7
// 157.172 us; speedup vs baseline: 9.7488x; 1.0340x over previous
//
#include <hip/hip_runtime.h>
#include <math.h>

#define NG 2048
#define NPG 64
#define EPG 512
#define ETOT (NG*EPG)
#define IND 64
#define H1D 128
#define H2D 64
#define OUTD 2016

typedef __attribute__((ext_vector_type(8))) short bf16x8;
typedef __attribute__((ext_vector_type(4))) float f32x4;

__device__ inline short f2b(float f) {
  union { float f; unsigned u; } v; v.f = f;
  unsigned r = (v.u + 0x7FFFu + ((v.u >> 16) & 1u)) >> 16;
  return (short)r;
}

// ---- pre-kernel: W1 -> frag-sequential layout WTgF[((ct*4+ks)*64+l)*8+j]
// col = ct*16+(l&15), k = ks*32+(l>>4)*8+j; k<64 -> w1_rel, else w1_root.
// A wave reading frag (ct,ks) loads 1KB contiguous (fully coalesced).
__global__ void p_w1(const float* __restrict__ w1_rel, const float* __restrict__ w1_root,
                     short* __restrict__ WTgF) {
  const int ct = blockIdx.x;             // 0..7
  const int ks = threadIdx.x >> 6, l = threadIdx.x & 63;
  const int col = ct*16 + (l & 15);
  const int kb  = ks*32 + (l >> 4)*8;
  short tmp[8];
  #pragma unroll
  for (int j = 0; j < 8; ++j) {
    const int k = kb + j;
    float v = (k < 64) ? w1_rel[k*H1D + col] : w1_root[(k - 64)*H1D + col];
    tmp[j] = f2b(v);
  }
  *(uint4*)&WTgF[(size_t)((ct*4 + ks)*64 + l)*8] = *(uint4*)tmp;
}

// ================= Kernel 1: per-graph encoder (+ folded weight transforms) ==========
// blocks 0..2047: encoder -> SVg. blocks 2048..2116: fc2->frag layout, w23T, fc1T.
// Encoder LDS = 42496 B -> 3 blocks/CU; only 4 __syncthreads on the block path.
__global__ __launch_bounds__(256, 3) void k1_encoder(
    const float* __restrict__ x, const int* __restrict__ ei,
    const short* __restrict__ WTgF, const float* __restrict__ b1,
    short* __restrict__ SVg,
    const float* __restrict__ fc2_w, const float* __restrict__ w2_rel, const float* __restrict__ w2_root,
    const float* __restrict__ w3_rel, const float* __restrict__ w3_root,
    const float* __restrict__ fc1_w,
    short* __restrict__ WF2g, short* __restrict__ W23T, short* __restrict__ fc1T)
{
  __shared__ __align__(16) char smem[42496];
  const int g = blockIdx.x;
  const int tid = threadIdx.x;

  if (g >= NG) {
    // ---------- folded transform path ----------
    float* L = (float*)smem;              // 33792 B <= 42496
    const int bid = g - NG;               // 0..68
    if (bid < 63) {                       // fc2 -> frag-sequential WF2g
      const int c0 = bid*32;
      for (int i = tid; i < 4096; i += 256) {
        int k = i >> 5, c = i & 31;
        L[k*33 + c] = fc2_w[(size_t)k*OUTD + c0 + c];
      }
      __syncthreads();
      const int tl = tid >> 7;            // local col-tile 0..1
      const int r  = tid & 127;
      const int ks = r >> 5;
      const int lp = r & 31;
      const int ct = bid*2 + tl;
      #pragma unroll
      for (int u = 0; u < 2; ++u) {
        const int l = lp*2 + u;
        const int cl = tl*16 + (l & 15);
        const int kb = ks*32 + (l >> 4)*8;
        short tmp[8];
        #pragma unroll
        for (int j = 0; j < 8; ++j) tmp[j] = f2b(L[(kb + j)*33 + cl]);
        *(uint4*)&WF2g[(size_t)((ct*4 + ks)*64 + l)*8] = *(uint4*)tmp;
      }
    } else if (bid < 67) {                // w2/w3 -> W23T (col-major pitch 264, for k1b)
      const int cc = bid - 63;
      const int j0 = cc*32;
      const float* wrel  = (cc < 2) ? w2_rel  : w3_rel;
      const float* wroot = (cc < 2) ? w2_root : w3_root;
      const int jl = j0 & 63;
      for (int i = tid; i < 4096; i += 256) {
        int k = i >> 5, c = i & 31;
        L[k*33 + c]        = wrel [k*H2D + jl + c];
        L[4224 + k*33 + c] = wroot[k*H2D + jl + c];
      }
      __syncthreads();
      const int c = tid >> 3, k0 = (tid & 7)*32;
      for (int kk = 0; kk < 32; ++kk) {
        int k = k0 + kk;
        float v = (k < 128) ? L[k*33 + c] : L[4224 + (k - 128)*33 + c];
        W23T[(size_t)(j0 + c)*264 + k] = f2b(v);
      }
    } else {                              // fc1 -> fc1T (pitch 72, for k1b)
      const int c0 = (bid - 67)*64;
      for (int i = tid; i < 4096; i += 256) {
        int k = i >> 6, c = i & 63;
        L[k*65 + c] = fc1_w[k*H1D + c0 + c];
      }
      __syncthreads();
      const int c = tid >> 2, k0 = (tid & 3)*16;
      for (int kk = 0; kk < 16; ++kk)
        fc1T[(size_t)(c0 + c)*72 + k0 + kk] = f2b(L[(k0 + kk)*65 + c]);
    }
    return;
  }

  // ---------- encoder path ----------
  short* Xb   = (short*)smem;               // 9216
  short* XbT  = (short*)(smem + 9216);      // 9216
  short* Ab   = (short*)(smem + 18432);     // 9216
  unsigned* Au32 = (unsigned*)(smem + 27648); // 64*17*4 = 4352 (packed u8 counts)
  short* AGb  = (short*)(smem + 32000);     // 9216 (separate -> phase1->2 is wave-local)
  float* deg  = (float*)(smem + 41216);     // 256
  float* hsum = (float*)(smem + 41472);     // 512
  float* wsum = (float*)(smem + 41984);     // 512

  const int w = tid >> 6, l = tid & 63;

  // hoist edge loads (HBM latency overlaps zero+stage)
  const int e0 = g*EPG + tid*2;
  const int s0 = ei[e0] & 63,     d0 = ei[ETOT + e0] & 63;
  const int s1 = ei[e0 + 1] & 63, d1 = ei[ETOT + e0 + 1] & 63;

  for (int i = tid; i < 64*17; i += 256) Au32[i] = 0u;
  if (tid < 128) { hsum[tid] = 0.f; wsum[tid] = 0.f; }

  // stage Xb (row-major bf16) + XbT (transposed bf16)
  {
    const int n = tid >> 2, f0 = (tid & 3) * 16;
    const float* xr = x + (size_t)g*(NPG*IND) + n*IND + f0;
    float4 v0 = *(const float4*)&xr[0];
    float4 v1 = *(const float4*)&xr[4];
    float4 v2 = *(const float4*)&xr[8];
    float4 v3 = *(const float4*)&xr[12];
    short b[16];
    b[0]=f2b(v0.x); b[1]=f2b(v0.y); b[2]=f2b(v0.z); b[3]=f2b(v0.w);
    b[4]=f2b(v1.x); b[5]=f2b(v1.y); b[6]=f2b(v1.z); b[7]=f2b(v1.w);
    b[8]=f2b(v2.x); b[9]=f2b(v2.y); b[10]=f2b(v2.z); b[11]=f2b(v2.w);
    b[12]=f2b(v3.x); b[13]=f2b(v3.y); b[14]=f2b(v3.z); b[15]=f2b(v3.w);
    short* xbp = &Xb[n*72 + f0];
    #pragma unroll
    for (int j = 0; j < 16; ++j) xbp[j] = b[j];
    #pragma unroll
    for (int j = 0; j < 16; ++j) XbT[(f0 + j)*72 + n] = b[j];
  }
  __syncthreads();                        // b1: zero/stage -> atomics

  // adjacency: packed u8 counts (4 cells per u32)
  atomicAdd(&Au32[d0*17 + (s0 >> 2)], 1u << (8*(s0 & 3)));
  atomicAdd(&Au32[d1*17 + (s1 >> 2)], 1u << (8*(s1 & 3)));
  __syncthreads();                        // b2: atomics -> cvt

  // cvt u8 -> bf16 into Ab (thread owns row, 16-col quarter); deg via SWAR on 16 threads
  {
    const int row = tid >> 2, qw = tid & 3;
    unsigned wds[4];
    #pragma unroll
    for (int q = 0; q < 4; ++q) wds[q] = Au32[row*17 + qw*4 + q];
    unsigned* abp = (unsigned*)&Ab[row*72 + qw*16];
    #pragma unroll
    for (int q = 0; q < 4; ++q) {
      unsigned wv = wds[q];
      #pragma unroll
      for (int p = 0; p < 2; ++p) {
        unsigned c0 = (wv >> (16*p)) & 255u, c1 = (wv >> (16*p + 8)) & 255u;
        abp[q*2 + p] = (unsigned)(unsigned short)f2b((float)c0)
                     | ((unsigned)(unsigned short)f2b((float)c1) << 16);
      }
    }
  }
  if (tid < 16) {   // deg[s]: byte-lane column sums (counts << 255, no carry)
    unsigned s = 0;
    #pragma unroll 8
    for (int d = 0; d < 64; ++d) s += Au32[d*17 + tid];
    deg[tid*4 + 0] = (float)(s & 255u);
    deg[tid*4 + 1] = (float)((s >> 8) & 255u);
    deg[tid*4 + 2] = (float)((s >> 16) & 255u);
    deg[tid*4 + 3] = (float)(s >> 24);
  }
  __syncthreads();                        // b3: cvt/deg -> phase1

  const int rm = w*16;
  const int fr = l & 15;
  const int koff = (l >> 4) * 8;

  // phase 1: AG = A @ X (M=64,N=64,K=64); wave strip rm..rm+15
  f32x4 agc[4];
  #pragma unroll
  for (int t = 0; t < 4; ++t) agc[t] = (f32x4){0.f,0.f,0.f,0.f};
  #pragma unroll
  for (int ks = 0; ks < 2; ++ks) {
    bf16x8 a = *(const bf16x8*)&Ab[(rm + fr)*72 + ks*32 + koff];
    #pragma unroll
    for (int t = 0; t < 4; ++t) {
      bf16x8 b = *(const bf16x8*)&XbT[(t*16 + fr)*72 + ks*32 + koff];
      agc[t] = __builtin_amdgcn_mfma_f32_16x16x32_bf16(a, b, agc[t], 0, 0, 0);
    }
  }
  // AGb is a separate buffer and wave w only touches rows rm..rm+15 -> NO barrier
  #pragma unroll
  for (int t = 0; t < 4; ++t)
    #pragma unroll
    for (int r = 0; r < 4; ++r)
      AGb[(rm + (l>>4)*4 + r)*72 + t*16 + fr] = f2b(agc[t][r]);

  // phase 2: h1pre = [AG|X] @ W1 (M=64,N=128,K=128), B-frags coalesced from global
  {
    float dg[4];
    #pragma unroll
    for (int r = 0; r < 4; ++r) dg[r] = deg[rm + (l>>4)*4 + r];

    bf16x8 afr[4];
    #pragma unroll
    for (int ks = 0; ks < 4; ++ks)
      afr[ks] = (ks < 2)
        ? *(const bf16x8*)&AGb[(rm + fr)*72 + ks*32 + koff]
        : *(const bf16x8*)&Xb[(rm + fr)*72 + (ks-2)*32 + koff];

    f32x4 acc[8];
    #pragma unroll
    for (int t = 0; t < 8; ++t) acc[t] = (f32x4){0.f,0.f,0.f,0.f};
    #pragma unroll
    for (int t = 0; t < 8; ++t)
      #pragma unroll
      for (int ks = 0; ks < 4; ++ks) {
        bf16x8 b = *(const bf16x8*)&WTgF[(size_t)((t*4 + ks)*64 + l)*8];
        acc[t] = __builtin_amdgcn_mfma_f32_16x16x32_bf16(afr[ks], b, acc[t], 0, 0, 0);
      }

    #pragma unroll
    for (int t = 0; t < 8; ++t) {
      const int col = t*16 + fr;
      const float bb = b1[col];
      float hs = 0.f, ws = 0.f;
      #pragma unroll
      for (int r = 0; r < 4; ++r) {
        float v = fmaxf(acc[t][r] + bb, 0.f);
        hs += v; ws += dg[r]*v;
      }
      hs += __shfl_down(hs, 32); ws += __shfl_down(ws, 32);
      hs += __shfl_down(hs, 16); ws += __shfl_down(ws, 16);
      if (l < 16) { atomicAdd(&hsum[col], hs); atomicAdd(&wsum[col], ws); }
    }
  }
  __syncthreads();                        // b4: sums -> write

  if (tid < 128) {
    SVg[(size_t)g*256 + tid]       = f2b(wsum[tid]);
    SVg[(size_t)g*256 + 128 + tid] = f2b(hsum[tid]);
  }
}

// ================= Kernel 1b: batched conv2/3-mean + reparam + fc1 ==========
__global__ __launch_bounds__(256) void k1b_latent(
    const short* __restrict__ SVg, const short* __restrict__ W23T,
    const float* __restrict__ b2, const float* __restrict__ b3,
    const float* __restrict__ eps, const short* __restrict__ fc1T,
    const float* __restrict__ fc1_b,
    float* __restrict__ out_mu, float* __restrict__ out_lv, short* __restrict__ hbufB)
{
  __shared__ short SV[32*264];
  __shared__ short Zt[32*72];
  const int g0 = blockIdx.x * 32;
  const int tid = threadIdx.x;
  const int w = tid >> 6, l = tid & 63;
  const int s = w >> 1;
  const int h = w & 1;
  const int fr = l & 15;
  const int koff = (l >> 4) * 8;

  {
    const uint4* src = (const uint4*)(SVg + (size_t)g0*256);
    for (int i = tid; i < 1024; i += 256) {
      int r = i >> 5, k0 = (i & 31) * 8;
      *(uint4*)&SV[r*264 + k0] = src[i];
    }
  }
  __syncthreads();

  f32x4 acc[4];
  #pragma unroll
  for (int t = 0; t < 4; ++t) acc[t] = (f32x4){0.f,0.f,0.f,0.f};
  #pragma unroll
  for (int ks = 0; ks < 8; ++ks) {
    bf16x8 a = *(const bf16x8*)&SV[(s*16 + fr)*264 + ks*32 + koff];
    #pragma unroll
    for (int j = 0; j < 2; ++j) {
      bf16x8 bm = *(const bf16x8*)&W23T[((2*h + j)*16 + fr)*264 + ks*32 + koff];
      bf16x8 bl = *(const bf16x8*)&W23T[((2*h + j + 4)*16 + fr)*264 + ks*32 + koff];
      acc[j]     = __builtin_amdgcn_mfma_f32_16x16x32_bf16(a, bm, acc[j], 0, 0, 0);
      acc[2 + j] = __builtin_amdgcn_mfma_f32_16x16x32_bf16(a, bl, acc[2 + j], 0, 0, 0);
    }
  }
  #pragma unroll
  for (int j = 0; j < 2; ++j) {
    const int col = (2*h + j)*16 + fr;
    const float bb2 = b2[col], bb3 = b3[col];
    #pragma unroll
    for (int r = 0; r < 4; ++r) {
      const int row = s*16 + (l>>4)*4 + r;
      const size_t gg = (size_t)(g0 + row);
      float mu = acc[j][r]     * (1.f/64.f) + bb2;
      float lv = acc[2 + j][r] * (1.f/64.f) + bb3;
      out_mu[gg*64 + col] = mu;
      out_lv[gg*64 + col] = lv;
      float z = mu + eps[gg*64 + col] * __expf(0.5f*lv);
      Zt[row*72 + col] = f2b(z);
    }
  }
  __syncthreads();

  f32x4 hacc[4];
  #pragma unroll
  for (int t = 0; t < 4; ++t) hacc[t] = (f32x4){0.f,0.f,0.f,0.f};
  #pragma unroll
  for (int ks = 0; ks < 2; ++ks) {
    bf16x8 a = *(const bf16x8*)&Zt[(s*16 + fr)*72 + ks*32 + koff];
    #pragma unroll
    for (int j = 0; j < 4; ++j) {
      bf16x8 b = *(const bf16x8*)&fc1T[((h*4 + j)*16 + fr)*72 + ks*32 + koff];
      hacc[j] = __builtin_amdgcn_mfma_f32_16x16x32_bf16(a, b, hacc[j], 0, 0, 0);
    }
  }
  #pragma unroll
  for (int j = 0; j < 4; ++j) {
    const int col = (h*4 + j)*16 + fr;
    const float bb = fc1_b[col];
    #pragma unroll
    for (int r = 0; r < 4; ++r) {
      const int row = s*16 + (l>>4)*4 + r;
      hbufB[(size_t)(g0 + row)*H1D + col] = f2b(fmaxf(hacc[j][r] + bb, 0.f));
    }
  }
}

// ================= Kernel 2: decoder GEMM (B-frags coalesced from global) ==========
// grid (32, 21): 64-row x 96-col tiles; wave w = 16-row strip, all 6 col-tiles.
__global__ __launch_bounds__(256, 4) void k2_decoder(
    const short* __restrict__ hbufB, const short* __restrict__ WF2g,
    const float* __restrict__ fc2_b, float* __restrict__ recon)
{
  __shared__ __align__(16) short Hb[64*136];
  const int bx = blockIdx.x, by = blockIdx.y;
  const int tid = threadIdx.x;
  const int w = tid >> 6, l = tid & 63;

  {
    const uint4* src = (const uint4*)(hbufB + (size_t)bx*64*H1D);
    for (int i = tid; i < 1024; i += 256) {
      int r = i >> 4, k0 = (i & 15) * 8;
      *(uint4*)&Hb[r*136 + k0] = src[i];
    }
  }
  __syncthreads();

  const int fr = l & 15;
  const int koff = (l >> 4) * 8;

  f32x4 acc[6];
  #pragma unroll
  for (int t = 0; t < 6; ++t) acc[t] = (f32x4){0.f,0.f,0.f,0.f};

  #pragma unroll
  for (int ks = 0; ks < 4; ++ks) {
    bf16x8 a = *(const bf16x8*)&Hb[(w*16 + fr)*136 + ks*32 + koff];
    #pragma unroll
    for (int t = 0; t < 6; ++t) {
      const int ct = by*6 + t;
      bf16x8 b = *(const bf16x8*)&WF2g[(size_t)((ct*4 + ks)*64 + l)*8];
      acc[t] = __builtin_amdgcn_mfma_f32_16x16x32_bf16(a, b, acc[t], 0, 0, 0);
    }
  }

  #pragma unroll
  for (int t = 0; t < 6; ++t) {
    const int col = by*96 + t*16 + fr;
    const float bb = fc2_b[col];
    #pragma unroll
    for (int r = 0; r < 4; ++r) {
      const int row = bx*64 + w*16 + (l>>4)*4 + r;
      float v = acc[t][r] + bb;
      recon[(size_t)row*OUTD + col] = 1.f/(1.f + __expf(-v));
    }
  }
}

extern "C" void kernel_launch(void* const* d_in, const int* in_sizes, int n_in,
                              void* d_out, int out_size, void* d_ws, size_t ws_size,
                              hipStream_t stream) {
  const float* x       = (const float*)d_in[0];
  const int*   ei      = (const int*)d_in[1];
  const float* eps     = (const float*)d_in[3];
  const float* w1_rel  = (const float*)d_in[4];
  const float* b1      = (const float*)d_in[5];
  const float* w1_root = (const float*)d_in[6];
  const float* w2_rel  = (const float*)d_in[7];
  const float* b2      = (const float*)d_in[8];
  const float* w2_root = (const float*)d_in[9];
  const float* w3_rel  = (const float*)d_in[10];
  const float* b3      = (const float*)d_in[11];
  const float* w3_root = (const float*)d_in[12];
  const float* fc1_w   = (const float*)d_in[13];
  const float* fc1_b   = (const float*)d_in[14];
  const float* fc2_w   = (const float*)d_in[15];
  const float* fc2_b   = (const float*)d_in[16];

  float* recon  = (float*)d_out;
  float* out_mu = recon + (size_t)NG*OUTD;
  float* out_lv = out_mu + (size_t)NG*H2D;

  char* p = (char*)d_ws;
  short* WTgF  = (short*)p;              p += 8*4*64*8*2;        // 32768
  short* WF2g  = (short*)p;              p += 126*4*64*8*2;      // 516096
  short* fc1T  = (short*)p;              p += 128*72*2;          // 18432
  short* W23T  = (short*)p;              p += 128*264*2;         // 67584
  short* SVg   = (short*)p;              p += (size_t)NG*256*2;  // 1048576
  short* hbufB = (short*)p;                                      // 524288

  p_w1<<<8, 256, 0, stream>>>(w1_rel, w1_root, WTgF);
  k1_encoder<<<NG + 69, 256, 0, stream>>>(x, ei, WTgF, b1, SVg,
      fc2_w, w2_rel, w2_root, w3_rel, w3_root, fc1_w, WF2g, W23T, fc1T);
  k1b_latent<<<64, 256, 0, stream>>>(SVg, W23T, b2, b3, eps, fc1T, fc1_b,
                                     out_mu, out_lv, hbufB);
  k2_decoder<<<dim3(32, 21), 256, 0, stream>>>(hbufB, WF2g, fc2_b, recon);
}

// Round 8
// 154.291 us; speedup vs baseline: 9.9308x; 1.0187x over previous
//
#include <hip/hip_runtime.h>
#include <math.h>

#define NG 2048
#define NPG 64
#define EPG 512
#define ETOT (NG*EPG)
#define IND 64
#define H1D 128
#define H2D 64
#define OUTD 2016

typedef __attribute__((ext_vector_type(8))) short bf16x8;
typedef __attribute__((ext_vector_type(4))) float f32x4;

__device__ inline short f2b(float f) {
  union { float f; unsigned u; } v; v.f = f;
  unsigned r = (v.u + 0x7FFFu + ((v.u >> 16) & 1u)) >> 16;
  return (short)r;
}

// ---- pre-kernel: W1 -> frag-sequential layout WTgF[((ct*4+ks)*64+l)*8+j]
__global__ void p_w1(const float* __restrict__ w1_rel, const float* __restrict__ w1_root,
                     short* __restrict__ WTgF) {
  const int ct = blockIdx.x;             // 0..7
  const int ks = threadIdx.x >> 6, l = threadIdx.x & 63;
  const int col = ct*16 + (l & 15);
  const int kb  = ks*32 + (l >> 4)*8;
  short tmp[8];
  #pragma unroll
  for (int j = 0; j < 8; ++j) {
    const int k = kb + j;
    float v = (k < 64) ? w1_rel[k*H1D + col] : w1_root[(k - 64)*H1D + col];
    tmp[j] = f2b(v);
  }
  *(uint4*)&WTgF[(size_t)((ct*4 + ks)*64 + l)*8] = *(uint4*)tmp;
}

// ================= Kernel 1: per-graph encoder (+ folded weight transforms) ==========
// Encoder LDS = 33280 B -> 4 blocks/CU (AGb overlays Ab: phase-1 A-frag reads and
// AGb writes are both wave-local to the same 16-row strip -> no barrier, no extra buf).
__global__ __launch_bounds__(256, 4) void k1_encoder(
    const float* __restrict__ x, const int* __restrict__ ei,
    const short* __restrict__ WTgF, const float* __restrict__ b1,
    short* __restrict__ SVg,
    const float* __restrict__ fc2_w, const float* __restrict__ w2_rel, const float* __restrict__ w2_root,
    const float* __restrict__ w3_rel, const float* __restrict__ w3_root,
    const float* __restrict__ fc1_w,
    short* __restrict__ WF2g, short* __restrict__ W23T, short* __restrict__ fc1T)
{
  __shared__ __align__(16) char smem[33792];   // 33280 used by encoder; 33792 for transforms
  const int g = blockIdx.x;
  const int tid = threadIdx.x;

  if (g >= NG) {
    // ---------- folded transform path ----------
    float* L = (float*)smem;              // 33792 B
    const int bid = g - NG;               // 0..68
    if (bid < 63) {                       // fc2 -> frag-sequential WF2g
      const int c0 = bid*32;
      for (int i = tid; i < 4096; i += 256) {
        int k = i >> 5, c = i & 31;
        L[k*33 + c] = fc2_w[(size_t)k*OUTD + c0 + c];
      }
      __syncthreads();
      const int tl = tid >> 7;
      const int r  = tid & 127;
      const int ks = r >> 5;
      const int lp = r & 31;
      const int ct = bid*2 + tl;
      #pragma unroll
      for (int u = 0; u < 2; ++u) {
        const int l = lp*2 + u;
        const int cl = tl*16 + (l & 15);
        const int kb = ks*32 + (l >> 4)*8;
        short tmp[8];
        #pragma unroll
        for (int j = 0; j < 8; ++j) tmp[j] = f2b(L[(kb + j)*33 + cl]);
        *(uint4*)&WF2g[(size_t)((ct*4 + ks)*64 + l)*8] = *(uint4*)tmp;
      }
    } else if (bid < 67) {                // w2/w3 -> W23T (pitch 264)
      const int cc = bid - 63;
      const int j0 = cc*32;
      const float* wrel  = (cc < 2) ? w2_rel  : w3_rel;
      const float* wroot = (cc < 2) ? w2_root : w3_root;
      const int jl = j0 & 63;
      for (int i = tid; i < 4096; i += 256) {
        int k = i >> 5, c = i & 31;
        L[k*33 + c]        = wrel [k*H2D + jl + c];
        L[4224 + k*33 + c] = wroot[k*H2D + jl + c];
      }
      __syncthreads();
      const int c = tid >> 3, k0 = (tid & 7)*32;
      for (int kk = 0; kk < 32; ++kk) {
        int k = k0 + kk;
        float v = (k < 128) ? L[k*33 + c] : L[4224 + (k - 128)*33 + c];
        W23T[(size_t)(j0 + c)*264 + k] = f2b(v);
      }
    } else {                              // fc1 -> fc1T (pitch 72)
      const int c0 = (bid - 67)*64;
      for (int i = tid; i < 4096; i += 256) {
        int k = i >> 6, c = i & 63;
        L[k*65 + c] = fc1_w[k*H1D + c0 + c];
      }
      __syncthreads();
      const int c = tid >> 2, k0 = (tid & 3)*16;
      for (int kk = 0; kk < 16; ++kk)
        fc1T[(size_t)(c0 + c)*72 + k0 + kk] = f2b(L[(k0 + kk)*65 + c]);
    }
    return;
  }

  // ---------- encoder path ----------
  // [0,9216) Xb | [9216,18432) XbT | [18432,27648) Ab (->AGb overlay, wave-local rows)
  // [27648,32000) Au32 | [32000,32256) deg | [32256,32768) hsum | [32768,33280) wsum
  short* Xb   = (short*)smem;
  short* XbT  = (short*)(smem + 9216);
  short* Ab   = (short*)(smem + 18432);
  unsigned* Au32 = (unsigned*)(smem + 27648);
  float* deg  = (float*)(smem + 32000);
  float* hsum = (float*)(smem + 32256);
  float* wsum = (float*)(smem + 32768);

  const int w = tid >> 6, l = tid & 63;

  // hoist edge loads (HBM latency overlaps zero+stage)
  const int e0 = g*EPG + tid*2;
  const int s0 = ei[e0] & 63,     d0 = ei[ETOT + e0] & 63;
  const int s1 = ei[e0 + 1] & 63, d1 = ei[ETOT + e0 + 1] & 63;

  for (int i = tid; i < 64*17; i += 256) Au32[i] = 0u;
  if (tid < 128) { hsum[tid] = 0.f; wsum[tid] = 0.f; }

  // stage Xb (row-major bf16) + XbT (transposed bf16)
  {
    const int n = tid >> 2, f0 = (tid & 3) * 16;
    const float* xr = x + (size_t)g*(NPG*IND) + n*IND + f0;
    float4 v0 = *(const float4*)&xr[0];
    float4 v1 = *(const float4*)&xr[4];
    float4 v2 = *(const float4*)&xr[8];
    float4 v3 = *(const float4*)&xr[12];
    short b[16];
    b[0]=f2b(v0.x); b[1]=f2b(v0.y); b[2]=f2b(v0.z); b[3]=f2b(v0.w);
    b[4]=f2b(v1.x); b[5]=f2b(v1.y); b[6]=f2b(v1.z); b[7]=f2b(v1.w);
    b[8]=f2b(v2.x); b[9]=f2b(v2.y); b[10]=f2b(v2.z); b[11]=f2b(v2.w);
    b[12]=f2b(v3.x); b[13]=f2b(v3.y); b[14]=f2b(v3.z); b[15]=f2b(v3.w);
    short* xbp = &Xb[n*72 + f0];
    #pragma unroll
    for (int j = 0; j < 16; ++j) xbp[j] = b[j];
    #pragma unroll
    for (int j = 0; j < 16; ++j) XbT[(f0 + j)*72 + n] = b[j];
  }
  __syncthreads();                        // b1: zero/stage -> atomics

  // adjacency: packed u8 counts (4 cells per u32)
  atomicAdd(&Au32[d0*17 + (s0 >> 2)], 1u << (8*(s0 & 3)));
  atomicAdd(&Au32[d1*17 + (s1 >> 2)], 1u << (8*(s1 & 3)));
  __syncthreads();                        // b2: atomics -> cvt

  // cvt u8 -> bf16 into Ab; rows are WAVE-LOCAL (wave w owns rows 16w..16w+15)
  {
    const int row = tid >> 2, qw = tid & 3;
    unsigned wds[4];
    #pragma unroll
    for (int q = 0; q < 4; ++q) wds[q] = Au32[row*17 + qw*4 + q];
    unsigned* abp = (unsigned*)&Ab[row*72 + qw*16];
    #pragma unroll
    for (int q = 0; q < 4; ++q) {
      unsigned wv = wds[q];
      #pragma unroll
      for (int p = 0; p < 2; ++p) {
        unsigned c0 = (wv >> (16*p)) & 255u, c1 = (wv >> (16*p + 8)) & 255u;
        abp[q*2 + p] = (unsigned)(unsigned short)f2b((float)c0)
                     | ((unsigned)(unsigned short)f2b((float)c1) << 16);
      }
    }
  }
  if (tid < 16) {   // deg: SWAR byte-lane column sums (published at b3, AFTER phase 1)
    unsigned s = 0;
    #pragma unroll 8
    for (int d = 0; d < 64; ++d) s += Au32[d*17 + tid];
    deg[tid*4 + 0] = (float)(s & 255u);
    deg[tid*4 + 1] = (float)((s >> 8) & 255u);
    deg[tid*4 + 2] = (float)((s >> 16) & 255u);
    deg[tid*4 + 3] = (float)(s >> 24);
  }

  const int rm = w*16;
  const int fr = l & 15;
  const int koff = (l >> 4) * 8;

  // phase 1: AG = A @ X — needs only own-wave Ab rows (just written) + XbT (b2-covered)
  f32x4 agc[4];
  #pragma unroll
  for (int t = 0; t < 4; ++t) agc[t] = (f32x4){0.f,0.f,0.f,0.f};
  #pragma unroll
  for (int ks = 0; ks < 2; ++ks) {
    bf16x8 a = *(const bf16x8*)&Ab[(rm + fr)*72 + ks*32 + koff];
    #pragma unroll
    for (int t = 0; t < 4; ++t) {
      bf16x8 b = *(const bf16x8*)&XbT[(t*16 + fr)*72 + ks*32 + koff];
      agc[t] = __builtin_amdgcn_mfma_f32_16x16x32_bf16(a, b, agc[t], 0, 0, 0);
    }
  }
  // overlay: write AG bf16 over own Ab rows (reads above already consumed them)
  short* AGb = Ab;
  #pragma unroll
  for (int t = 0; t < 4; ++t)
    #pragma unroll
    for (int r = 0; r < 4; ++r)
      AGb[(rm + (l>>4)*4 + r)*72 + t*16 + fr] = f2b(agc[t][r]);
  __syncthreads();                        // b3: publish deg (phase-1 already done)

  // phase 2: h1pre = [AG|X] @ W1, B-frags coalesced from global (L1/L2-hot)
  {
    float dg[4];
    #pragma unroll
    for (int r = 0; r < 4; ++r) dg[r] = deg[rm + (l>>4)*4 + r];

    bf16x8 afr[4];
    #pragma unroll
    for (int ks = 0; ks < 4; ++ks)
      afr[ks] = (ks < 2)
        ? *(const bf16x8*)&AGb[(rm + fr)*72 + ks*32 + koff]
        : *(const bf16x8*)&Xb[(rm + fr)*72 + (ks-2)*32 + koff];

    f32x4 acc[8];
    #pragma unroll
    for (int t = 0; t < 8; ++t) acc[t] = (f32x4){0.f,0.f,0.f,0.f};
    #pragma unroll
    for (int t = 0; t < 8; ++t)
      #pragma unroll
      for (int ks = 0; ks < 4; ++ks) {
        bf16x8 b = *(const bf16x8*)&WTgF[(size_t)((t*4 + ks)*64 + l)*8];
        acc[t] = __builtin_amdgcn_mfma_f32_16x16x32_bf16(afr[ks], b, acc[t], 0, 0, 0);
      }

    #pragma unroll
    for (int t = 0; t < 8; ++t) {
      const int col = t*16 + fr;
      const float bb = b1[col];
      float hs = 0.f, ws = 0.f;
      #pragma unroll
      for (int r = 0; r < 4; ++r) {
        float v = fmaxf(acc[t][r] + bb, 0.f);
        hs += v; ws += dg[r]*v;
      }
      hs += __shfl_down(hs, 32); ws += __shfl_down(ws, 32);
      hs += __shfl_down(hs, 16); ws += __shfl_down(ws, 16);
      if (l < 16) { atomicAdd(&hsum[col], hs); atomicAdd(&wsum[col], ws); }
    }
  }
  __syncthreads();                        // b4: sums -> write

  if (tid < 128) {
    SVg[(size_t)g*256 + tid]       = f2b(wsum[tid]);
    SVg[(size_t)g*256 + 128 + tid] = f2b(hsum[tid]);
  }
}

// ================= Kernel 1b: batched conv2/3-mean + reparam + fc1 ==========
__global__ __launch_bounds__(256) void k1b_latent(
    const short* __restrict__ SVg, const short* __restrict__ W23T,
    const float* __restrict__ b2, const float* __restrict__ b3,
    const float* __restrict__ eps, const short* __restrict__ fc1T,
    const float* __restrict__ fc1_b,
    float* __restrict__ out_mu, float* __restrict__ out_lv, short* __restrict__ hbufB)
{
  __shared__ short SV[32*264];
  __shared__ short Zt[32*72];
  const int g0 = blockIdx.x * 32;
  const int tid = threadIdx.x;
  const int w = tid >> 6, l = tid & 63;
  const int s = w >> 1;
  const int h = w & 1;
  const int fr = l & 15;
  const int koff = (l >> 4) * 8;

  {
    const uint4* src = (const uint4*)(SVg + (size_t)g0*256);
    for (int i = tid; i < 1024; i += 256) {
      int r = i >> 5, k0 = (i & 31) * 8;
      *(uint4*)&SV[r*264 + k0] = src[i];
    }
  }
  __syncthreads();

  f32x4 acc[4];
  #pragma unroll
  for (int t = 0; t < 4; ++t) acc[t] = (f32x4){0.f,0.f,0.f,0.f};
  #pragma unroll
  for (int ks = 0; ks < 8; ++ks) {
    bf16x8 a = *(const bf16x8*)&SV[(s*16 + fr)*264 + ks*32 + koff];
    #pragma unroll
    for (int j = 0; j < 2; ++j) {
      bf16x8 bm = *(const bf16x8*)&W23T[((2*h + j)*16 + fr)*264 + ks*32 + koff];
      bf16x8 bl = *(const bf16x8*)&W23T[((2*h + j + 4)*16 + fr)*264 + ks*32 + koff];
      acc[j]     = __builtin_amdgcn_mfma_f32_16x16x32_bf16(a, bm, acc[j], 0, 0, 0);
      acc[2 + j] = __builtin_amdgcn_mfma_f32_16x16x32_bf16(a, bl, acc[2 + j], 0, 0, 0);
    }
  }
  #pragma unroll
  for (int j = 0; j < 2; ++j) {
    const int col = (2*h + j)*16 + fr;
    const float bb2 = b2[col], bb3 = b3[col];
    #pragma unroll
    for (int r = 0; r < 4; ++r) {
      const int row = s*16 + (l>>4)*4 + r;
      const size_t gg = (size_t)(g0 + row);
      float mu = acc[j][r]     * (1.f/64.f) + bb2;
      float lv = acc[2 + j][r] * (1.f/64.f) + bb3;
      out_mu[gg*64 + col] = mu;
      out_lv[gg*64 + col] = lv;
      float z = mu + eps[gg*64 + col] * __expf(0.5f*lv);
      Zt[row*72 + col] = f2b(z);
    }
  }
  __syncthreads();

  f32x4 hacc[4];
  #pragma unroll
  for (int t = 0; t < 4; ++t) hacc[t] = (f32x4){0.f,0.f,0.f,0.f};
  #pragma unroll
  for (int ks = 0; ks < 2; ++ks) {
    bf16x8 a = *(const bf16x8*)&Zt[(s*16 + fr)*72 + ks*32 + koff];
    #pragma unroll
    for (int j = 0; j < 4; ++j) {
      bf16x8 b = *(const bf16x8*)&fc1T[((h*4 + j)*16 + fr)*72 + ks*32 + koff];
      hacc[j] = __builtin_amdgcn_mfma_f32_16x16x32_bf16(a, b, hacc[j], 0, 0, 0);
    }
  }
  #pragma unroll
  for (int j = 0; j < 4; ++j) {
    const int col = (h*4 + j)*16 + fr;
    const float bb = fc1_b[col];
    #pragma unroll
    for (int r = 0; r < 4; ++r) {
      const int row = s*16 + (l>>4)*4 + r;
      hbufB[(size_t)(g0 + row)*H1D + col] = f2b(fmaxf(hacc[j][r] + bb, 0.f));
    }
  }
}

// ================= Kernel 2: decoder GEMM (B-frags coalesced from global) ==========
__global__ __launch_bounds__(256, 4) void k2_decoder(
    const short* __restrict__ hbufB, const short* __restrict__ WF2g,
    const float* __restrict__ fc2_b, float* __restrict__ recon)
{
  __shared__ __align__(16) short Hb[64*136];
  const int bx = blockIdx.x, by = blockIdx.y;
  const int tid = threadIdx.x;
  const int w = tid >> 6, l = tid & 63;

  {
    const uint4* src = (const uint4*)(hbufB + (size_t)bx*64*H1D);
    for (int i = tid; i < 1024; i += 256) {
      int r = i >> 4, k0 = (i & 15) * 8;
      *(uint4*)&Hb[r*136 + k0] = src[i];
    }
  }
  __syncthreads();

  const int fr = l & 15;
  const int koff = (l >> 4) * 8;

  f32x4 acc[6];
  #pragma unroll
  for (int t = 0; t < 6; ++t) acc[t] = (f32x4){0.f,0.f,0.f,0.f};

  #pragma unroll
  for (int ks = 0; ks < 4; ++ks) {
    bf16x8 a = *(const bf16x8*)&Hb[(w*16 + fr)*136 + ks*32 + koff];
    #pragma unroll
    for (int t = 0; t < 6; ++t) {
      const int ct = by*6 + t;
      bf16x8 b = *(const bf16x8*)&WF2g[(size_t)((ct*4 + ks)*64 + l)*8];
      acc[t] = __builtin_amdgcn_mfma_f32_16x16x32_bf16(a, b, acc[t], 0, 0, 0);
    }
  }

  #pragma unroll
  for (int t = 0; t < 6; ++t) {
    const int col = by*96 + t*16 + fr;
    const float bb = fc2_b[col];
    #pragma unroll
    for (int r = 0; r < 4; ++r) {
      const int row = bx*64 + w*16 + (l>>4)*4 + r;
      float v = acc[t][r] + bb;
      recon[(size_t)row*OUTD + col] = 1.f/(1.f + __expf(-v));
    }
  }
}

extern "C" void kernel_launch(void* const* d_in, const int* in_sizes, int n_in,
                              void* d_out, int out_size, void* d_ws, size_t ws_size,
                              hipStream_t stream) {
  const float* x       = (const float*)d_in[0];
  const int*   ei      = (const int*)d_in[1];
  const float* eps     = (const float*)d_in[3];
  const float* w1_rel  = (const float*)d_in[4];
  const float* b1      = (const float*)d_in[5];
  const float* w1_root = (const float*)d_in[6];
  const float* w2_rel  = (const float*)d_in[7];
  const float* b2      = (const float*)d_in[8];
  const float* w2_root = (const float*)d_in[9];
  const float* w3_rel  = (const float*)d_in[10];
  const float* b3      = (const float*)d_in[11];
  const float* w3_root = (const float*)d_in[12];
  const float* fc1_w   = (const float*)d_in[13];
  const float* fc1_b   = (const float*)d_in[14];
  const float* fc2_w   = (const float*)d_in[15];
  const float* fc2_b   = (const float*)d_in[16];

  float* recon  = (float*)d_out;
  float* out_mu = recon + (size_t)NG*OUTD;
  float* out_lv = out_mu + (size_t)NG*H2D;

  char* p = (char*)d_ws;
  short* WTgF  = (short*)p;              p += 8*4*64*8*2;        // 32768
  short* WF2g  = (short*)p;              p += 126*4*64*8*2;      // 516096
  short* fc1T  = (short*)p;              p += 128*72*2;          // 18432
  short* W23T  = (short*)p;              p += 128*264*2;         // 67584
  short* SVg   = (short*)p;              p += (size_t)NG*256*2;  // 1048576
  short* hbufB = (short*)p;                                      // 524288

  p_w1<<<8, 256, 0, stream>>>(w1_rel, w1_root, WTgF);
  k1_encoder<<<NG + 69, 256, 0, stream>>>(x, ei, WTgF, b1, SVg,
      fc2_w, w2_rel, w2_root, w3_rel, w3_root, fc1_w, WF2g, W23T, fc1T);
  k1b_latent<<<64, 256, 0, stream>>>(SVg, W23T, b2, b3, eps, fc1T, fc1_b,
                                     out_mu, out_lv, hbufB);
  k2_decoder<<<dim3(32, 21), 256, 0, stream>>>(hbufB, WF2g, fc2_b, recon);
}

// Round 9
// 152.061 us; speedup vs baseline: 10.0764x; 1.0147x over previous
//
#include <hip/hip_runtime.h>
#include <math.h>

#define NG 2048
#define NPG 64
#define EPG 512
#define ETOT (NG*EPG)
#define IND 64
#define H1D 128
#define H2D 64
#define OUTD 2016

typedef __attribute__((ext_vector_type(8))) short bf16x8;
typedef __attribute__((ext_vector_type(4))) float f32x4;

__device__ inline short f2b(float f) {
  union { float f; unsigned u; } v; v.f = f;
  unsigned r = (v.u + 0x7FFFu + ((v.u >> 16) & 1u)) >> 16;
  return (short)r;
}

// ---- pre-kernel: W1 -> frag-sequential layout WTgF[((ct*4+ks)*64+l)*8+j]
__global__ void p_w1(const float* __restrict__ w1_rel, const float* __restrict__ w1_root,
                     short* __restrict__ WTgF) {
  const int ct = blockIdx.x;             // 0..7
  const int ks = threadIdx.x >> 6, l = threadIdx.x & 63;
  const int col = ct*16 + (l & 15);
  const int kb  = ks*32 + (l >> 4)*8;
  short tmp[8];
  #pragma unroll
  for (int j = 0; j < 8; ++j) {
    const int k = kb + j;
    float v = (k < 64) ? w1_rel[k*H1D + col] : w1_root[(k - 64)*H1D + col];
    tmp[j] = f2b(v);
  }
  *(uint4*)&WTgF[(size_t)((ct*4 + ks)*64 + l)*8] = *(uint4*)tmp;
}

// ================= Kernel 1: per-graph encoder (+ folded weight transforms) ==========
// Encoder LDS = 32768 B EXACTLY -> 5 blocks/CU (20 waves/CU). deg is computed
// per-wave in registers via SWAR shfl-reduce (no LDS array, no serial wave-0 loop).
__global__ __launch_bounds__(256, 5) void k1_encoder(
    const float* __restrict__ x, const int* __restrict__ ei,
    const short* __restrict__ WTgF, const float* __restrict__ b1,
    short* __restrict__ SVg,
    const float* __restrict__ fc2_w, const float* __restrict__ w2_rel, const float* __restrict__ w2_root,
    const float* __restrict__ w3_rel, const float* __restrict__ w3_root,
    const float* __restrict__ fc1_w,
    short* __restrict__ WF2g, short* __restrict__ W23T, short* __restrict__ fc1T)
{
  __shared__ __align__(16) char smem[32768];
  const int g = blockIdx.x;
  const int tid = threadIdx.x;

  if (g >= NG) {
    // ---------- folded transform path (LDS use <= 16896 B) ----------
    float* L = (float*)smem;
    const int bid = g - NG;               // 0..68
    if (bid < 63) {                       // fc2 -> frag-sequential WF2g
      const int c0 = bid*32;
      for (int i = tid; i < 4096; i += 256) {
        int k = i >> 5, c = i & 31;
        L[k*33 + c] = fc2_w[(size_t)k*OUTD + c0 + c];
      }
      __syncthreads();
      const int tl = tid >> 7;
      const int r  = tid & 127;
      const int ks = r >> 5;
      const int lp = r & 31;
      const int ct = bid*2 + tl;
      #pragma unroll
      for (int u = 0; u < 2; ++u) {
        const int l = lp*2 + u;
        const int cl = tl*16 + (l & 15);
        const int kb = ks*32 + (l >> 4)*8;
        short tmp[8];
        #pragma unroll
        for (int j = 0; j < 8; ++j) tmp[j] = f2b(L[(kb + j)*33 + cl]);
        *(uint4*)&WF2g[(size_t)((ct*4 + ks)*64 + l)*8] = *(uint4*)tmp;
      }
    } else if (bid < 67) {                // w2/w3 -> W23T (pitch 264), two passes
      const int cc = bid - 63;
      const int j0 = cc*32;
      const float* wrel  = (cc < 2) ? w2_rel  : w3_rel;
      const float* wroot = (cc < 2) ? w2_root : w3_root;
      const int jl = j0 & 63;
      const int c = tid >> 3, k0 = (tid & 7)*32;
      // pass 1: rel half (k 0..127)
      for (int i = tid; i < 4096; i += 256) {
        int k = i >> 5, cc2 = i & 31;
        L[k*33 + cc2] = wrel[k*H2D + jl + cc2];
      }
      __syncthreads();
      if (k0 < 128)
        for (int kk = 0; kk < 32; ++kk)
          W23T[(size_t)(j0 + c)*264 + k0 + kk] = f2b(L[(k0 + kk)*33 + c]);
      __syncthreads();
      // pass 2: root half (k 128..255)
      for (int i = tid; i < 4096; i += 256) {
        int k = i >> 5, cc2 = i & 31;
        L[k*33 + cc2] = wroot[k*H2D + jl + cc2];
      }
      __syncthreads();
      if (k0 >= 128)
        for (int kk = 0; kk < 32; ++kk)
          W23T[(size_t)(j0 + c)*264 + k0 + kk] = f2b(L[(k0 + kk - 128)*33 + c]);
    } else {                              // fc1 -> fc1T (pitch 72)
      const int c0 = (bid - 67)*64;
      for (int i = tid; i < 4096; i += 256) {
        int k = i >> 6, c = i & 63;
        L[k*65 + c] = fc1_w[k*H1D + c0 + c];
      }
      __syncthreads();
      const int c = tid >> 2, k0 = (tid & 3)*16;
      for (int kk = 0; kk < 16; ++kk)
        fc1T[(size_t)(c0 + c)*72 + k0 + kk] = f2b(L[(k0 + kk)*65 + c]);
    }
    return;
  }

  // ---------- encoder path ----------
  // [0,9216) Xb | [9216,18432) XbT | [18432,27648) Ab (->AGb overlay, wave-local rows)
  // [27648,31744) Au32 (64x16 words, packed u8 counts) | [31744,32256) hsum | [32256,32768) wsum
  short* Xb   = (short*)smem;
  short* XbT  = (short*)(smem + 9216);
  short* Ab   = (short*)(smem + 18432);
  unsigned* Au32 = (unsigned*)(smem + 27648);
  float* hsum = (float*)(smem + 31744);
  float* wsum = (float*)(smem + 32256);

  const int w = tid >> 6, l = tid & 63;

  // hoist edge loads (HBM latency overlaps zero+stage)
  const int e0 = g*EPG + tid*2;
  const int s0 = ei[e0] & 63,     d0 = ei[ETOT + e0] & 63;
  const int s1 = ei[e0 + 1] & 63, d1 = ei[ETOT + e0 + 1] & 63;

  for (int i = tid; i < 64*16; i += 256) Au32[i] = 0u;
  if (tid < 128) { hsum[tid] = 0.f; wsum[tid] = 0.f; }

  // stage Xb (row-major bf16) + XbT (transposed bf16)
  {
    const int n = tid >> 2, f0 = (tid & 3) * 16;
    const float* xr = x + (size_t)g*(NPG*IND) + n*IND + f0;
    float4 v0 = *(const float4*)&xr[0];
    float4 v1 = *(const float4*)&xr[4];
    float4 v2 = *(const float4*)&xr[8];
    float4 v3 = *(const float4*)&xr[12];
    short b[16];
    b[0]=f2b(v0.x); b[1]=f2b(v0.y); b[2]=f2b(v0.z); b[3]=f2b(v0.w);
    b[4]=f2b(v1.x); b[5]=f2b(v1.y); b[6]=f2b(v1.z); b[7]=f2b(v1.w);
    b[8]=f2b(v2.x); b[9]=f2b(v2.y); b[10]=f2b(v2.z); b[11]=f2b(v2.w);
    b[12]=f2b(v3.x); b[13]=f2b(v3.y); b[14]=f2b(v3.z); b[15]=f2b(v3.w);
    short* xbp = &Xb[n*72 + f0];
    #pragma unroll
    for (int j = 0; j < 16; ++j) xbp[j] = b[j];
    #pragma unroll
    for (int j = 0; j < 16; ++j) XbT[(f0 + j)*72 + n] = b[j];
  }
  __syncthreads();                        // b1: zero/stage -> atomics

  // adjacency: packed u8 counts (4 cells per u32, pitch 16 words)
  atomicAdd(&Au32[d0*16 + (s0 >> 2)], 1u << (8*(s0 & 3)));
  atomicAdd(&Au32[d1*16 + (s1 >> 2)], 1u << (8*(s1 & 3)));
  __syncthreads();                        // b2: atomics -> cvt

  // cvt u8 -> bf16 into Ab; rows are WAVE-LOCAL (wave w owns rows 16w..16w+15)
  {
    const int row = tid >> 2, qw = tid & 3;
    unsigned wds[4];
    #pragma unroll
    for (int q = 0; q < 4; ++q) wds[q] = Au32[row*16 + qw*4 + q];
    unsigned* abp = (unsigned*)&Ab[row*72 + qw*16];
    #pragma unroll
    for (int q = 0; q < 4; ++q) {
      unsigned wv = wds[q];
      #pragma unroll
      for (int p = 0; p < 2; ++p) {
        unsigned c0 = (wv >> (16*p)) & 255u, c1 = (wv >> (16*p + 8)) & 255u;
        abp[q*2 + p] = (unsigned)(unsigned short)f2b((float)c0)
                     | ((unsigned)(unsigned short)f2b((float)c1) << 16);
      }
    }
  }

  // deg (out-degree of sources 16w..16w+15) per-wave in registers:
  // lane l sums word (4w + (l&3)) over rows d = (l>>2) + 16i, SWAR byte lanes.
  float dg[4];
  {
    unsigned ps = 0;
    #pragma unroll
    for (int i = 0; i < 4; ++i) ps += Au32[((l >> 2) + 16*i)*16 + 4*w + (l & 3)];
    ps += __shfl_xor(ps, 4);
    ps += __shfl_xor(ps, 8);
    ps += __shfl_xor(ps, 16);
    ps += __shfl_xor(ps, 32);
    // lane l needs word 4w + (l>>4); lanes 0..3 hold words 4w+0..3 after reduce
    unsigned dword = __shfl(ps, (l >> 4));
    dg[0] = (float)(dword & 255u);
    dg[1] = (float)((dword >> 8) & 255u);
    dg[2] = (float)((dword >> 16) & 255u);
    dg[3] = (float)(dword >> 24);
  }

  const int rm = w*16;
  const int fr = l & 15;
  const int koff = (l >> 4) * 8;

  // phase 1: AG = A @ X — needs only own-wave Ab rows (just written) + XbT (b2-covered)
  f32x4 agc[4];
  #pragma unroll
  for (int t = 0; t < 4; ++t) agc[t] = (f32x4){0.f,0.f,0.f,0.f};
  #pragma unroll
  for (int ks = 0; ks < 2; ++ks) {
    bf16x8 a = *(const bf16x8*)&Ab[(rm + fr)*72 + ks*32 + koff];
    #pragma unroll
    for (int t = 0; t < 4; ++t) {
      bf16x8 b = *(const bf16x8*)&XbT[(t*16 + fr)*72 + ks*32 + koff];
      agc[t] = __builtin_amdgcn_mfma_f32_16x16x32_bf16(a, b, agc[t], 0, 0, 0);
    }
  }
  // overlay: write AG bf16 over own Ab rows (reads above already consumed them)
  short* AGb = Ab;
  #pragma unroll
  for (int t = 0; t < 4; ++t)
    #pragma unroll
    for (int r = 0; r < 4; ++r)
      AGb[(rm + (l>>4)*4 + r)*72 + t*16 + fr] = f2b(agc[t][r]);
  __syncthreads();                        // b3: all waves' Ab->AGb settled (phase-1 done)

  // phase 2: h1pre = [AG|X] @ W1, B-frags coalesced from global (L1/L2-hot)
  {
    bf16x8 afr[4];
    #pragma unroll
    for (int ks = 0; ks < 4; ++ks)
      afr[ks] = (ks < 2)
        ? *(const bf16x8*)&AGb[(rm + fr)*72 + ks*32 + koff]
        : *(const bf16x8*)&Xb[(rm + fr)*72 + (ks-2)*32 + koff];

    f32x4 acc[8];
    #pragma unroll
    for (int t = 0; t < 8; ++t) acc[t] = (f32x4){0.f,0.f,0.f,0.f};
    #pragma unroll
    for (int t = 0; t < 8; ++t)
      #pragma unroll
      for (int ks = 0; ks < 4; ++ks) {
        bf16x8 b = *(const bf16x8*)&WTgF[(size_t)((t*4 + ks)*64 + l)*8];
        acc[t] = __builtin_amdgcn_mfma_f32_16x16x32_bf16(afr[ks], b, acc[t], 0, 0, 0);
      }

    #pragma unroll
    for (int t = 0; t < 8; ++t) {
      const int col = t*16 + fr;
      const float bb = b1[col];
      float hs = 0.f, ws = 0.f;
      #pragma unroll
      for (int r = 0; r < 4; ++r) {
        float v = fmaxf(acc[t][r] + bb, 0.f);
        hs += v; ws += dg[r]*v;
      }
      hs += __shfl_down(hs, 32); ws += __shfl_down(ws, 32);
      hs += __shfl_down(hs, 16); ws += __shfl_down(ws, 16);
      if (l < 16) { atomicAdd(&hsum[col], hs); atomicAdd(&wsum[col], ws); }
    }
  }
  __syncthreads();                        // b4: sums -> write

  if (tid < 128) {
    SVg[(size_t)g*256 + tid]       = f2b(wsum[tid]);
    SVg[(size_t)g*256 + 128 + tid] = f2b(hsum[tid]);
  }
}

// ================= Kernel 1b: batched conv2/3-mean + reparam + fc1 ==========
__global__ __launch_bounds__(256) void k1b_latent(
    const short* __restrict__ SVg, const short* __restrict__ W23T,
    const float* __restrict__ b2, const float* __restrict__ b3,
    const float* __restrict__ eps, const short* __restrict__ fc1T,
    const float* __restrict__ fc1_b,
    float* __restrict__ out_mu, float* __restrict__ out_lv, short* __restrict__ hbufB)
{
  __shared__ short SV[32*264];
  __shared__ short Zt[32*72];
  const int g0 = blockIdx.x * 32;
  const int tid = threadIdx.x;
  const int w = tid >> 6, l = tid & 63;
  const int s = w >> 1;
  const int h = w & 1;
  const int fr = l & 15;
  const int koff = (l >> 4) * 8;

  {
    const uint4* src = (const uint4*)(SVg + (size_t)g0*256);
    for (int i = tid; i < 1024; i += 256) {
      int r = i >> 5, k0 = (i & 31) * 8;
      *(uint4*)&SV[r*264 + k0] = src[i];
    }
  }
  __syncthreads();

  f32x4 acc[4];
  #pragma unroll
  for (int t = 0; t < 4; ++t) acc[t] = (f32x4){0.f,0.f,0.f,0.f};
  #pragma unroll
  for (int ks = 0; ks < 8; ++ks) {
    bf16x8 a = *(const bf16x8*)&SV[(s*16 + fr)*264 + ks*32 + koff];
    #pragma unroll
    for (int j = 0; j < 2; ++j) {
      bf16x8 bm = *(const bf16x8*)&W23T[((2*h + j)*16 + fr)*264 + ks*32 + koff];
      bf16x8 bl = *(const bf16x8*)&W23T[((2*h + j + 4)*16 + fr)*264 + ks*32 + koff];
      acc[j]     = __builtin_amdgcn_mfma_f32_16x16x32_bf16(a, bm, acc[j], 0, 0, 0);
      acc[2 + j] = __builtin_amdgcn_mfma_f32_16x16x32_bf16(a, bl, acc[2 + j], 0, 0, 0);
    }
  }
  #pragma unroll
  for (int j = 0; j < 2; ++j) {
    const int col = (2*h + j)*16 + fr;
    const float bb2 = b2[col], bb3 = b3[col];
    #pragma unroll
    for (int r = 0; r < 4; ++r) {
      const int row = s*16 + (l>>4)*4 + r;
      const size_t gg = (size_t)(g0 + row);
      float mu = acc[j][r]     * (1.f/64.f) + bb2;
      float lv = acc[2 + j][r] * (1.f/64.f) + bb3;
      out_mu[gg*64 + col] = mu;
      out_lv[gg*64 + col] = lv;
      float z = mu + eps[gg*64 + col] * __expf(0.5f*lv);
      Zt[row*72 + col] = f2b(z);
    }
  }
  __syncthreads();

  f32x4 hacc[4];
  #pragma unroll
  for (int t = 0; t < 4; ++t) hacc[t] = (f32x4){0.f,0.f,0.f,0.f};
  #pragma unroll
  for (int ks = 0; ks < 2; ++ks) {
    bf16x8 a = *(const bf16x8*)&Zt[(s*16 + fr)*72 + ks*32 + koff];
    #pragma unroll
    for (int j = 0; j < 4; ++j) {
      bf16x8 b = *(const bf16x8*)&fc1T[((h*4 + j)*16 + fr)*72 + ks*32 + koff];
      hacc[j] = __builtin_amdgcn_mfma_f32_16x16x32_bf16(a, b, hacc[j], 0, 0, 0);
    }
  }
  #pragma unroll
  for (int j = 0; j < 4; ++j) {
    const int col = (h*4 + j)*16 + fr;
    const float bb = fc1_b[col];
    #pragma unroll
    for (int r = 0; r < 4; ++r) {
      const int row = s*16 + (l>>4)*4 + r;
      hbufB[(size_t)(g0 + row)*H1D + col] = f2b(fmaxf(hacc[j][r] + bb, 0.f));
    }
  }
}

// ================= Kernel 2: decoder GEMM (B-frags coalesced from global) ==========
__global__ __launch_bounds__(256, 4) void k2_decoder(
    const short* __restrict__ hbufB, const short* __restrict__ WF2g,
    const float* __restrict__ fc2_b, float* __restrict__ recon)
{
  __shared__ __align__(16) short Hb[64*136];
  const int bx = blockIdx.x, by = blockIdx.y;
  const int tid = threadIdx.x;
  const int w = tid >> 6, l = tid & 63;

  {
    const uint4* src = (const uint4*)(hbufB + (size_t)bx*64*H1D);
    for (int i = tid; i < 1024; i += 256) {
      int r = i >> 4, k0 = (i & 15) * 8;
      *(uint4*)&Hb[r*136 + k0] = src[i];
    }
  }
  __syncthreads();

  const int fr = l & 15;
  const int koff = (l >> 4) * 8;

  f32x4 acc[6];
  #pragma unroll
  for (int t = 0; t < 6; ++t) acc[t] = (f32x4){0.f,0.f,0.f,0.f};

  #pragma unroll
  for (int ks = 0; ks < 4; ++ks) {
    bf16x8 a = *(const bf16x8*)&Hb[(w*16 + fr)*136 + ks*32 + koff];
    #pragma unroll
    for (int t = 0; t < 6; ++t) {
      const int ct = by*6 + t;
      bf16x8 b = *(const bf16x8*)&WF2g[(size_t)((ct*4 + ks)*64 + l)*8];
      acc[t] = __builtin_amdgcn_mfma_f32_16x16x32_bf16(a, b, acc[t], 0, 0, 0);
    }
  }

  #pragma unroll
  for (int t = 0; t < 6; ++t) {
    const int col = by*96 + t*16 + fr;
    const float bb = fc2_b[col];
    #pragma unroll
    for (int r = 0; r < 4; ++r) {
      const int row = bx*64 + w*16 + (l>>4)*4 + r;
      float v = acc[t][r] + bb;
      recon[(size_t)row*OUTD + col] = 1.f/(1.f + __expf(-v));
    }
  }
}

extern "C" void kernel_launch(void* const* d_in, const int* in_sizes, int n_in,
                              void* d_out, int out_size, void* d_ws, size_t ws_size,
                              hipStream_t stream) {
  const float* x       = (const float*)d_in[0];
  const int*   ei      = (const int*)d_in[1];
  const float* eps     = (const float*)d_in[3];
  const float* w1_rel  = (const float*)d_in[4];
  const float* b1      = (const float*)d_in[5];
  const float* w1_root = (const float*)d_in[6];
  const float* w2_rel  = (const float*)d_in[7];
  const float* b2      = (const float*)d_in[8];
  const float* w2_root = (const float*)d_in[9];
  const float* w3_rel  = (const float*)d_in[10];
  const float* b3      = (const float*)d_in[11];
  const float* w3_root = (const float*)d_in[12];
  const float* fc1_w   = (const float*)d_in[13];
  const float* fc1_b   = (const float*)d_in[14];
  const float* fc2_w   = (const float*)d_in[15];
  const float* fc2_b   = (const float*)d_in[16];

  float* recon  = (float*)d_out;
  float* out_mu = recon + (size_t)NG*OUTD;
  float* out_lv = out_mu + (size_t)NG*H2D;

  char* p = (char*)d_ws;
  short* WTgF  = (short*)p;              p += 8*4*64*8*2;        // 32768
  short* WF2g  = (short*)p;              p += 126*4*64*8*2;      // 516096
  short* fc1T  = (short*)p;              p += 128*72*2;          // 18432
  short* W23T  = (short*)p;              p += 128*264*2;         // 67584
  short* SVg   = (short*)p;              p += (size_t)NG*256*2;  // 1048576
  short* hbufB = (short*)p;                                      // 524288

  p_w1<<<8, 256, 0, stream>>>(w1_rel, w1_root, WTgF);
  k1_encoder<<<NG + 69, 256, 0, stream>>>(x, ei, WTgF, b1, SVg,
      fc2_w, w2_rel, w2_root, w3_rel, w3_root, fc1_w, WF2g, W23T, fc1T);
  k1b_latent<<<64, 256, 0, stream>>>(SVg, W23T, b2, b3, eps, fc1T, fc1_b,
                                     out_mu, out_lv, hbufB);
  k2_decoder<<<dim3(32, 21), 256, 0, stream>>>(hbufB, WF2g, fc2_b, recon);
}

// Round 10
// 145.802 us; speedup vs baseline: 10.5090x; 1.0429x over previous
//
#include <hip/hip_runtime.h>
#include <math.h>

#define NG 2048
#define NPG 64
#define EPG 512
#define ETOT (NG*EPG)
#define IND 64
#define H1D 128
#define H2D 64
#define OUTD 2016

typedef __attribute__((ext_vector_type(8))) short bf16x8;
typedef __attribute__((ext_vector_type(4))) float f32x4;

__device__ inline short f2b(float f) {
  union { float f; unsigned u; } v; v.f = f;
  unsigned r = (v.u + 0x7FFFu + ((v.u >> 16) & 1u)) >> 16;
  return (short)r;
}

// ---- pre-kernel: W1 -> frag-sequential layout WTgF[((ct*4+ks)*64+l)*8+j]
__global__ void p_w1(const float* __restrict__ w1_rel, const float* __restrict__ w1_root,
                     short* __restrict__ WTgF) {
  const int ct = blockIdx.x;             // 0..7
  const int ks = threadIdx.x >> 6, l = threadIdx.x & 63;
  const int col = ct*16 + (l & 15);
  const int kb  = ks*32 + (l >> 4)*8;
  short tmp[8];
  #pragma unroll
  for (int j = 0; j < 8; ++j) {
    const int k = kb + j;
    float v = (k < 64) ? w1_rel[k*H1D + col] : w1_root[(k - 64)*H1D + col];
    tmp[j] = f2b(v);
  }
  *(uint4*)&WTgF[(size_t)((ct*4 + ks)*64 + l)*8] = *(uint4*)tmp;
}

// ================= Kernel 1: per-graph encoder (+ folded weight transforms) ==========
// Encoder LDS = 32768 B -> 5 blocks/CU. THREE barriers only: b3 was removed after
// auditing: phase-2 reads AGb/Xb rows owned by the same wave; dg is in registers.
__global__ __launch_bounds__(256, 5) void k1_encoder(
    const float* __restrict__ x, const int* __restrict__ ei,
    const short* __restrict__ WTgF, const float* __restrict__ b1,
    short* __restrict__ SVg,
    const float* __restrict__ fc2_w, const float* __restrict__ w2_rel, const float* __restrict__ w2_root,
    const float* __restrict__ w3_rel, const float* __restrict__ w3_root,
    const float* __restrict__ fc1_w,
    short* __restrict__ WF2g, short* __restrict__ W23T, short* __restrict__ fc1T)
{
  __shared__ __align__(16) char smem[32768];
  const int g = blockIdx.x;
  const int tid = threadIdx.x;

  if (g >= NG) {
    // ---------- folded transform path ----------
    float* L = (float*)smem;
    const int bid = g - NG;               // 0..68
    if (bid < 63) {                       // fc2 -> frag-sequential WF2g
      const int c0 = bid*32;
      for (int i = tid; i < 4096; i += 256) {
        int k = i >> 5, c = i & 31;
        L[k*33 + c] = fc2_w[(size_t)k*OUTD + c0 + c];
      }
      __syncthreads();
      const int tl = tid >> 7;
      const int r  = tid & 127;
      const int ks = r >> 5;
      const int lp = r & 31;
      const int ct = bid*2 + tl;
      #pragma unroll
      for (int u = 0; u < 2; ++u) {
        const int l = lp*2 + u;
        const int cl = tl*16 + (l & 15);
        const int kb = ks*32 + (l >> 4)*8;
        short tmp[8];
        #pragma unroll
        for (int j = 0; j < 8; ++j) tmp[j] = f2b(L[(kb + j)*33 + cl]);
        *(uint4*)&WF2g[(size_t)((ct*4 + ks)*64 + l)*8] = *(uint4*)tmp;
      }
    } else if (bid < 67) {                // w2/w3 -> W23T (pitch 264), two passes
      const int cc = bid - 63;
      const int j0 = cc*32;
      const float* wrel  = (cc < 2) ? w2_rel  : w3_rel;
      const float* wroot = (cc < 2) ? w2_root : w3_root;
      const int jl = j0 & 63;
      const int c = tid >> 3, k0 = (tid & 7)*32;
      for (int i = tid; i < 4096; i += 256) {
        int k = i >> 5, cc2 = i & 31;
        L[k*33 + cc2] = wrel[k*H2D + jl + cc2];
      }
      __syncthreads();
      if (k0 < 128)
        for (int kk = 0; kk < 32; ++kk)
          W23T[(size_t)(j0 + c)*264 + k0 + kk] = f2b(L[(k0 + kk)*33 + c]);
      __syncthreads();
      for (int i = tid; i < 4096; i += 256) {
        int k = i >> 5, cc2 = i & 31;
        L[k*33 + cc2] = wroot[k*H2D + jl + cc2];
      }
      __syncthreads();
      if (k0 >= 128)
        for (int kk = 0; kk < 32; ++kk)
          W23T[(size_t)(j0 + c)*264 + k0 + kk] = f2b(L[(k0 + kk - 128)*33 + c]);
    } else {                              // fc1 -> fc1T (pitch 72)
      const int c0 = (bid - 67)*64;
      for (int i = tid; i < 4096; i += 256) {
        int k = i >> 6, c = i & 63;
        L[k*65 + c] = fc1_w[k*H1D + c0 + c];
      }
      __syncthreads();
      const int c = tid >> 2, k0 = (tid & 3)*16;
      for (int kk = 0; kk < 16; ++kk)
        fc1T[(size_t)(c0 + c)*72 + k0 + kk] = f2b(L[(k0 + kk)*65 + c]);
    }
    return;
  }

  // ---------- encoder path ----------
  short* Xb   = (short*)smem;
  short* XbT  = (short*)(smem + 9216);
  short* Ab   = (short*)(smem + 18432);
  unsigned* Au32 = (unsigned*)(smem + 27648);
  float* hsum = (float*)(smem + 31744);
  float* wsum = (float*)(smem + 32256);

  const int w = tid >> 6, l = tid & 63;

  // hoist ALL global loads (edges + x) to issue at block start
  const int e0 = g*EPG + tid*2;
  const int s0 = ei[e0] & 63,     d0 = ei[ETOT + e0] & 63;
  const int s1 = ei[e0 + 1] & 63, d1 = ei[ETOT + e0 + 1] & 63;
  const int n = tid >> 2, f0 = (tid & 3) * 16;
  const float* xr = x + (size_t)g*(NPG*IND) + n*IND + f0;
  float4 v0 = *(const float4*)&xr[0];
  float4 v1 = *(const float4*)&xr[4];
  float4 v2 = *(const float4*)&xr[8];
  float4 v3 = *(const float4*)&xr[12];

  for (int i = tid; i < 64*16; i += 256) Au32[i] = 0u;
  if (tid < 128) { hsum[tid] = 0.f; wsum[tid] = 0.f; }
  __syncthreads();                        // b1: Au32/hsum/wsum zeroed -> atomics

  // adjacency: packed u8 counts (4 cells per u32, pitch 16 words)
  atomicAdd(&Au32[d0*16 + (s0 >> 2)], 1u << (8*(s0 & 3)));
  atomicAdd(&Au32[d1*16 + (s1 >> 2)], 1u << (8*(s1 & 3)));

  // stage Xb (row-major bf16) + XbT (transposed) — overlaps atomic latency.
  // Wave w stages Xb rows 16w..16w+15 (wave-local for phase 2).
  {
    short b[16];
    b[0]=f2b(v0.x); b[1]=f2b(v0.y); b[2]=f2b(v0.z); b[3]=f2b(v0.w);
    b[4]=f2b(v1.x); b[5]=f2b(v1.y); b[6]=f2b(v1.z); b[7]=f2b(v1.w);
    b[8]=f2b(v2.x); b[9]=f2b(v2.y); b[10]=f2b(v2.z); b[11]=f2b(v2.w);
    b[12]=f2b(v3.x); b[13]=f2b(v3.y); b[14]=f2b(v3.z); b[15]=f2b(v3.w);
    short* xbp = &Xb[n*72 + f0];
    #pragma unroll
    for (int j = 0; j < 16; ++j) xbp[j] = b[j];
    #pragma unroll
    for (int j = 0; j < 16; ++j) XbT[(f0 + j)*72 + n] = b[j];
  }
  __syncthreads();                        // b2: atomics + staging -> everything below

  // cvt u8 -> bf16 into Ab; rows WAVE-LOCAL (wave w owns rows 16w..16w+15)
  {
    const int row = tid >> 2, qw = tid & 3;
    unsigned wds[4];
    #pragma unroll
    for (int q = 0; q < 4; ++q) wds[q] = Au32[row*16 + qw*4 + q];
    unsigned* abp = (unsigned*)&Ab[row*72 + qw*16];
    #pragma unroll
    for (int q = 0; q < 4; ++q) {
      unsigned wv = wds[q];
      #pragma unroll
      for (int p = 0; p < 2; ++p) {
        unsigned c0 = (wv >> (16*p)) & 255u, c1 = (wv >> (16*p + 8)) & 255u;
        abp[q*2 + p] = (unsigned)(unsigned short)f2b((float)c0)
                     | ((unsigned)(unsigned short)f2b((float)c1) << 16);
      }
    }
  }

  // deg per-wave in registers (SWAR shfl-reduce over Au32)
  float dg[4];
  {
    unsigned ps = 0;
    #pragma unroll
    for (int i = 0; i < 4; ++i) ps += Au32[((l >> 2) + 16*i)*16 + 4*w + (l & 3)];
    ps += __shfl_xor(ps, 4);
    ps += __shfl_xor(ps, 8);
    ps += __shfl_xor(ps, 16);
    ps += __shfl_xor(ps, 32);
    unsigned dword = __shfl(ps, (l >> 4));
    dg[0] = (float)(dword & 255u);
    dg[1] = (float)((dword >> 8) & 255u);
    dg[2] = (float)((dword >> 16) & 255u);
    dg[3] = (float)(dword >> 24);
  }

  const int rm = w*16;
  const int fr = l & 15;
  const int koff = (l >> 4) * 8;

  // phase 1: AG = A @ X — Ab rows own-wave, XbT all-waves (b2-covered)
  f32x4 agc[4];
  #pragma unroll
  for (int t = 0; t < 4; ++t) agc[t] = (f32x4){0.f,0.f,0.f,0.f};
  #pragma unroll
  for (int ks = 0; ks < 2; ++ks) {
    bf16x8 a = *(const bf16x8*)&Ab[(rm + fr)*72 + ks*32 + koff];
    #pragma unroll
    for (int t = 0; t < 4; ++t) {
      bf16x8 b = *(const bf16x8*)&XbT[(t*16 + fr)*72 + ks*32 + koff];
      agc[t] = __builtin_amdgcn_mfma_f32_16x16x32_bf16(a, b, agc[t], 0, 0, 0);
    }
  }
  // overlay: write AG bf16 over own Ab rows (same-wave reads already consumed them)
  short* AGb = Ab;
  #pragma unroll
  for (int t = 0; t < 4; ++t)
    #pragma unroll
    for (int r = 0; r < 4; ++r)
      AGb[(rm + (l>>4)*4 + r)*72 + t*16 + fr] = f2b(agc[t][r]);
  // NO barrier: phase 2 consumes only own-wave AGb/Xb rows + registers + global.

  // phase 2: h1pre = [AG|X] @ W1, B-frags coalesced from global (L1/L2-hot)
  {
    bf16x8 afr[4];
    #pragma unroll
    for (int ks = 0; ks < 4; ++ks)
      afr[ks] = (ks < 2)
        ? *(const bf16x8*)&AGb[(rm + fr)*72 + ks*32 + koff]
        : *(const bf16x8*)&Xb[(rm + fr)*72 + (ks-2)*32 + koff];

    f32x4 acc[8];
    #pragma unroll
    for (int t = 0; t < 8; ++t) acc[t] = (f32x4){0.f,0.f,0.f,0.f};
    #pragma unroll
    for (int t = 0; t < 8; ++t)
      #pragma unroll
      for (int ks = 0; ks < 4; ++ks) {
        bf16x8 b = *(const bf16x8*)&WTgF[(size_t)((t*4 + ks)*64 + l)*8];
        acc[t] = __builtin_amdgcn_mfma_f32_16x16x32_bf16(afr[ks], b, acc[t], 0, 0, 0);
      }

    #pragma unroll
    for (int t = 0; t < 8; ++t) {
      const int col = t*16 + fr;
      const float bb = b1[col];
      float hs = 0.f, ws = 0.f;
      #pragma unroll
      for (int r = 0; r < 4; ++r) {
        float v = fmaxf(acc[t][r] + bb, 0.f);
        hs += v; ws += dg[r]*v;
      }
      hs += __shfl_down(hs, 32); ws += __shfl_down(ws, 32);
      hs += __shfl_down(hs, 16); ws += __shfl_down(ws, 16);
      if (l < 16) { atomicAdd(&hsum[col], hs); atomicAdd(&wsum[col], ws); }
    }
  }
  __syncthreads();                        // b3: sums -> write

  if (tid < 128) {
    SVg[(size_t)g*256 + tid]       = f2b(wsum[tid]);
    SVg[(size_t)g*256 + 128 + tid] = f2b(hsum[tid]);
  }
}

// ================= Kernel 1b: batched conv2/3-mean + reparam + fc1 ==========
// GEMM2 output now scattered into A-frag-sequential global layout hbufF so k2
// needs no LDS/barrier: hbufF[((rt*4+ks)*64 + (row&15)+16*q)*8 + (col&7)].
__global__ __launch_bounds__(256) void k1b_latent(
    const short* __restrict__ SVg, const short* __restrict__ W23T,
    const float* __restrict__ b2, const float* __restrict__ b3,
    const float* __restrict__ eps, const short* __restrict__ fc1T,
    const float* __restrict__ fc1_b,
    float* __restrict__ out_mu, float* __restrict__ out_lv, short* __restrict__ hbufF)
{
  __shared__ short SV[32*264];
  __shared__ short Zt[32*72];
  const int g0 = blockIdx.x * 32;
  const int tid = threadIdx.x;
  const int w = tid >> 6, l = tid & 63;
  const int s = w >> 1;
  const int h = w & 1;
  const int fr = l & 15;
  const int koff = (l >> 4) * 8;

  {
    const uint4* src = (const uint4*)(SVg + (size_t)g0*256);
    for (int i = tid; i < 1024; i += 256) {
      int r = i >> 5, k0 = (i & 31) * 8;
      *(uint4*)&SV[r*264 + k0] = src[i];
    }
  }
  __syncthreads();

  f32x4 acc[4];
  #pragma unroll
  for (int t = 0; t < 4; ++t) acc[t] = (f32x4){0.f,0.f,0.f,0.f};
  #pragma unroll
  for (int ks = 0; ks < 8; ++ks) {
    bf16x8 a = *(const bf16x8*)&SV[(s*16 + fr)*264 + ks*32 + koff];
    #pragma unroll
    for (int j = 0; j < 2; ++j) {
      bf16x8 bm = *(const bf16x8*)&W23T[((2*h + j)*16 + fr)*264 + ks*32 + koff];
      bf16x8 bl = *(const bf16x8*)&W23T[((2*h + j + 4)*16 + fr)*264 + ks*32 + koff];
      acc[j]     = __builtin_amdgcn_mfma_f32_16x16x32_bf16(a, bm, acc[j], 0, 0, 0);
      acc[2 + j] = __builtin_amdgcn_mfma_f32_16x16x32_bf16(a, bl, acc[2 + j], 0, 0, 0);
    }
  }
  #pragma unroll
  for (int j = 0; j < 2; ++j) {
    const int col = (2*h + j)*16 + fr;
    const float bb2 = b2[col], bb3 = b3[col];
    #pragma unroll
    for (int r = 0; r < 4; ++r) {
      const int row = s*16 + (l>>4)*4 + r;
      const size_t gg = (size_t)(g0 + row);
      float mu = acc[j][r]     * (1.f/64.f) + bb2;
      float lv = acc[2 + j][r] * (1.f/64.f) + bb3;
      out_mu[gg*64 + col] = mu;
      out_lv[gg*64 + col] = lv;
      float z = mu + eps[gg*64 + col] * __expf(0.5f*lv);
      Zt[row*72 + col] = f2b(z);
    }
  }
  __syncthreads();

  f32x4 hacc[4];
  #pragma unroll
  for (int t = 0; t < 4; ++t) hacc[t] = (f32x4){0.f,0.f,0.f,0.f};
  #pragma unroll
  for (int ks = 0; ks < 2; ++ks) {
    bf16x8 a = *(const bf16x8*)&Zt[(s*16 + fr)*72 + ks*32 + koff];
    #pragma unroll
    for (int j = 0; j < 4; ++j) {
      bf16x8 b = *(const bf16x8*)&fc1T[((h*4 + j)*16 + fr)*72 + ks*32 + koff];
      hacc[j] = __builtin_amdgcn_mfma_f32_16x16x32_bf16(a, b, hacc[j], 0, 0, 0);
    }
  }
  // scatter into A-frag-sequential layout
  #pragma unroll
  for (int j = 0; j < 4; ++j) {
    const int col = (h*4 + j)*16 + fr;      // 0..127
    const int ks  = col >> 5;
    const int q   = (col >> 3) & 3;
    const int j8  = col & 7;
    const float bb = fc1_b[col];
    #pragma unroll
    for (int r = 0; r < 4; ++r) {
      const int row = s*16 + (l>>4)*4 + r;  // 0..31
      const int rt  = blockIdx.x*2 + (row >> 4);
      const int lane = (row & 15) + 16*q;
      hbufF[(size_t)((rt*4 + ks)*64 + lane)*8 + j8] = f2b(fmaxf(hacc[j][r] + bb, 0.f));
    }
  }
}

// ================= Kernel 2: decoder GEMM — zero LDS, zero barriers ==========
// grid (32, 21): 64-row x 96-col tiles; A-frags AND B-frags coalesced from global.
__global__ __launch_bounds__(256, 8) void k2_decoder(
    const short* __restrict__ hbufF, const short* __restrict__ WF2g,
    const float* __restrict__ fc2_b, float* __restrict__ recon)
{
  const int bx = blockIdx.x, by = blockIdx.y;
  const int tid = threadIdx.x;
  const int w = tid >> 6, l = tid & 63;
  const int fr = l & 15;
  const int rt = bx*4 + w;                 // row-tile (16 rows)

  bf16x8 afr[4];
  #pragma unroll
  for (int ks = 0; ks < 4; ++ks)
    afr[ks] = *(const bf16x8*)&hbufF[(size_t)((rt*4 + ks)*64 + l)*8];

  f32x4 acc[6];
  #pragma unroll
  for (int t = 0; t < 6; ++t) acc[t] = (f32x4){0.f,0.f,0.f,0.f};

  #pragma unroll
  for (int ks = 0; ks < 4; ++ks) {
    #pragma unroll
    for (int t = 0; t < 6; ++t) {
      const int ct = by*6 + t;
      bf16x8 b = *(const bf16x8*)&WF2g[(size_t)((ct*4 + ks)*64 + l)*8];
      acc[t] = __builtin_amdgcn_mfma_f32_16x16x32_bf16(afr[ks], b, acc[t], 0, 0, 0);
    }
  }

  #pragma unroll
  for (int t = 0; t < 6; ++t) {
    const int col = by*96 + t*16 + fr;
    const float bb = fc2_b[col];
    #pragma unroll
    for (int r = 0; r < 4; ++r) {
      const int row = bx*64 + w*16 + (l>>4)*4 + r;
      float v = acc[t][r] + bb;
      recon[(size_t)row*OUTD + col] = 1.f/(1.f + __expf(-v));
    }
  }
}

extern "C" void kernel_launch(void* const* d_in, const int* in_sizes, int n_in,
                              void* d_out, int out_size, void* d_ws, size_t ws_size,
                              hipStream_t stream) {
  const float* x       = (const float*)d_in[0];
  const int*   ei      = (const int*)d_in[1];
  const float* eps     = (const float*)d_in[3];
  const float* w1_rel  = (const float*)d_in[4];
  const float* b1      = (const float*)d_in[5];
  const float* w1_root = (const float*)d_in[6];
  const float* w2_rel  = (const float*)d_in[7];
  const float* b2      = (const float*)d_in[8];
  const float* w2_root = (const float*)d_in[9];
  const float* w3_rel  = (const float*)d_in[10];
  const float* b3      = (const float*)d_in[11];
  const float* w3_root = (const float*)d_in[12];
  const float* fc1_w   = (const float*)d_in[13];
  const float* fc1_b   = (const float*)d_in[14];
  const float* fc2_w   = (const float*)d_in[15];
  const float* fc2_b   = (const float*)d_in[16];

  float* recon  = (float*)d_out;
  float* out_mu = recon + (size_t)NG*OUTD;
  float* out_lv = out_mu + (size_t)NG*H2D;

  char* p = (char*)d_ws;
  short* WTgF  = (short*)p;              p += 8*4*64*8*2;        // 32768
  short* WF2g  = (short*)p;              p += 126*4*64*8*2;      // 516096
  short* fc1T  = (short*)p;              p += 128*72*2;          // 18432
  short* W23T  = (short*)p;              p += 128*264*2;         // 67584
  short* SVg   = (short*)p;              p += (size_t)NG*256*2;  // 1048576
  short* hbufF = (short*)p;                                      // 524288

  p_w1<<<8, 256, 0, stream>>>(w1_rel, w1_root, WTgF);
  k1_encoder<<<NG + 69, 256, 0, stream>>>(x, ei, WTgF, b1, SVg,
      fc2_w, w2_rel, w2_root, w3_rel, w3_root, fc1_w, WF2g, W23T, fc1T);
  k1b_latent<<<64, 256, 0, stream>>>(SVg, W23T, b2, b3, eps, fc1T, fc1_b,
                                     out_mu, out_lv, hbufF);
  k2_decoder<<<dim3(32, 21), 256, 0, stream>>>(hbufF, WF2g, fc2_b, recon);
}

// Round 11
// 142.329 us; speedup vs baseline: 10.7654x; 1.0244x over previous
//
#include <hip/hip_runtime.h>
#include <math.h>

#define NG 2048
#define NPG 64
#define EPG 512
#define ETOT (NG*EPG)
#define IND 64
#define H1D 128
#define H2D 64
#define OUTD 2016

typedef __attribute__((ext_vector_type(8))) short bf16x8;
typedef __attribute__((ext_vector_type(4))) float f32x4;

__device__ inline short f2b(float f) {
  union { float f; unsigned u; } v; v.f = f;
  unsigned r = (v.u + 0x7FFFu + ((v.u >> 16) & 1u)) >> 16;
  return (short)r;
}

// ---- pre-kernel: W1 -> frag-sequential layout WTgF[((ct*4+ks)*64+l)*8+j]
__global__ void p_w1(const float* __restrict__ w1_rel, const float* __restrict__ w1_root,
                     short* __restrict__ WTgF) {
  const int ct = blockIdx.x;             // 0..7
  const int ks = threadIdx.x >> 6, l = threadIdx.x & 63;
  const int col = ct*16 + (l & 15);
  const int kb  = ks*32 + (l >> 4)*8;
  short tmp[8];
  #pragma unroll
  for (int j = 0; j < 8; ++j) {
    const int k = kb + j;
    float v = (k < 64) ? w1_rel[k*H1D + col] : w1_root[(k - 64)*H1D + col];
    tmp[j] = f2b(v);
  }
  *(uint4*)&WTgF[(size_t)((ct*4 + ks)*64 + l)*8] = *(uint4*)tmp;
}

// ================= Kernel 1: per-graph encoder (+ folded weight transforms) ==========
// Encoder LDS = 31744 B -> 5 blocks/CU. TWO barriers. Epilogue writes per-wave
// fp32 partial colsums straight to global SVp[g][wave][256]; k1b sums the 4.
__global__ __launch_bounds__(256, 5) void k1_encoder(
    const float* __restrict__ x, const int* __restrict__ ei,
    const short* __restrict__ WTgF, const float* __restrict__ b1,
    float* __restrict__ SVp,
    const float* __restrict__ fc2_w, const float* __restrict__ w2_rel, const float* __restrict__ w2_root,
    const float* __restrict__ w3_rel, const float* __restrict__ w3_root,
    const float* __restrict__ fc1_w,
    short* __restrict__ WF2g, short* __restrict__ W23T, short* __restrict__ fc1T)
{
  __shared__ __align__(16) char smem[32768];
  const int g = blockIdx.x;
  const int tid = threadIdx.x;

  if (g >= NG) {
    // ---------- folded transform path ----------
    float* L = (float*)smem;
    const int bid = g - NG;               // 0..68
    if (bid < 63) {                       // fc2 -> frag-sequential WF2g
      const int c0 = bid*32;
      for (int i = tid; i < 4096; i += 256) {
        int k = i >> 5, c = i & 31;
        L[k*33 + c] = fc2_w[(size_t)k*OUTD + c0 + c];
      }
      __syncthreads();
      const int tl = tid >> 7;
      const int r  = tid & 127;
      const int ks = r >> 5;
      const int lp = r & 31;
      const int ct = bid*2 + tl;
      #pragma unroll
      for (int u = 0; u < 2; ++u) {
        const int l = lp*2 + u;
        const int cl = tl*16 + (l & 15);
        const int kb = ks*32 + (l >> 4)*8;
        short tmp[8];
        #pragma unroll
        for (int j = 0; j < 8; ++j) tmp[j] = f2b(L[(kb + j)*33 + cl]);
        *(uint4*)&WF2g[(size_t)((ct*4 + ks)*64 + l)*8] = *(uint4*)tmp;
      }
    } else if (bid < 67) {                // w2/w3 -> W23T (pitch 264), two passes
      const int cc = bid - 63;
      const int j0 = cc*32;
      const float* wrel  = (cc < 2) ? w2_rel  : w3_rel;
      const float* wroot = (cc < 2) ? w2_root : w3_root;
      const int jl = j0 & 63;
      const int c = tid >> 3, k0 = (tid & 7)*32;
      for (int i = tid; i < 4096; i += 256) {
        int k = i >> 5, cc2 = i & 31;
        L[k*33 + cc2] = wrel[k*H2D + jl + cc2];
      }
      __syncthreads();
      if (k0 < 128)
        for (int kk = 0; kk < 32; ++kk)
          W23T[(size_t)(j0 + c)*264 + k0 + kk] = f2b(L[(k0 + kk)*33 + c]);
      __syncthreads();
      for (int i = tid; i < 4096; i += 256) {
        int k = i >> 5, cc2 = i & 31;
        L[k*33 + cc2] = wroot[k*H2D + jl + cc2];
      }
      __syncthreads();
      if (k0 >= 128)
        for (int kk = 0; kk < 32; ++kk)
          W23T[(size_t)(j0 + c)*264 + k0 + kk] = f2b(L[(k0 + kk - 128)*33 + c]);
    } else {                              // fc1 -> fc1T (pitch 72)
      const int c0 = (bid - 67)*64;
      for (int i = tid; i < 4096; i += 256) {
        int k = i >> 6, c = i & 63;
        L[k*65 + c] = fc1_w[k*H1D + c0 + c];
      }
      __syncthreads();
      const int c = tid >> 2, k0 = (tid & 3)*16;
      for (int kk = 0; kk < 16; ++kk)
        fc1T[(size_t)(c0 + c)*72 + k0 + kk] = f2b(L[(k0 + kk)*65 + c]);
    }
    return;
  }

  // ---------- encoder path ----------
  short* Xb   = (short*)smem;               // 9216
  short* XbT  = (short*)(smem + 9216);      // 9216
  short* Ab   = (short*)(smem + 18432);     // 9216 (->AGb overlay, wave-local rows)
  unsigned* Au32 = (unsigned*)(smem + 27648); // 4096 (packed u8 counts)

  const int w = tid >> 6, l = tid & 63;

  // hoist ALL global loads (edges + x) to issue at block start
  const int e0 = g*EPG + tid*2;
  const int s0 = ei[e0] & 63,     d0 = ei[ETOT + e0] & 63;
  const int s1 = ei[e0 + 1] & 63, d1 = ei[ETOT + e0 + 1] & 63;
  const int n = tid >> 2, f0 = (tid & 3) * 16;
  const float* xr = x + (size_t)g*(NPG*IND) + n*IND + f0;
  float4 v0 = *(const float4*)&xr[0];
  float4 v1 = *(const float4*)&xr[4];
  float4 v2 = *(const float4*)&xr[8];
  float4 v3 = *(const float4*)&xr[12];

  for (int i = tid; i < 64*16; i += 256) Au32[i] = 0u;
  __syncthreads();                        // b1: Au32 zeroed -> atomics

  // adjacency: packed u8 counts (4 cells per u32, pitch 16 words)
  atomicAdd(&Au32[d0*16 + (s0 >> 2)], 1u << (8*(s0 & 3)));
  atomicAdd(&Au32[d1*16 + (s1 >> 2)], 1u << (8*(s1 & 3)));

  // stage Xb (row-major bf16) + XbT (transposed) — overlaps atomic latency.
  {
    short b[16];
    b[0]=f2b(v0.x); b[1]=f2b(v0.y); b[2]=f2b(v0.z); b[3]=f2b(v0.w);
    b[4]=f2b(v1.x); b[5]=f2b(v1.y); b[6]=f2b(v1.z); b[7]=f2b(v1.w);
    b[8]=f2b(v2.x); b[9]=f2b(v2.y); b[10]=f2b(v2.z); b[11]=f2b(v2.w);
    b[12]=f2b(v3.x); b[13]=f2b(v3.y); b[14]=f2b(v3.z); b[15]=f2b(v3.w);
    short* xbp = &Xb[n*72 + f0];
    #pragma unroll
    for (int j = 0; j < 16; ++j) xbp[j] = b[j];
    #pragma unroll
    for (int j = 0; j < 16; ++j) XbT[(f0 + j)*72 + n] = b[j];
  }
  __syncthreads();                        // b2: atomics + staging -> everything below

  // cvt u8 -> bf16 into Ab; rows WAVE-LOCAL (wave w owns rows 16w..16w+15)
  {
    const int row = tid >> 2, qw = tid & 3;
    unsigned wds[4];
    #pragma unroll
    for (int q = 0; q < 4; ++q) wds[q] = Au32[row*16 + qw*4 + q];
    unsigned* abp = (unsigned*)&Ab[row*72 + qw*16];
    #pragma unroll
    for (int q = 0; q < 4; ++q) {
      unsigned wv = wds[q];
      #pragma unroll
      for (int p = 0; p < 2; ++p) {
        unsigned c0 = (wv >> (16*p)) & 255u, c1 = (wv >> (16*p + 8)) & 255u;
        abp[q*2 + p] = (unsigned)(unsigned short)f2b((float)c0)
                     | ((unsigned)(unsigned short)f2b((float)c1) << 16);
      }
    }
  }

  // deg per-wave in registers (SWAR shfl-reduce over Au32)
  float dg[4];
  {
    unsigned ps = 0;
    #pragma unroll
    for (int i = 0; i < 4; ++i) ps += Au32[((l >> 2) + 16*i)*16 + 4*w + (l & 3)];
    ps += __shfl_xor(ps, 4);
    ps += __shfl_xor(ps, 8);
    ps += __shfl_xor(ps, 16);
    ps += __shfl_xor(ps, 32);
    unsigned dword = __shfl(ps, (l >> 4));
    dg[0] = (float)(dword & 255u);
    dg[1] = (float)((dword >> 8) & 255u);
    dg[2] = (float)((dword >> 16) & 255u);
    dg[3] = (float)(dword >> 24);
  }

  const int rm = w*16;
  const int fr = l & 15;
  const int koff = (l >> 4) * 8;

  // phase 1: AG = A @ X — Ab rows own-wave, XbT all-waves (b2-covered)
  f32x4 agc[4];
  #pragma unroll
  for (int t = 0; t < 4; ++t) agc[t] = (f32x4){0.f,0.f,0.f,0.f};
  #pragma unroll
  for (int ks = 0; ks < 2; ++ks) {
    bf16x8 a = *(const bf16x8*)&Ab[(rm + fr)*72 + ks*32 + koff];
    #pragma unroll
    for (int t = 0; t < 4; ++t) {
      bf16x8 b = *(const bf16x8*)&XbT[(t*16 + fr)*72 + ks*32 + koff];
      agc[t] = __builtin_amdgcn_mfma_f32_16x16x32_bf16(a, b, agc[t], 0, 0, 0);
    }
  }
  // overlay: write AG bf16 over own Ab rows (same-wave reads already consumed them)
  short* AGb = Ab;
  #pragma unroll
  for (int t = 0; t < 4; ++t)
    #pragma unroll
    for (int r = 0; r < 4; ++r)
      AGb[(rm + (l>>4)*4 + r)*72 + t*16 + fr] = f2b(agc[t][r]);
  // NO barrier: phase 2 consumes only own-wave AGb/Xb rows + registers + global.

  // phase 2: h1pre = [AG|X] @ W1, B-frags coalesced from global (L1/L2-hot)
  {
    bf16x8 afr[4];
    #pragma unroll
    for (int ks = 0; ks < 4; ++ks)
      afr[ks] = (ks < 2)
        ? *(const bf16x8*)&AGb[(rm + fr)*72 + ks*32 + koff]
        : *(const bf16x8*)&Xb[(rm + fr)*72 + (ks-2)*32 + koff];

    f32x4 acc[8];
    #pragma unroll
    for (int t = 0; t < 8; ++t) acc[t] = (f32x4){0.f,0.f,0.f,0.f};
    #pragma unroll
    for (int t = 0; t < 8; ++t)
      #pragma unroll
      for (int ks = 0; ks < 4; ++ks) {
        bf16x8 b = *(const bf16x8*)&WTgF[(size_t)((t*4 + ks)*64 + l)*8];
        acc[t] = __builtin_amdgcn_mfma_f32_16x16x32_bf16(afr[ks], b, acc[t], 0, 0, 0);
      }

    // epilogue: per-wave partial colsums straight to global (no LDS, no barrier)
    float* SVp_g = SVp + (size_t)(g*4 + w)*256;
    #pragma unroll
    for (int t = 0; t < 8; ++t) {
      const int col = t*16 + fr;
      const float bb = b1[col];
      float hs = 0.f, ws = 0.f;
      #pragma unroll
      for (int r = 0; r < 4; ++r) {
        float v = fmaxf(acc[t][r] + bb, 0.f);
        hs += v; ws += dg[r]*v;
      }
      hs += __shfl_down(hs, 32); ws += __shfl_down(ws, 32);
      hs += __shfl_down(hs, 16); ws += __shfl_down(ws, 16);
      if (l < 16) {
        SVp_g[col]       = ws;
        SVp_g[128 + col] = hs;
      }
    }
  }
}

// ================= Kernel 1b: batched conv2/3-mean + reparam + fc1 ==========
// Stages SV tile by summing the 4 per-wave fp32 partials from SVp.
__global__ __launch_bounds__(256) void k1b_latent(
    const float* __restrict__ SVp, const short* __restrict__ W23T,
    const float* __restrict__ b2, const float* __restrict__ b3,
    const float* __restrict__ eps, const short* __restrict__ fc1T,
    const float* __restrict__ fc1_b,
    float* __restrict__ out_mu, float* __restrict__ out_lv, short* __restrict__ hbufF)
{
  __shared__ short SV[32*264];
  __shared__ short Zt[32*72];
  const int g0 = blockIdx.x * 32;
  const int tid = threadIdx.x;
  const int w = tid >> 6, l = tid & 63;
  const int s = w >> 1;
  const int h = w & 1;
  const int fr = l & 15;
  const int koff = (l >> 4) * 8;

  // stage SV tile: sum 4 per-wave partials (coalesced fp32 loads)
  for (int i = tid; i < 32*256; i += 256) {
    const int r = i >> 8, k = i & 255;
    const float* p4 = SVp + (size_t)(g0 + r)*1024 + k;
    float v = (p4[0] + p4[256]) + (p4[512] + p4[768]);
    SV[r*264 + k] = f2b(v);
  }
  __syncthreads();

  f32x4 acc[4];
  #pragma unroll
  for (int t = 0; t < 4; ++t) acc[t] = (f32x4){0.f,0.f,0.f,0.f};
  #pragma unroll
  for (int ks = 0; ks < 8; ++ks) {
    bf16x8 a = *(const bf16x8*)&SV[(s*16 + fr)*264 + ks*32 + koff];
    #pragma unroll
    for (int j = 0; j < 2; ++j) {
      bf16x8 bm = *(const bf16x8*)&W23T[((2*h + j)*16 + fr)*264 + ks*32 + koff];
      bf16x8 bl = *(const bf16x8*)&W23T[((2*h + j + 4)*16 + fr)*264 + ks*32 + koff];
      acc[j]     = __builtin_amdgcn_mfma_f32_16x16x32_bf16(a, bm, acc[j], 0, 0, 0);
      acc[2 + j] = __builtin_amdgcn_mfma_f32_16x16x32_bf16(a, bl, acc[2 + j], 0, 0, 0);
    }
  }
  #pragma unroll
  for (int j = 0; j < 2; ++j) {
    const int col = (2*h + j)*16 + fr;
    const float bb2 = b2[col], bb3 = b3[col];
    #pragma unroll
    for (int r = 0; r < 4; ++r) {
      const int row = s*16 + (l>>4)*4 + r;
      const size_t gg = (size_t)(g0 + row);
      float mu = acc[j][r]     * (1.f/64.f) + bb2;
      float lv = acc[2 + j][r] * (1.f/64.f) + bb3;
      out_mu[gg*64 + col] = mu;
      out_lv[gg*64 + col] = lv;
      float z = mu + eps[gg*64 + col] * __expf(0.5f*lv);
      Zt[row*72 + col] = f2b(z);
    }
  }
  __syncthreads();

  f32x4 hacc[4];
  #pragma unroll
  for (int t = 0; t < 4; ++t) hacc[t] = (f32x4){0.f,0.f,0.f,0.f};
  #pragma unroll
  for (int ks = 0; ks < 2; ++ks) {
    bf16x8 a = *(const bf16x8*)&Zt[(s*16 + fr)*72 + ks*32 + koff];
    #pragma unroll
    for (int j = 0; j < 4; ++j) {
      bf16x8 b = *(const bf16x8*)&fc1T[((h*4 + j)*16 + fr)*72 + ks*32 + koff];
      hacc[j] = __builtin_amdgcn_mfma_f32_16x16x32_bf16(a, b, hacc[j], 0, 0, 0);
    }
  }
  // scatter into A-frag-sequential layout for k2
  #pragma unroll
  for (int j = 0; j < 4; ++j) {
    const int col = (h*4 + j)*16 + fr;      // 0..127
    const int ks  = col >> 5;
    const int q   = (col >> 3) & 3;
    const int j8  = col & 7;
    const float bb = fc1_b[col];
    #pragma unroll
    for (int r = 0; r < 4; ++r) {
      const int row = s*16 + (l>>4)*4 + r;  // 0..31
      const int rt  = blockIdx.x*2 + (row >> 4);
      const int lane = (row & 15) + 16*q;
      hbufF[(size_t)((rt*4 + ks)*64 + lane)*8 + j8] = f2b(fmaxf(hacc[j][r] + bb, 0.f));
    }
  }
}

// ================= Kernel 2: decoder GEMM — zero LDS, zero barriers ==========
__global__ __launch_bounds__(256, 8) void k2_decoder(
    const short* __restrict__ hbufF, const short* __restrict__ WF2g,
    const float* __restrict__ fc2_b, float* __restrict__ recon)
{
  const int bx = blockIdx.x, by = blockIdx.y;
  const int tid = threadIdx.x;
  const int w = tid >> 6, l = tid & 63;
  const int fr = l & 15;
  const int rt = bx*4 + w;                 // row-tile (16 rows)

  bf16x8 afr[4];
  #pragma unroll
  for (int ks = 0; ks < 4; ++ks)
    afr[ks] = *(const bf16x8*)&hbufF[(size_t)((rt*4 + ks)*64 + l)*8];

  f32x4 acc[6];
  #pragma unroll
  for (int t = 0; t < 6; ++t) acc[t] = (f32x4){0.f,0.f,0.f,0.f};

  #pragma unroll
  for (int ks = 0; ks < 4; ++ks) {
    #pragma unroll
    for (int t = 0; t < 6; ++t) {
      const int ct = by*6 + t;
      bf16x8 b = *(const bf16x8*)&WF2g[(size_t)((ct*4 + ks)*64 + l)*8];
      acc[t] = __builtin_amdgcn_mfma_f32_16x16x32_bf16(afr[ks], b, acc[t], 0, 0, 0);
    }
  }

  #pragma unroll
  for (int t = 0; t < 6; ++t) {
    const int col = by*96 + t*16 + fr;
    const float bb = fc2_b[col];
    #pragma unroll
    for (int r = 0; r < 4; ++r) {
      const int row = bx*64 + w*16 + (l>>4)*4 + r;
      float v = acc[t][r] + bb;
      recon[(size_t)row*OUTD + col] = 1.f/(1.f + __expf(-v));
    }
  }
}

extern "C" void kernel_launch(void* const* d_in, const int* in_sizes, int n_in,
                              void* d_out, int out_size, void* d_ws, size_t ws_size,
                              hipStream_t stream) {
  const float* x       = (const float*)d_in[0];
  const int*   ei      = (const int*)d_in[1];
  const float* eps     = (const float*)d_in[3];
  const float* w1_rel  = (const float*)d_in[4];
  const float* b1      = (const float*)d_in[5];
  const float* w1_root = (const float*)d_in[6];
  const float* w2_rel  = (const float*)d_in[7];
  const float* b2      = (const float*)d_in[8];
  const float* w2_root = (const float*)d_in[9];
  const float* w3_rel  = (const float*)d_in[10];
  const float* b3      = (const float*)d_in[11];
  const float* w3_root = (const float*)d_in[12];
  const float* fc1_w   = (const float*)d_in[13];
  const float* fc1_b   = (const float*)d_in[14];
  const float* fc2_w   = (const float*)d_in[15];
  const float* fc2_b   = (const float*)d_in[16];

  float* recon  = (float*)d_out;
  float* out_mu = recon + (size_t)NG*OUTD;
  float* out_lv = out_mu + (size_t)NG*H2D;

  char* p = (char*)d_ws;
  short* WTgF  = (short*)p;              p += 8*4*64*8*2;           // 32768
  short* WF2g  = (short*)p;              p += 126*4*64*8*2;         // 516096
  short* fc1T  = (short*)p;              p += 128*72*2;             // 18432
  short* W23T  = (short*)p;              p += 128*264*2;            // 67584
  float* SVp   = (float*)p;              p += (size_t)NG*4*256*4;   // 8 MB
  short* hbufF = (short*)p;                                          // 524288

  p_w1<<<8, 256, 0, stream>>>(w1_rel, w1_root, WTgF);
  k1_encoder<<<NG + 69, 256, 0, stream>>>(x, ei, WTgF, b1, SVp,
      fc2_w, w2_rel, w2_root, w3_rel, w3_root, fc1_w, WF2g, W23T, fc1T);
  k1b_latent<<<64, 256, 0, stream>>>(SVp, W23T, b2, b3, eps, fc1T, fc1_b,
                                     out_mu, out_lv, hbufF);
  k2_decoder<<<dim3(32, 21), 256, 0, stream>>>(hbufF, WF2g, fc2_b, recon);
}